// Round 1
// baseline (1030.278 us; speedup 1.0000x reference)
//
#include <hip/hip_runtime.h>

#define NN 4096   // H*W
#define DD 256    // feature channels
#define CC 19     // classes
#define BB 2      // batch

// ---------------------------------------------------------------------------
// K1: softmax confidence mask + scrambled one-hot bitmasks
// ---------------------------------------------------------------------------
__global__ void k_mask_bits(const float* __restrict__ pred, const float* __restrict__ cw,
                            float* __restrict__ maskb, unsigned int* __restrict__ ohbits) {
  int g = blockIdx.x * 256 + threadIdx.x;
  if (g >= BB * NN) return;
  int b = g >> 12, n = g & (NN - 1);
  const float* p = pred + (size_t)b * CC * NN + n;
  float v[CC];
  float mx = -1e30f; int am = 0;
#pragma unroll
  for (int c = 0; c < CC; ++c) {
    float t = p[(size_t)c * NN];
    v[c] = t;
    if (t > mx) { mx = t; am = c; }
  }
  float s = 0.f;
#pragma unroll
  for (int c = 0; c < CC; ++c) s += expf(v[c] - mx);
  float pprob = 1.f / s;
  float cmax = 0.f;
#pragma unroll
  for (int c = 0; c < CC; ++c) cmax = fmaxf(cmax, cw[c]);
  float cwm = cw[am] / (cmax + 1e-10f) * 0.95f;
  maskb[g] = (pprob >= 0.95f || pprob >= cwm) ? 1.f : 0.f;
  // one_hot [B,H,W,C] -> transpose(0,2,3,1) -> [B,W,C,H] -> reshape(B,-1,19)
  int h = n >> 6, w = n & 63;
  int L = w * (CC * 64) + am * 64 + h;     // flat index in [W,C,H]
  atomicOr(&ohbits[b * NN + L / CC], 1u << (L % CC));
}

// ---------------------------------------------------------------------------
// K2: row-normalize features, stored transposed xnT[b][d][n]
// ---------------------------------------------------------------------------
__global__ void k_norm_feat(const float* __restrict__ feat, float* __restrict__ xnT) {
  int g = blockIdx.x * 64 + threadIdx.x;
  int b = g >> 12, n = g & (NN - 1);
  const float* f = feat + (size_t)b * DD * NN + n;
  float s = 0.f;
  for (int d = 0; d < DD; ++d) { float t = f[(size_t)d * NN]; s += t * t; }
  float r = 1.f / (sqrtf(s) + 1e-9f);
  float* o = xnT + (size_t)b * DD * NN + n;
  for (int d = 0; d < DD; ++d) o[(size_t)d * NN] = f[(size_t)d * NN] * r;
}

// ---------------------------------------------------------------------------
// K3: aff1 = clamp(Gram(xn), 0).  Symmetric: block (I<=J) writes both tiles.
// ---------------------------------------------------------------------------
__global__ __launch_bounds__(256) void k_gram1(const float* __restrict__ xnT, float* __restrict__ M) {
  int b = blockIdx.z, I = blockIdx.y, J = blockIdx.x;
  if (I > J) return;
  const float* X = xnT + (size_t)b * DD * NN;
  float* Mb = M + (size_t)b * NN * NN;
  __shared__ float sA[16][64];
  __shared__ float sB[16][64];
  __shared__ float tr[64][65];
  int t = threadIdx.x;
  int r = t >> 4, c = t & 15;
  int i0 = I * 64, j0 = J * 64;
  float acc[4][4] = {};
  for (int k0 = 0; k0 < DD; k0 += 16) {
    int lk = t >> 6, lcol = t & 63;
#pragma unroll
    for (int e = 0; e < 4; ++e) {
      const float* src = X + (size_t)(k0 + lk + e * 4) * NN;
      sA[lk + e * 4][lcol] = src[i0 + lcol];
      sB[lk + e * 4][lcol] = src[j0 + lcol];
    }
    __syncthreads();
#pragma unroll
    for (int k = 0; k < 16; ++k) {
      float av[4], bv[4];
#pragma unroll
      for (int i = 0; i < 4; ++i) av[i] = sA[k][r * 4 + i];
#pragma unroll
      for (int j = 0; j < 4; ++j) bv[j] = sB[k][c * 4 + j];
#pragma unroll
      for (int i = 0; i < 4; ++i) {
#pragma unroll
        for (int j = 0; j < 4; ++j) acc[i][j] += av[i] * bv[j];
      }
    }
    __syncthreads();
  }
#pragma unroll
  for (int i = 0; i < 4; ++i) {
#pragma unroll
    for (int j = 0; j < 4; ++j) acc[i][j] = fmaxf(acc[i][j], 0.f);
    float4 v = make_float4(acc[i][0], acc[i][1], acc[i][2], acc[i][3]);
    *reinterpret_cast<float4*>(&Mb[(size_t)(i0 + r * 4 + i) * NN + j0 + c * 4]) = v;
  }
  if (I != J) {
#pragma unroll
    for (int i = 0; i < 4; ++i) {
#pragma unroll
      for (int j = 0; j < 4; ++j) tr[r * 4 + i][c * 4 + j] = acc[i][j];
    }
    __syncthreads();
#pragma unroll
    for (int e = 0; e < 16; ++e) {
      int lin = t + e * 256;
      int jr = lin >> 6, ic = lin & 63;
      Mb[(size_t)(j0 + jr) * NN + i0 + ic] = tr[ic][jr];
    }
  }
}

// ---------------------------------------------------------------------------
// K4: per-row 21st-largest value (extract-max x21 on LDS copy)
// ---------------------------------------------------------------------------
__global__ __launch_bounds__(256) void k_topk(const float* __restrict__ M, float* __restrict__ thr) {
  int b = blockIdx.y, n = blockIdx.x;
  const float* row = M + (size_t)b * NN * NN + (size_t)n * NN;
  __shared__ float vals[NN];
  __shared__ float wrv[4];
  __shared__ int wri[4];
  int t = threadIdx.x;
  int wid = t >> 6, lane = t & 63;
  for (int i = t; i < NN; i += 256) vals[i] = row[i];
  __syncthreads();
  float last = 0.f;
  for (int it = 0; it < 21; ++it) {
    float bv = -2.f; int bi = 0;
#pragma unroll
    for (int e = 0; e < 16; ++e) {
      int idx = t + e * 256;
      float v = vals[idx];
      if (v > bv) { bv = v; bi = idx; }
    }
    // wave argmax reduce (tie -> lowest index)
    for (int off = 32; off > 0; off >>= 1) {
      float ov = __shfl_down(bv, off);
      int oi = __shfl_down(bi, off);
      if (ov > bv || (ov == bv && oi < bi)) { bv = ov; bi = oi; }
    }
    if (lane == 0) { wrv[wid] = bv; wri[wid] = bi; }
    __syncthreads();
    if (t == 0) {
      float fv = wrv[0]; int fi = wri[0];
#pragma unroll
      for (int w = 1; w < 4; ++w) {
        if (wrv[w] > fv || (wrv[w] == fv && wri[w] < fi)) { fv = wrv[w]; fi = wri[w]; }
      }
      vals[fi] = -1.f;
      last = fv;
    }
    __syncthreads();
  }
  if (t == 0) thr[b * NN + n] = last;
}

// ---------------------------------------------------------------------------
// K5: in-place sparsify + symmetrize  As = S + S^T, plus degree partial sums
// ---------------------------------------------------------------------------
__global__ __launch_bounds__(256) void k_symm(float* __restrict__ M, const float* __restrict__ thr,
                                              float* __restrict__ dsum) {
  int b = blockIdx.z, I = blockIdx.y, J = blockIdx.x;
  if (I > J) return;
  float* Mb = M + (size_t)b * NN * NN;
  const float* th = thr + b * NN;
  __shared__ float A[64][65];
  __shared__ float Bt[64][65];
  int t = threadIdx.x;
  int i0 = I * 64, j0 = J * 64;
  float areg[16];
#pragma unroll
  for (int e = 0; e < 16; ++e) {
    int lin = t + e * 256;
    int i = lin >> 6, j = lin & 63;
    areg[e] = Mb[(size_t)(i0 + i) * NN + j0 + j];
    Bt[i][j] = Mb[(size_t)(j0 + i) * NN + i0 + j];   // tile (J,I), row-coalesced
  }
  __syncthreads();
#pragma unroll
  for (int e = 0; e < 16; ++e) {
    int lin = t + e * 256;
    int i = lin >> 6, j = lin & 63;
    float a = areg[e];
    float sa = (a >= th[i0 + i]) ? a : 0.f;
    float bt = Bt[j][i];
    float sb = (bt >= th[j0 + j]) ? bt : 0.f;
    float v = sa + sb;
    A[i][j] = v;
    Mb[(size_t)(i0 + i) * NN + j0 + j] = v;
  }
  __syncthreads();
  if (I != J) {
#pragma unroll
    for (int e = 0; e < 16; ++e) {
      int lin = t + e * 256;
      int j = lin >> 6, i = lin & 63;
      Mb[(size_t)(j0 + j) * NN + i0 + i] = A[i][j];
    }
  }
  if (t < 64) {
    float s = 0.f;
#pragma unroll
    for (int j = 0; j < 64; ++j) s += A[t][j];
    atomicAdd(&dsum[b * NN + i0 + t], s);
  } else if (t < 128 && I != J) {
    int j = t - 64;
    float s = 0.f;
#pragma unroll
    for (int i = 0; i < 64; ++i) s += A[i][j];
    atomicAdd(&dsum[b * NN + j0 + j], s);
  }
}

// ---------------------------------------------------------------------------
// K6: d = (d + 1e-10)^-0.5
// ---------------------------------------------------------------------------
__global__ void k_fin_d(float* __restrict__ d) {
  int g = blockIdx.x * 256 + threadIdx.x;
  if (g < BB * NN) d[g] = 1.f / sqrtf(d[g] + 1e-10f);
}

// ---------------------------------------------------------------------------
// K7: yT[b][c][n] = d1n[b][n] * pred[b][c][n]
// ---------------------------------------------------------------------------
__global__ void k_make_y(const float* __restrict__ pred, const float* __restrict__ d1,
                         float* __restrict__ yT) {
  int g = blockIdx.x * 256 + threadIdx.x;
  if (g >= BB * CC * NN) return;
  int b = g / (CC * NN);
  int n = g & (NN - 1);
  yT[g] = pred[g] * d1[b * NN + n];
}

// ---------------------------------------------------------------------------
// K8: p2[b][n][c] = d1n[n] * sum_m As[n][m] * yT[c][m]
// ---------------------------------------------------------------------------
__global__ __launch_bounds__(256) void k_p2(const float* __restrict__ M, const float* __restrict__ yT,
                                            const float* __restrict__ d1, float* __restrict__ p2b) {
  int b = blockIdx.y, n = blockIdx.x;
  const float* row = M + (size_t)b * NN * NN + (size_t)n * NN;
  const float* Y = yT + (size_t)b * CC * NN;
  __shared__ float ys[CC][256];
  __shared__ float part[CC][4];
  int t = threadIdx.x;
  float acc[CC] = {};
  for (int m0 = 0; m0 < NN; m0 += 256) {
#pragma unroll
    for (int c = 0; c < CC; ++c) ys[c][t] = Y[(size_t)c * NN + m0 + t];
    __syncthreads();
    float a = row[m0 + t];
#pragma unroll
    for (int c = 0; c < CC; ++c) acc[c] += a * ys[c][t];
    __syncthreads();
  }
  int wid = t >> 6, lane = t & 63;
#pragma unroll
  for (int c = 0; c < CC; ++c) {
    float v = acc[c];
    for (int off = 32; off > 0; off >>= 1) v += __shfl_down(v, off);
    if (lane == 0) part[c][wid] = v;
  }
  __syncthreads();
  if (t < CC) {
    float s = part[t][0] + part[t][1] + part[t][2] + part[t][3];
    p2b[((size_t)b * NN + n) * CC + t] = d1[b * NN + n] * s;
  }
}

// ---------------------------------------------------------------------------
// K9: fused blend + 19x19 conv x2 -> pred_out, then softmax + cosine-normalize
// ---------------------------------------------------------------------------
__global__ __launch_bounds__(256) void k_pred_head(const float* __restrict__ pred,
    const float* __restrict__ p2b, const float* __restrict__ maskb,
    const float* __restrict__ w1, const float* __restrict__ b1,
    const float* __restrict__ w2, const float* __restrict__ b2,
    float* __restrict__ out, float* __restrict__ spnT) {
  __shared__ float sw1[CC * CC], sw2[CC * CC], sb1[CC], sb2[CC];
  int t = threadIdx.x;
  for (int i = t; i < CC * CC; i += 256) { sw1[i] = w1[i]; sw2[i] = w2[i]; }
  if (t < CC) { sb1[t] = b1[t]; sb2[t] = b2[t]; }
  __syncthreads();
  int g = blockIdx.x * 256 + t;
  int b = g >> 12, n = g & (NN - 1);
  float m = maskb[g];
  float ca = (m > 0.5f) ? 0.2f : 0.8f;   // coefficient on p2
  float cb = (m > 0.5f) ? 0.8f : 0.2f;   // coefficient on pred
  const float* P = pred + (size_t)b * CC * NN + n;
  const float* Q = p2b + (size_t)g * CC;
  float p3[CC];
#pragma unroll
  for (int c = 0; c < CC; ++c) p3[c] = ca * Q[c] + cb * P[(size_t)c * NN];
  float midv[CC];
#pragma unroll
  for (int o = 0; o < CC; ++o) {
    float s = sb1[o];
#pragma unroll
    for (int c = 0; c < CC; ++c) s += sw1[o * CC + c] * p3[c];
    midv[o] = s;
  }
  float ov[CC];
  float mx = -1e30f;
#pragma unroll
  for (int o = 0; o < CC; ++o) {
    float s = sb2[o];
#pragma unroll
    for (int c = 0; c < CC; ++c) s += sw2[o * CC + c] * midv[c];
    ov[o] = s;
    out[(size_t)b * CC * NN + (size_t)o * NN + n] = s;
    mx = fmaxf(mx, s);
  }
  float se = 0.f;
  float e[CC];
#pragma unroll
  for (int o = 0; o < CC; ++o) { e[o] = expf(ov[o] - mx); se += e[o]; }
  float inv = 1.f / se;
  float nrm = 0.f;
#pragma unroll
  for (int o = 0; o < CC; ++o) { float sp = e[o] * inv; e[o] = sp; nrm += sp * sp; }
  float rn = 1.f / (sqrtf(nrm) + 1e-9f);
#pragma unroll
  for (int o = 0; o < CC; ++o) spnT[(size_t)b * CC * NN + (size_t)o * NN + n] = e[o] * rn;
}

// ---------------------------------------------------------------------------
// K10: aff_f = bitmask ? clamp(Gram(spn),0) : 0   (K=19), symmetric write
// ---------------------------------------------------------------------------
__global__ __launch_bounds__(256) void k_gram2(const float* __restrict__ spnT,
    const unsigned int* __restrict__ bits, float* __restrict__ M) {
  int b = blockIdx.z, I = blockIdx.y, J = blockIdx.x;
  if (I > J) return;
  const float* X = spnT + (size_t)b * CC * NN;
  float* Mb = M + (size_t)b * NN * NN;
  __shared__ float sA[CC][64], sB[CC][64];
  __shared__ unsigned int bI[64], bJ[64];
  __shared__ float tr[64][65];
  int t = threadIdx.x;
  int r = t >> 4, c = t & 15;
  int i0 = I * 64, j0 = J * 64;
  for (int e = t; e < CC * 64; e += 256) {
    int k = e >> 6, col = e & 63;
    sA[k][col] = X[(size_t)k * NN + i0 + col];
    sB[k][col] = X[(size_t)k * NN + j0 + col];
  }
  if (t < 64) bI[t] = bits[b * NN + i0 + t];
  else if (t < 128) bJ[t - 64] = bits[b * NN + j0 + t - 64];
  __syncthreads();
  float acc[4][4] = {};
#pragma unroll
  for (int k = 0; k < CC; ++k) {
    float av[4], bv[4];
#pragma unroll
    for (int i = 0; i < 4; ++i) av[i] = sA[k][r * 4 + i];
#pragma unroll
    for (int j = 0; j < 4; ++j) bv[j] = sB[k][c * 4 + j];
#pragma unroll
    for (int i = 0; i < 4; ++i) {
#pragma unroll
      for (int j = 0; j < 4; ++j) acc[i][j] += av[i] * bv[j];
    }
  }
#pragma unroll
  for (int i = 0; i < 4; ++i) {
#pragma unroll
    for (int j = 0; j < 4; ++j) {
      bool keep = (bI[r * 4 + i] & bJ[c * 4 + j]) != 0u;
      acc[i][j] = keep ? fmaxf(acc[i][j], 0.f) : 0.f;
    }
    float4 v = make_float4(acc[i][0], acc[i][1], acc[i][2], acc[i][3]);
    *reinterpret_cast<float4*>(&Mb[(size_t)(i0 + r * 4 + i) * NN + j0 + c * 4]) = v;
  }
  if (I != J) {
#pragma unroll
    for (int i = 0; i < 4; ++i) {
#pragma unroll
      for (int j = 0; j < 4; ++j) tr[r * 4 + i][c * 4 + j] = acc[i][j];
    }
    __syncthreads();
#pragma unroll
    for (int e = 0; e < 16; ++e) {
      int lin = t + e * 256;
      int jr = lin >> 6, ic = lin & 63;
      Mb[(size_t)(j0 + jr) * NN + i0 + ic] = tr[ic][jr];
    }
  }
}

// ---------------------------------------------------------------------------
// K11: d2[n] = (row_sum(F) + 1e-10)^-0.5
// ---------------------------------------------------------------------------
__global__ __launch_bounds__(256) void k_rowsum2(const float* __restrict__ M, float* __restrict__ d2) {
  int b = blockIdx.y, n = blockIdx.x;
  const float* row = M + (size_t)b * NN * NN + (size_t)n * NN;
  int t = threadIdx.x;
  float s = 0.f;
  for (int m = t; m < NN; m += 256) s += row[m];
  for (int off = 32; off > 0; off >>= 1) s += __shfl_down(s, off);
  __shared__ float p4[4];
  int wid = t >> 6, lane = t & 63;
  if (lane == 0) p4[wid] = s;
  __syncthreads();
  if (t == 0) d2[b * NN + n] = 1.f / sqrtf(p4[0] + p4[1] + p4[2] + p4[3] + 1e-10f);
}

// ---------------------------------------------------------------------------
// K12: new_feat[b][n][d] = d2[n] * sum_m F[n][m] * d2[m] * feat[b][d][m]
// ---------------------------------------------------------------------------
__global__ __launch_bounds__(256) void k_newfeat(const float* __restrict__ M, const float* __restrict__ feat,
    const float* __restrict__ d2, float* __restrict__ nf) {
  int b = blockIdx.z;
  int n0 = blockIdx.y * 64;
  int d0 = blockIdx.x * 64;
  const float* Mb = M + (size_t)b * NN * NN;
  const float* F = feat + (size_t)b * DD * NN;
  const float* dd = d2 + b * NN;
  __shared__ float sF[64 * 17];
  __shared__ float sZ[16 * 68];
  int t = threadIdx.x;
  int r = t >> 4, c = t & 15;
  float acc[4][4] = {};
  for (int m0 = 0; m0 < NN; m0 += 16) {
    int k = t & 15;
    int base = t >> 4;
#pragma unroll
    for (int e = 0; e < 4; ++e) {
      int rr = base + e * 16;
      sF[rr * 17 + k] = Mb[(size_t)(n0 + rr) * NN + m0 + k];
      sZ[k * 68 + rr] = F[(size_t)(d0 + rr) * NN + m0 + k] * dd[m0 + k];
    }
    __syncthreads();
#pragma unroll
    for (int kk = 0; kk < 16; ++kk) {
      float av[4], bv[4];
#pragma unroll
      for (int i = 0; i < 4; ++i) av[i] = sF[(r * 4 + i) * 17 + kk];
#pragma unroll
      for (int j = 0; j < 4; ++j) bv[j] = sZ[kk * 68 + c * 4 + j];
#pragma unroll
      for (int i = 0; i < 4; ++i) {
#pragma unroll
        for (int j = 0; j < 4; ++j) acc[i][j] += av[i] * bv[j];
      }
    }
    __syncthreads();
  }
#pragma unroll
  for (int i = 0; i < 4; ++i) {
    float sc = dd[n0 + r * 4 + i];
    float4 v = make_float4(acc[i][0] * sc, acc[i][1] * sc, acc[i][2] * sc, acc[i][3] * sc);
    *reinterpret_cast<float4*>(&nf[((size_t)b * NN + n0 + r * 4 + i) * DD + d0 + c * 4]) = v;
  }
}

// ---------------------------------------------------------------------------
// K13: mid[b][o][n] = relu(w1 @ nf^T + b1)   (B operand transposed from nf[n][d])
// ---------------------------------------------------------------------------
__global__ __launch_bounds__(256) void k_conv1(const float* __restrict__ w1, const float* __restrict__ b1,
                                               const float* __restrict__ nf, float* __restrict__ mid) {
  int b = blockIdx.z;
  int o0 = blockIdx.y * 64;
  int n0 = blockIdx.x * 64;
  __shared__ float sW[64 * 17];
  __shared__ float sN[16 * 68];
  int t = threadIdx.x;
  int r = t >> 4, c = t & 15;
  float acc[4][4] = {};
  for (int d0 = 0; d0 < DD; d0 += 16) {
    int k = t & 15;
    int base = t >> 4;
#pragma unroll
    for (int e = 0; e < 4; ++e) {
      int rr = base + e * 16;
      sW[rr * 17 + k] = w1[(size_t)(o0 + rr) * DD + d0 + k];
      sN[k * 68 + rr] = nf[((size_t)b * NN + n0 + rr) * DD + d0 + k];
    }
    __syncthreads();
#pragma unroll
    for (int kk = 0; kk < 16; ++kk) {
      float av[4], bv[4];
#pragma unroll
      for (int i = 0; i < 4; ++i) av[i] = sW[(r * 4 + i) * 17 + kk];
#pragma unroll
      for (int j = 0; j < 4; ++j) bv[j] = sN[kk * 68 + c * 4 + j];
#pragma unroll
      for (int i = 0; i < 4; ++i) {
#pragma unroll
        for (int j = 0; j < 4; ++j) acc[i][j] += av[i] * bv[j];
      }
    }
    __syncthreads();
  }
#pragma unroll
  for (int i = 0; i < 4; ++i) {
    float bias = b1[o0 + r * 4 + i];
    float4 v;
    v.x = fmaxf(acc[i][0] + bias, 0.f);
    v.y = fmaxf(acc[i][1] + bias, 0.f);
    v.z = fmaxf(acc[i][2] + bias, 0.f);
    v.w = fmaxf(acc[i][3] + bias, 0.f);
    *reinterpret_cast<float4*>(&mid[((size_t)b * DD + o0 + r * 4 + i) * NN + n0 + c * 4]) = v;
  }
}

// ---------------------------------------------------------------------------
// K14: feat_out[b][o][n] = w2 @ mid + b2   (B operand natural layout [c][n])
// ---------------------------------------------------------------------------
__global__ __launch_bounds__(256) void k_conv2(const float* __restrict__ w2, const float* __restrict__ b2,
                                               const float* __restrict__ mid, float* __restrict__ outp) {
  int b = blockIdx.z;
  int o0 = blockIdx.y * 64;
  int n0 = blockIdx.x * 64;
  __shared__ float sW[64 * 17];
  __shared__ float sM[16 * 64];
  int t = threadIdx.x;
  int r = t >> 4, c = t & 15;
  float acc[4][4] = {};
  for (int d0 = 0; d0 < DD; d0 += 16) {
    {
      int k = t & 15;
      int base = t >> 4;
#pragma unroll
      for (int e = 0; e < 4; ++e) {
        int rr = base + e * 16;
        sW[rr * 17 + k] = w2[(size_t)(o0 + rr) * DD + d0 + k];
      }
      int k2 = t >> 6;
      int nl = t & 63;
#pragma unroll
      for (int e = 0; e < 4; ++e) {
        sM[(k2 + e * 4) * 64 + nl] = mid[((size_t)b * DD + d0 + k2 + e * 4) * NN + n0 + nl];
      }
    }
    __syncthreads();
#pragma unroll
    for (int kk = 0; kk < 16; ++kk) {
      float av[4], bv[4];
#pragma unroll
      for (int i = 0; i < 4; ++i) av[i] = sW[(r * 4 + i) * 17 + kk];
#pragma unroll
      for (int j = 0; j < 4; ++j) bv[j] = sM[kk * 64 + c * 4 + j];
#pragma unroll
      for (int i = 0; i < 4; ++i) {
#pragma unroll
        for (int j = 0; j < 4; ++j) acc[i][j] += av[i] * bv[j];
      }
    }
    __syncthreads();
  }
#pragma unroll
  for (int i = 0; i < 4; ++i) {
    float bias = b2[o0 + r * 4 + i];
    float4 v = make_float4(acc[i][0] + bias, acc[i][1] + bias, acc[i][2] + bias, acc[i][3] + bias);
    *reinterpret_cast<float4*>(&outp[((size_t)b * DD + o0 + r * 4 + i) * NN + n0 + c * 4]) = v;
  }
}

// ---------------------------------------------------------------------------
extern "C" void kernel_launch(void* const* d_in, const int* in_sizes, int n_in,
                              void* d_out, int out_size, void* d_ws, size_t ws_size,
                              hipStream_t stream) {
  (void)in_sizes; (void)n_in; (void)out_size; (void)ws_size;
  const float* pred   = (const float*)d_in[0];
  const float* feat   = (const float*)d_in[1];
  const float* w_cls1 = (const float*)d_in[2];
  const float* b_cls1 = (const float*)d_in[3];
  const float* w_cls2 = (const float*)d_in[4];
  const float* b_cls2 = (const float*)d_in[5];
  const float* w_pro1 = (const float*)d_in[6];
  const float* b_pro1 = (const float*)d_in[7];
  const float* w_pro2 = (const float*)d_in[8];
  const float* b_pro2 = (const float*)d_in[9];
  const float* cw     = (const float*)d_in[10];
  float* out = (float*)d_out;

  // workspace layout (floats); ~154 MB total
  float* Mbuf = (float*)d_ws;                               // B*N*N (reused: aff1 -> As -> aff_f)
  float* xnT  = Mbuf + (size_t)BB * NN * NN;                // B*D*N normalized feat (transposed)
  float* nf   = xnT + (size_t)BB * DD * NN;                 // B*N*D new_feat
  float* mid  = nf + (size_t)BB * NN * DD;                  // B*D*N conv1 output
  float* spnT = mid + (size_t)BB * DD * NN;                 // B*C*N normalized softmax
  float* yT   = spnT + (size_t)BB * CC * NN;                // B*C*N d1*pred
  float* p2b  = yT + (size_t)BB * CC * NN;                  // B*N*C propagated preds
  float* thr  = p2b + (size_t)BB * NN * CC;                 // B*N top-21 threshold
  float* dsum = thr + BB * NN;                              // B*N degree (then d1^-1/2)
  float* d2s  = dsum + BB * NN;                             // B*N d2^-1/2
  float* maskb = d2s + BB * NN;                             // B*N confidence mask
  unsigned int* ohbits = (unsigned int*)(maskb + BB * NN);  // B*N one-hot bitmasks

  hipMemsetAsync(dsum, 0, sizeof(float) * BB * NN, stream);
  hipMemsetAsync(ohbits, 0, sizeof(unsigned int) * BB * NN, stream);

  dim3 gt(64, 64, BB);
  k_mask_bits<<<BB * NN / 256, 256, 0, stream>>>(pred, cw, maskb, ohbits);
  k_norm_feat<<<BB * NN / 64, 64, 0, stream>>>(feat, xnT);
  k_gram1<<<gt, 256, 0, stream>>>(xnT, Mbuf);
  k_topk<<<dim3(NN, BB), 256, 0, stream>>>(Mbuf, thr);
  k_symm<<<gt, 256, 0, stream>>>(Mbuf, thr, dsum);
  k_fin_d<<<BB * NN / 256, 256, 0, stream>>>(dsum);
  k_make_y<<<(BB * CC * NN + 255) / 256, 256, 0, stream>>>(pred, dsum, yT);
  k_p2<<<dim3(NN, BB), 256, 0, stream>>>(Mbuf, yT, dsum, p2b);
  k_pred_head<<<BB * NN / 256, 256, 0, stream>>>(pred, p2b, maskb, w_cls1, b_cls1,
                                                 w_cls2, b_cls2, out, spnT);
  k_gram2<<<gt, 256, 0, stream>>>(spnT, ohbits, Mbuf);
  k_rowsum2<<<dim3(NN, BB), 256, 0, stream>>>(Mbuf, d2s);
  k_newfeat<<<dim3(4, 64, BB), 256, 0, stream>>>(Mbuf, feat, d2s, nf);
  k_conv1<<<dim3(64, 4, BB), 256, 0, stream>>>(w_pro1, b_pro1, nf, mid);
  k_conv2<<<dim3(64, 4, BB), 256, 0, stream>>>(w_pro2, b_pro2, mid,
                                               out + (size_t)BB * CC * NN);
}

// Round 3
// 785.495 us; speedup vs baseline: 1.3116x; 1.3116x over previous
//
#include <hip/hip_runtime.h>

#define NN 4096   // H*W
#define DD 256    // feature channels
#define CC 19     // classes
#define BB 2      // batch

typedef __attribute__((ext_vector_type(8))) short bf16x8;   // MFMA A/B frag (4 VGPRs)
typedef __attribute__((ext_vector_type(4))) float f32x4;    // MFMA C/D frag

__device__ inline unsigned short f2b(float f) {   // fp32 -> bf16 RNE
  unsigned int u = __float_as_uint(f);
  return (unsigned short)((u + 0x7FFFu + ((u >> 16) & 1u)) >> 16);
}

// ---------------------------------------------------------------------------
// K1: softmax confidence mask + scrambled one-hot bitmasks
// ---------------------------------------------------------------------------
__global__ void k_mask_bits(const float* __restrict__ pred, const float* __restrict__ cw,
                            float* __restrict__ maskb, unsigned int* __restrict__ ohbits) {
  int g = blockIdx.x * 256 + threadIdx.x;
  if (g >= BB * NN) return;
  int b = g >> 12, n = g & (NN - 1);
  const float* p = pred + (size_t)b * CC * NN + n;
  float v[CC];
  float mx = -1e30f; int am = 0;
#pragma unroll
  for (int c = 0; c < CC; ++c) {
    float t = p[(size_t)c * NN];
    v[c] = t;
    if (t > mx) { mx = t; am = c; }
  }
  float s = 0.f;
#pragma unroll
  for (int c = 0; c < CC; ++c) s += expf(v[c] - mx);
  float pprob = 1.f / s;
  float cmax = 0.f;
#pragma unroll
  for (int c = 0; c < CC; ++c) cmax = fmaxf(cmax, cw[c]);
  float cwm = cw[am] / (cmax + 1e-10f) * 0.95f;
  maskb[g] = (pprob >= 0.95f || pprob >= cwm) ? 1.f : 0.f;
  // one_hot [B,H,W,C] -> transpose(0,2,3,1) -> [B,W,C,H] -> reshape(B,-1,19)
  int h = n >> 6, w = n & 63;
  int L = w * (CC * 64) + am * 64 + h;     // flat index in [W,C,H]
  atomicOr(&ohbits[b * NN + L / CC], 1u << (L % CC));
}

// ---------------------------------------------------------------------------
// K2: row-normalize features, stored transposed xnT[b][d][n]
// ---------------------------------------------------------------------------
__global__ void k_norm_feat(const float* __restrict__ feat, float* __restrict__ xnT) {
  int g = blockIdx.x * 64 + threadIdx.x;
  int b = g >> 12, n = g & (NN - 1);
  const float* f = feat + (size_t)b * DD * NN + n;
  float s = 0.f;
  for (int d = 0; d < DD; ++d) { float t = f[(size_t)d * NN]; s += t * t; }
  float r = 1.f / (sqrtf(s) + 1e-9f);
  float* o = xnT + (size_t)b * DD * NN + n;
  for (int d = 0; d < DD; ++d) o[(size_t)d * NN] = f[(size_t)d * NN] * r;
}

// ---------------------------------------------------------------------------
// K3: aff1 = clamp(Gram(xn), 0).  Symmetric: block (I<=J) writes both tiles.
// (fp32 VALU — feeds discrete top-21 threshold; bf16 would flip edges)
// ---------------------------------------------------------------------------
__global__ __launch_bounds__(256) void k_gram1(const float* __restrict__ xnT, float* __restrict__ M) {
  int b = blockIdx.z, I = blockIdx.y, J = blockIdx.x;
  if (I > J) return;
  const float* X = xnT + (size_t)b * DD * NN;
  float* Mb = M + (size_t)b * NN * NN;
  __shared__ float sA[16][64];
  __shared__ float sB[16][64];
  __shared__ float tr[64][65];
  int t = threadIdx.x;
  int r = t >> 4, c = t & 15;
  int i0 = I * 64, j0 = J * 64;
  float acc[4][4] = {};
  for (int k0 = 0; k0 < DD; k0 += 16) {
    int lk = t >> 6, lcol = t & 63;
#pragma unroll
    for (int e = 0; e < 4; ++e) {
      const float* src = X + (size_t)(k0 + lk + e * 4) * NN;
      sA[lk + e * 4][lcol] = src[i0 + lcol];
      sB[lk + e * 4][lcol] = src[j0 + lcol];
    }
    __syncthreads();
#pragma unroll
    for (int k = 0; k < 16; ++k) {
      float av[4], bv[4];
#pragma unroll
      for (int i = 0; i < 4; ++i) av[i] = sA[k][r * 4 + i];
#pragma unroll
      for (int j = 0; j < 4; ++j) bv[j] = sB[k][c * 4 + j];
#pragma unroll
      for (int i = 0; i < 4; ++i) {
#pragma unroll
        for (int j = 0; j < 4; ++j) acc[i][j] += av[i] * bv[j];
      }
    }
    __syncthreads();
  }
#pragma unroll
  for (int i = 0; i < 4; ++i) {
#pragma unroll
    for (int j = 0; j < 4; ++j) acc[i][j] = fmaxf(acc[i][j], 0.f);
    float4 v = make_float4(acc[i][0], acc[i][1], acc[i][2], acc[i][3]);
    *reinterpret_cast<float4*>(&Mb[(size_t)(i0 + r * 4 + i) * NN + j0 + c * 4]) = v;
  }
  if (I != J) {
#pragma unroll
    for (int i = 0; i < 4; ++i) {
#pragma unroll
      for (int j = 0; j < 4; ++j) tr[r * 4 + i][c * 4 + j] = acc[i][j];
    }
    __syncthreads();
#pragma unroll
    for (int e = 0; e < 16; ++e) {
      int lin = t + e * 256;
      int jr = lin >> 6, ic = lin & 63;
      Mb[(size_t)(j0 + jr) * NN + i0 + ic] = tr[ic][jr];
    }
  }
}

// ---------------------------------------------------------------------------
// K4: per-row 21st-largest value (extract-max x21 on LDS copy)
// ---------------------------------------------------------------------------
__global__ __launch_bounds__(256) void k_topk(const float* __restrict__ M, float* __restrict__ thr) {
  int b = blockIdx.y, n = blockIdx.x;
  const float* row = M + (size_t)b * NN * NN + (size_t)n * NN;
  __shared__ float vals[NN];
  __shared__ float wrv[4];
  __shared__ int wri[4];
  int t = threadIdx.x;
  int wid = t >> 6, lane = t & 63;
  for (int i = t; i < NN; i += 256) vals[i] = row[i];
  __syncthreads();
  float last = 0.f;
  for (int it = 0; it < 21; ++it) {
    float bv = -2.f; int bi = 0;
#pragma unroll
    for (int e = 0; e < 16; ++e) {
      int idx = t + e * 256;
      float v = vals[idx];
      if (v > bv) { bv = v; bi = idx; }
    }
    for (int off = 32; off > 0; off >>= 1) {
      float ov = __shfl_down(bv, off);
      int oi = __shfl_down(bi, off);
      if (ov > bv || (ov == bv && oi < bi)) { bv = ov; bi = oi; }
    }
    if (lane == 0) { wrv[wid] = bv; wri[wid] = bi; }
    __syncthreads();
    if (t == 0) {
      float fv = wrv[0]; int fi = wri[0];
#pragma unroll
      for (int w = 1; w < 4; ++w) {
        if (wrv[w] > fv || (wrv[w] == fv && wri[w] < fi)) { fv = wrv[w]; fi = wri[w]; }
      }
      vals[fi] = -1.f;
      last = fv;
    }
    __syncthreads();
  }
  if (t == 0) thr[b * NN + n] = last;
}

// ---------------------------------------------------------------------------
// K5: in-place sparsify + symmetrize  As = S + S^T, plus degree partial sums
// ---------------------------------------------------------------------------
__global__ __launch_bounds__(256) void k_symm(float* __restrict__ M, const float* __restrict__ thr,
                                              float* __restrict__ dsum) {
  int b = blockIdx.z, I = blockIdx.y, J = blockIdx.x;
  if (I > J) return;
  float* Mb = M + (size_t)b * NN * NN;
  const float* th = thr + b * NN;
  __shared__ float A[64][65];
  __shared__ float Bt[64][65];
  int t = threadIdx.x;
  int i0 = I * 64, j0 = J * 64;
  float areg[16];
#pragma unroll
  for (int e = 0; e < 16; ++e) {
    int lin = t + e * 256;
    int i = lin >> 6, j = lin & 63;
    areg[e] = Mb[(size_t)(i0 + i) * NN + j0 + j];
    Bt[i][j] = Mb[(size_t)(j0 + i) * NN + i0 + j];
  }
  __syncthreads();
#pragma unroll
  for (int e = 0; e < 16; ++e) {
    int lin = t + e * 256;
    int i = lin >> 6, j = lin & 63;
    float a = areg[e];
    float sa = (a >= th[i0 + i]) ? a : 0.f;
    float bt = Bt[j][i];
    float sb = (bt >= th[j0 + j]) ? bt : 0.f;
    float v = sa + sb;
    A[i][j] = v;
    Mb[(size_t)(i0 + i) * NN + j0 + j] = v;
  }
  __syncthreads();
  if (I != J) {
#pragma unroll
    for (int e = 0; e < 16; ++e) {
      int lin = t + e * 256;
      int j = lin >> 6, i = lin & 63;
      Mb[(size_t)(j0 + j) * NN + i0 + i] = A[i][j];
    }
  }
  if (t < 64) {
    float s = 0.f;
#pragma unroll
    for (int j = 0; j < 64; ++j) s += A[t][j];
    atomicAdd(&dsum[b * NN + i0 + t], s);
  } else if (t < 128 && I != J) {
    int j = t - 64;
    float s = 0.f;
#pragma unroll
    for (int i = 0; i < 64; ++i) s += A[i][j];
    atomicAdd(&dsum[b * NN + j0 + j], s);
  }
}

// ---------------------------------------------------------------------------
// K6: d = (d + 1e-10)^-0.5
// ---------------------------------------------------------------------------
__global__ void k_fin_d(float* __restrict__ d) {
  int g = blockIdx.x * 256 + threadIdx.x;
  if (g < BB * NN) d[g] = 1.f / sqrtf(d[g] + 1e-10f);
}

// ---------------------------------------------------------------------------
// K7: yT[b][c][n] = d1n[b][n] * pred[b][c][n]
// ---------------------------------------------------------------------------
__global__ void k_make_y(const float* __restrict__ pred, const float* __restrict__ d1,
                         float* __restrict__ yT) {
  int g = blockIdx.x * 256 + threadIdx.x;
  if (g >= BB * CC * NN) return;
  int b = g / (CC * NN);
  int n = g & (NN - 1);
  yT[g] = pred[g] * d1[b * NN + n];
}

// ---------------------------------------------------------------------------
// K8: p2[b][n][c] = d1n[n] * sum_m As[n][m] * yT[c][m]
// ---------------------------------------------------------------------------
__global__ __launch_bounds__(256) void k_p2(const float* __restrict__ M, const float* __restrict__ yT,
                                            const float* __restrict__ d1, float* __restrict__ p2b) {
  int b = blockIdx.y, n = blockIdx.x;
  const float* row = M + (size_t)b * NN * NN + (size_t)n * NN;
  const float* Y = yT + (size_t)b * CC * NN;
  __shared__ float ys[CC][256];
  __shared__ float part[CC][4];
  int t = threadIdx.x;
  float acc[CC] = {};
  for (int m0 = 0; m0 < NN; m0 += 256) {
#pragma unroll
    for (int c = 0; c < CC; ++c) ys[c][t] = Y[(size_t)c * NN + m0 + t];
    __syncthreads();
    float a = row[m0 + t];
#pragma unroll
    for (int c = 0; c < CC; ++c) acc[c] += a * ys[c][t];
    __syncthreads();
  }
  int wid = t >> 6, lane = t & 63;
#pragma unroll
  for (int c = 0; c < CC; ++c) {
    float v = acc[c];
    for (int off = 32; off > 0; off >>= 1) v += __shfl_down(v, off);
    if (lane == 0) part[c][wid] = v;
  }
  __syncthreads();
  if (t < CC) {
    float s = part[t][0] + part[t][1] + part[t][2] + part[t][3];
    p2b[((size_t)b * NN + n) * CC + t] = d1[b * NN + n] * s;
  }
}

// ---------------------------------------------------------------------------
// K9: fused blend + 19x19 conv x2 -> pred_out, then softmax + cosine-normalize
// ---------------------------------------------------------------------------
__global__ __launch_bounds__(256) void k_pred_head(const float* __restrict__ pred,
    const float* __restrict__ p2b, const float* __restrict__ maskb,
    const float* __restrict__ w1, const float* __restrict__ b1,
    const float* __restrict__ w2, const float* __restrict__ b2,
    float* __restrict__ out, float* __restrict__ spnT) {
  __shared__ float sw1[CC * CC], sw2[CC * CC], sb1[CC], sb2[CC];
  int t = threadIdx.x;
  for (int i = t; i < CC * CC; i += 256) { sw1[i] = w1[i]; sw2[i] = w2[i]; }
  if (t < CC) { sb1[t] = b1[t]; sb2[t] = b2[t]; }
  __syncthreads();
  int g = blockIdx.x * 256 + t;
  int b = g >> 12, n = g & (NN - 1);
  float m = maskb[g];
  float ca = (m > 0.5f) ? 0.2f : 0.8f;
  float cb = (m > 0.5f) ? 0.8f : 0.2f;
  const float* P = pred + (size_t)b * CC * NN + n;
  const float* Q = p2b + (size_t)g * CC;
  float p3[CC];
#pragma unroll
  for (int c = 0; c < CC; ++c) p3[c] = ca * Q[c] + cb * P[(size_t)c * NN];
  float midv[CC];
#pragma unroll
  for (int o = 0; o < CC; ++o) {
    float s = sb1[o];
#pragma unroll
    for (int c = 0; c < CC; ++c) s += sw1[o * CC + c] * p3[c];
    midv[o] = s;
  }
  float ov[CC];
  float mx = -1e30f;
#pragma unroll
  for (int o = 0; o < CC; ++o) {
    float s = sb2[o];
#pragma unroll
    for (int c = 0; c < CC; ++c) s += sw2[o * CC + c] * midv[c];
    ov[o] = s;
    out[(size_t)b * CC * NN + (size_t)o * NN + n] = s;
    mx = fmaxf(mx, s);
  }
  float se = 0.f;
  float e[CC];
#pragma unroll
  for (int o = 0; o < CC; ++o) { e[o] = expf(ov[o] - mx); se += e[o]; }
  float inv = 1.f / se;
  float nrm = 0.f;
#pragma unroll
  for (int o = 0; o < CC; ++o) { float sp = e[o] * inv; e[o] = sp; nrm += sp * sp; }
  float rn = 1.f / (sqrtf(nrm) + 1e-9f);
#pragma unroll
  for (int o = 0; o < CC; ++o) spnT[(size_t)b * CC * NN + (size_t)o * NN + n] = e[o] * rn;
}

// ---------------------------------------------------------------------------
// K10: aff_f = bitmask ? clamp(Gram(spn),0) : 0   (K=19), writes bf16
// ---------------------------------------------------------------------------
__global__ __launch_bounds__(256) void k_gram2(const float* __restrict__ spnT,
    const unsigned int* __restrict__ bits, unsigned short* __restrict__ Mh) {
  int b = blockIdx.z, I = blockIdx.y, J = blockIdx.x;
  if (I > J) return;
  const float* X = spnT + (size_t)b * CC * NN;
  unsigned short* Mb = Mh + (size_t)b * NN * NN;
  __shared__ float sA[CC][64], sB[CC][64];
  __shared__ unsigned int bI[64], bJ[64];
  __shared__ float tr[64][65];
  int t = threadIdx.x;
  int r = t >> 4, c = t & 15;
  int i0 = I * 64, j0 = J * 64;
  for (int e = t; e < CC * 64; e += 256) {
    int k = e >> 6, col = e & 63;
    sA[k][col] = X[(size_t)k * NN + i0 + col];
    sB[k][col] = X[(size_t)k * NN + j0 + col];
  }
  if (t < 64) bI[t] = bits[b * NN + i0 + t];
  else if (t < 128) bJ[t - 64] = bits[b * NN + j0 + t - 64];
  __syncthreads();
  float acc[4][4] = {};
#pragma unroll
  for (int k = 0; k < CC; ++k) {
    float av[4], bv[4];
#pragma unroll
    for (int i = 0; i < 4; ++i) av[i] = sA[k][r * 4 + i];
#pragma unroll
    for (int j = 0; j < 4; ++j) bv[j] = sB[k][c * 4 + j];
#pragma unroll
    for (int i = 0; i < 4; ++i) {
#pragma unroll
      for (int j = 0; j < 4; ++j) acc[i][j] += av[i] * bv[j];
    }
  }
#pragma unroll
  for (int i = 0; i < 4; ++i) {
#pragma unroll
    for (int j = 0; j < 4; ++j) {
      bool keep = (bI[r * 4 + i] & bJ[c * 4 + j]) != 0u;
      acc[i][j] = keep ? fmaxf(acc[i][j], 0.f) : 0.f;
    }
    ushort4 v;
    v.x = f2b(acc[i][0]); v.y = f2b(acc[i][1]); v.z = f2b(acc[i][2]); v.w = f2b(acc[i][3]);
    *reinterpret_cast<ushort4*>(&Mb[(size_t)(i0 + r * 4 + i) * NN + j0 + c * 4]) = v;
  }
  if (I != J) {
#pragma unroll
    for (int i = 0; i < 4; ++i) {
#pragma unroll
      for (int j = 0; j < 4; ++j) tr[r * 4 + i][c * 4 + j] = acc[i][j];
    }
    __syncthreads();
#pragma unroll
    for (int e = 0; e < 16; ++e) {
      int lin = t + e * 256;
      int jr = lin >> 6, ic = lin & 63;
      Mb[(size_t)(j0 + jr) * NN + i0 + ic] = f2b(tr[ic][jr]);
    }
  }
}

// ---------------------------------------------------------------------------
// K11: d2[n] = (row_sum(aff_f bf16) + 1e-10)^-0.5
// ---------------------------------------------------------------------------
__global__ __launch_bounds__(256) void k_rowsum2h(const unsigned short* __restrict__ Mh,
                                                  float* __restrict__ d2) {
  int b = blockIdx.y, n = blockIdx.x;
  const unsigned short* row = Mh + (size_t)b * NN * NN + (size_t)n * NN;
  int t = threadIdx.x;
  float s = 0.f;
#pragma unroll
  for (int i = 0; i < 8; ++i) {
    unsigned int u = *reinterpret_cast<const unsigned int*>(&row[(i * 256 + t) * 2]);
    s += __uint_as_float(u << 16) + __uint_as_float(u & 0xffff0000u);
  }
  for (int off = 32; off > 0; off >>= 1) s += __shfl_down(s, off);
  __shared__ float p4[4];
  int wid = t >> 6, lane = t & 63;
  if (lane == 0) p4[wid] = s;
  __syncthreads();
  if (t == 0) d2[b * NN + n] = 1.f / sqrtf(p4[0] + p4[1] + p4[2] + p4[3] + 1e-10f);
}

// ---------------------------------------------------------------------------
// K12a: zb[b][d][m] = bf16(feat[b][d][m] * d2[b][m])
// ---------------------------------------------------------------------------
__global__ void k_make_z(const float* __restrict__ feat, const float* __restrict__ d2,
                         unsigned short* __restrict__ zb) {
  int g = blockIdx.x * 256 + threadIdx.x;   // BB*DD*NN/4 threads
  int idx = g * 4;
  int b = idx / (DD * NN);
  int m = idx & (NN - 1);
  float4 f = *reinterpret_cast<const float4*>(&feat[idx]);
  const float* dd = d2 + b * NN + m;
  ushort4 o;
  o.x = f2b(f.x * dd[0]); o.y = f2b(f.y * dd[1]);
  o.z = f2b(f.z * dd[2]); o.w = f2b(f.w * dd[3]);
  *reinterpret_cast<ushort4*>(&zb[idx]) = o;
}

// K12b: convert projection weights to bf16
__global__ void k_prep_w(const float* __restrict__ w1, const float* __restrict__ w2,
                         unsigned short* __restrict__ wb1, unsigned short* __restrict__ wb2) {
  int g = blockIdx.x * 256 + threadIdx.x;   // DD*DD threads
  wb1[g] = f2b(w1[g]);
  wb2[g] = f2b(w2[g]);
}

// ---------------------------------------------------------------------------
// K13: new_feat via MFMA.  GEMM: M=d(64-tile), N=n(64-tile), K=m(4096).
//   A = zb[d][m] (bf16, k-major)   B = aff_f[n][m] (bf16, k-major)
//   D[row=d][col=n]; epilogue scales by d2[n]; nfh[b][n][d] bf16 (8B stores).
// ---------------------------------------------------------------------------
__global__ __launch_bounds__(256) void k_newfeat_mfma(
    const unsigned short* __restrict__ Mh, const unsigned short* __restrict__ zb,
    const float* __restrict__ d2, unsigned short* __restrict__ nfh) {
  int b = blockIdx.z;
  int nblk = blockIdx.x;   // 64
  int dblk = blockIdx.y;   // 4
  const unsigned short* A = zb + (size_t)b * DD * NN + (size_t)(dblk * 64) * NN;
  const unsigned short* Bm = Mh + (size_t)b * NN * NN + (size_t)(nblk * 64) * NN;
  __shared__ unsigned short As[64][72];
  __shared__ unsigned short Bs[64][72];
  int t = threadIdx.x;
  int wave = t >> 6, lane = t & 63;
  int wd = (wave & 1) * 32, wn = (wave >> 1) * 32;
  int lrow = lane & 15, quad = lane >> 4;
  f32x4 acc[2][2] = {{{0.f,0.f,0.f,0.f},{0.f,0.f,0.f,0.f}},{{0.f,0.f,0.f,0.f},{0.f,0.f,0.f,0.f}}};
  int sr = t >> 3, sc = (t & 7) * 8;     // sr: 0..31, two row-passes cover 64
  for (int m0 = 0; m0 < NN; m0 += 64) {
#pragma unroll
    for (int e = 0; e < 2; ++e) {
      int rr = sr + e * 32;
      *reinterpret_cast<int4*>(&As[rr][sc]) =
          *reinterpret_cast<const int4*>(&A[(size_t)rr * NN + m0 + sc]);
      *reinterpret_cast<int4*>(&Bs[rr][sc]) =
          *reinterpret_cast<const int4*>(&Bm[(size_t)rr * NN + m0 + sc]);
    }
    __syncthreads();
#pragma unroll
    for (int kc = 0; kc < 2; ++kc) {
      int ko = kc * 32 + quad * 8;
      bf16x8 af[2], bfr[2];
#pragma unroll
      for (int i = 0; i < 2; ++i) {
        af[i]  = *reinterpret_cast<const bf16x8*>(&As[wd + i * 16 + lrow][ko]);
        bfr[i] = *reinterpret_cast<const bf16x8*>(&Bs[wn + i * 16 + lrow][ko]);
      }
#pragma unroll
      for (int i = 0; i < 2; ++i)
#pragma unroll
        for (int j = 0; j < 2; ++j)
          acc[i][j] = __builtin_amdgcn_mfma_f32_16x16x32_bf16(af[i], bfr[j], acc[i][j], 0, 0, 0);
    }
    __syncthreads();
  }
#pragma unroll
  for (int j = 0; j < 2; ++j) {
    int n = nblk * 64 + wn + j * 16 + lrow;
    float sc2 = d2[b * NN + n];
#pragma unroll
    for (int i = 0; i < 2; ++i) {
      int d = dblk * 64 + wd + i * 16 + quad * 4;
      ushort4 v;
      v.x = f2b(acc[i][j].x * sc2); v.y = f2b(acc[i][j].y * sc2);
      v.z = f2b(acc[i][j].z * sc2); v.w = f2b(acc[i][j].w * sc2);
      *reinterpret_cast<ushort4*>(&nfh[((size_t)b * NN + n) * DD + d]) = v;
    }
  }
}

// ---------------------------------------------------------------------------
// K14: conv1 via MFMA. GEMM: M=n, N=o1, K=d.  A=nfh[n][d], B=wb1[o][d].
//   out midh[b][o][n] bf16 with relu+bias (8B stores).
// ---------------------------------------------------------------------------
__global__ __launch_bounds__(256) void k_conv1_mfma(
    const unsigned short* __restrict__ nfh, const unsigned short* __restrict__ wb1,
    const float* __restrict__ b1, unsigned short* __restrict__ midh) {
  int b = blockIdx.z;
  int nblk = blockIdx.x;   // 64
  int oblk = blockIdx.y;   // 4
  int n0 = nblk * 64, o0 = oblk * 64;
  __shared__ unsigned short As[64][72];   // nf tile [n][d]
  __shared__ unsigned short Bs[64][72];   // W1 tile [o][d]
  int t = threadIdx.x;
  int wave = t >> 6, lane = t & 63;
  int wn = (wave & 1) * 32, wo = (wave >> 1) * 32;
  int lrow = lane & 15, quad = lane >> 4;
  f32x4 acc[2][2] = {{{0.f,0.f,0.f,0.f},{0.f,0.f,0.f,0.f}},{{0.f,0.f,0.f,0.f},{0.f,0.f,0.f,0.f}}};
  int sr = t >> 3, sc = (t & 7) * 8;
  for (int d0 = 0; d0 < DD; d0 += 64) {
#pragma unroll
    for (int e = 0; e < 2; ++e) {
      int rr = sr + e * 32;
      *reinterpret_cast<int4*>(&As[rr][sc]) =
          *reinterpret_cast<const int4*>(&nfh[((size_t)b * NN + n0 + rr) * DD + d0 + sc]);
      *reinterpret_cast<int4*>(&Bs[rr][sc]) =
          *reinterpret_cast<const int4*>(&wb1[(size_t)(o0 + rr) * DD + d0 + sc]);
    }
    __syncthreads();
#pragma unroll
    for (int kc = 0; kc < 2; ++kc) {
      int ko = kc * 32 + quad * 8;
      bf16x8 af[2], bfr[2];
#pragma unroll
      for (int i = 0; i < 2; ++i) {
        af[i]  = *reinterpret_cast<const bf16x8*>(&As[wn + i * 16 + lrow][ko]);
        bfr[i] = *reinterpret_cast<const bf16x8*>(&Bs[wo + i * 16 + lrow][ko]);
      }
#pragma unroll
      for (int i = 0; i < 2; ++i)
#pragma unroll
        for (int j = 0; j < 2; ++j)
          acc[i][j] = __builtin_amdgcn_mfma_f32_16x16x32_bf16(af[i], bfr[j], acc[i][j], 0, 0, 0);
    }
    __syncthreads();
  }
#pragma unroll
  for (int j = 0; j < 2; ++j) {
    int o = o0 + wo + j * 16 + lrow;
    float bias = b1[o];
#pragma unroll
    for (int i = 0; i < 2; ++i) {
      int nb = n0 + wn + i * 16 + quad * 4;
      ushort4 v;
      v.x = f2b(fmaxf(acc[i][j].x + bias, 0.f));
      v.y = f2b(fmaxf(acc[i][j].y + bias, 0.f));
      v.z = f2b(fmaxf(acc[i][j].z + bias, 0.f));
      v.w = f2b(fmaxf(acc[i][j].w + bias, 0.f));
      *reinterpret_cast<ushort4*>(&midh[((size_t)b * DD + o) * NN + nb]) = v;
    }
  }
}

// ---------------------------------------------------------------------------
// K15: conv2 via MFMA. GEMM: M=n, N=o2, K=o1.  A=midh[o1][n] (LDS transpose),
//   B=wb2[o2][o1].  out feat_out[b][o2][n] fp32 (float4 stores) + bias.
// ---------------------------------------------------------------------------
__global__ __launch_bounds__(256) void k_conv2_mfma(
    const unsigned short* __restrict__ midh, const unsigned short* __restrict__ wb2,
    const float* __restrict__ b2, float* __restrict__ outp) {
  int b = blockIdx.z;
  int nblk = blockIdx.x;   // 64
  int oblk = blockIdx.y;   // 4
  int n0 = nblk * 64, o0 = oblk * 64;
  __shared__ unsigned short As[64][72];   // mid^T tile [n][o1]
  __shared__ unsigned short Bs[64][72];   // W2 tile [o2][o1]
  int t = threadIdx.x;
  int wave = t >> 6, lane = t & 63;
  int wn = (wave & 1) * 32, wo = (wave >> 1) * 32;
  int lrow = lane & 15, quad = lane >> 4;
  f32x4 acc[2][2] = {{{0.f,0.f,0.f,0.f},{0.f,0.f,0.f,0.f}},{{0.f,0.f,0.f,0.f},{0.f,0.f,0.f,0.f}}};
  int sr = t >> 3, sc = (t & 7) * 8;
  for (int d0 = 0; d0 < DD; d0 += 64) {
#pragma unroll
    for (int e = 0; e < 2; ++e) {
      int rr = sr + e * 32;
      *reinterpret_cast<int4*>(&Bs[rr][sc]) =
          *reinterpret_cast<const int4*>(&wb2[(size_t)(o0 + rr) * DD + d0 + sc]);
      unsigned short v[8];
      *reinterpret_cast<int4*>(v) =
          *reinterpret_cast<const int4*>(&midh[((size_t)b * DD + d0 + rr) * NN + n0 + sc]);
#pragma unroll
      for (int j = 0; j < 8; ++j) As[sc + j][rr] = v[j];
    }
    __syncthreads();
#pragma unroll
    for (int kc = 0; kc < 2; ++kc) {
      int ko = kc * 32 + quad * 8;
      bf16x8 af[2], bfr[2];
#pragma unroll
      for (int i = 0; i < 2; ++i) {
        af[i]  = *reinterpret_cast<const bf16x8*>(&As[wn + i * 16 + lrow][ko]);
        bfr[i] = *reinterpret_cast<const bf16x8*>(&Bs[wo + i * 16 + lrow][ko]);
      }
#pragma unroll
      for (int i = 0; i < 2; ++i)
#pragma unroll
        for (int j = 0; j < 2; ++j)
          acc[i][j] = __builtin_amdgcn_mfma_f32_16x16x32_bf16(af[i], bfr[j], acc[i][j], 0, 0, 0);
    }
    __syncthreads();
  }
#pragma unroll
  for (int j = 0; j < 2; ++j) {
    int o = o0 + wo + j * 16 + lrow;
    float bias = b2[o];
#pragma unroll
    for (int i = 0; i < 2; ++i) {
      int nb = n0 + wn + i * 16 + quad * 4;
      float4 v = make_float4(acc[i][j].x + bias, acc[i][j].y + bias,
                             acc[i][j].z + bias, acc[i][j].w + bias);
      *reinterpret_cast<float4*>(&outp[((size_t)b * DD + o) * NN + nb]) = v;
    }
  }
}

// ---------------------------------------------------------------------------
extern "C" void kernel_launch(void* const* d_in, const int* in_sizes, int n_in,
                              void* d_out, int out_size, void* d_ws, size_t ws_size,
                              hipStream_t stream) {
  (void)in_sizes; (void)n_in; (void)out_size; (void)ws_size;
  const float* pred   = (const float*)d_in[0];
  const float* feat   = (const float*)d_in[1];
  const float* w_cls1 = (const float*)d_in[2];
  const float* b_cls1 = (const float*)d_in[3];
  const float* w_cls2 = (const float*)d_in[4];
  const float* b_cls2 = (const float*)d_in[5];
  const float* w_pro1 = (const float*)d_in[6];
  const float* b_pro1 = (const float*)d_in[7];
  const float* w_pro2 = (const float*)d_in[8];
  const float* b_pro2 = (const float*)d_in[9];
  const float* cw     = (const float*)d_in[10];
  float* out = (float*)d_out;

  // workspace layout
  float* Mbuf = (float*)d_ws;                               // B*N*N fp32 (aff1/As); bf16 Mh aliases
  float* xnT  = Mbuf + (size_t)BB * NN * NN;
  float* spnT = xnT + (size_t)BB * DD * NN;
  float* yT   = spnT + (size_t)BB * CC * NN;
  float* p2b  = yT + (size_t)BB * CC * NN;
  float* thr  = p2b + (size_t)BB * NN * CC;
  float* dsum = thr + BB * NN;
  float* d2s  = dsum + BB * NN;
  float* maskb = d2s + BB * NN;
  unsigned int* ohbits = (unsigned int*)(maskb + BB * NN);
  unsigned short* nfh  = (unsigned short*)(ohbits + BB * NN);  // B*N*D bf16
  unsigned short* midh = nfh + (size_t)BB * NN * DD;           // B*D*N bf16
  unsigned short* zb   = midh + (size_t)BB * DD * NN;          // B*D*N bf16
  unsigned short* wb1  = zb + (size_t)BB * DD * NN;            // D*D bf16
  unsigned short* wb2  = wb1 + (size_t)DD * DD;                // D*D bf16
  unsigned short* Mh   = (unsigned short*)Mbuf;                // aliases Mbuf (after k_p2)

  hipMemsetAsync(dsum, 0, sizeof(float) * BB * NN, stream);
  hipMemsetAsync(ohbits, 0, sizeof(unsigned int) * BB * NN, stream);

  dim3 gt(64, 64, BB);
  // --- pred branch (fp32, discrete-safe) ---
  k_mask_bits<<<BB * NN / 256, 256, 0, stream>>>(pred, cw, maskb, ohbits);
  k_norm_feat<<<BB * NN / 64, 64, 0, stream>>>(feat, xnT);
  k_gram1<<<gt, 256, 0, stream>>>(xnT, Mbuf);
  k_topk<<<dim3(NN, BB), 256, 0, stream>>>(Mbuf, thr);
  k_symm<<<gt, 256, 0, stream>>>(Mbuf, thr, dsum);
  k_fin_d<<<BB * NN / 256, 256, 0, stream>>>(dsum);
  k_make_y<<<(BB * CC * NN + 255) / 256, 256, 0, stream>>>(pred, dsum, yT);
  k_p2<<<dim3(NN, BB), 256, 0, stream>>>(Mbuf, yT, dsum, p2b);
  k_pred_head<<<BB * NN / 256, 256, 0, stream>>>(pred, p2b, maskb, w_cls1, b_cls1,
                                                 w_cls2, b_cls2, out, spnT);
  // --- feat branch (bf16 MFMA) ---
  k_gram2<<<gt, 256, 0, stream>>>(spnT, ohbits, Mh);
  k_rowsum2h<<<dim3(NN, BB), 256, 0, stream>>>(Mh, d2s);
  k_make_z<<<BB * DD * NN / 4 / 256, 256, 0, stream>>>(feat, d2s, zb);
  k_prep_w<<<DD * DD / 256, 256, 0, stream>>>(w_pro1, w_pro2, wb1, wb2);
  k_newfeat_mfma<<<dim3(64, 4, BB), 256, 0, stream>>>(Mh, zb, d2s, nfh);
  k_conv1_mfma<<<dim3(64, 4, BB), 256, 0, stream>>>(nfh, wb1, b_pro1, midh);
  k_conv2_mfma<<<dim3(64, 4, BB), 256, 0, stream>>>(midh, wb2, b_pro2,
                                                    out + (size_t)BB * CC * NN);
}

// Round 4
// 772.329 us; speedup vs baseline: 1.3340x; 1.0170x over previous
//
#include <hip/hip_runtime.h>

#define NN 4096   // H*W
#define DD 256    // feature channels
#define CC 19     // classes
#define BB 2      // batch

typedef __attribute__((ext_vector_type(8))) short bf16x8;   // MFMA A/B frag (4 VGPRs)
typedef __attribute__((ext_vector_type(4))) float f32x4;    // MFMA C/D frag

__device__ inline unsigned short f2b(float f) {   // fp32 -> bf16 RNE
  unsigned int u = __float_as_uint(f);
  return (unsigned short)((u + 0x7FFFu + ((u >> 16) & 1u)) >> 16);
}
__device__ inline float b2f(unsigned short h) {
  return __uint_as_float(((unsigned int)h) << 16);
}
__device__ inline unsigned int pack2(float a, float b) {
  return (unsigned int)f2b(a) | ((unsigned int)f2b(b) << 16);
}

// ---------------------------------------------------------------------------
// K1: softmax confidence mask + scrambled one-hot bitmasks
// ---------------------------------------------------------------------------
__global__ void k_mask_bits(const float* __restrict__ pred, const float* __restrict__ cw,
                            float* __restrict__ maskb, unsigned int* __restrict__ ohbits) {
  int g = blockIdx.x * 256 + threadIdx.x;
  if (g >= BB * NN) return;
  int b = g >> 12, n = g & (NN - 1);
  const float* p = pred + (size_t)b * CC * NN + n;
  float v[CC];
  float mx = -1e30f; int am = 0;
#pragma unroll
  for (int c = 0; c < CC; ++c) {
    float t = p[(size_t)c * NN];
    v[c] = t;
    if (t > mx) { mx = t; am = c; }
  }
  float s = 0.f;
#pragma unroll
  for (int c = 0; c < CC; ++c) s += expf(v[c] - mx);
  float pprob = 1.f / s;
  float cmax = 0.f;
#pragma unroll
  for (int c = 0; c < CC; ++c) cmax = fmaxf(cmax, cw[c]);
  float cwm = cw[am] / (cmax + 1e-10f) * 0.95f;
  maskb[g] = (pprob >= 0.95f || pprob >= cwm) ? 1.f : 0.f;
  // one_hot [B,H,W,C] -> transpose(0,2,3,1) -> [B,W,C,H] -> reshape(B,-1,19)
  int h = n >> 6, w = n & 63;
  int L = w * (CC * 64) + am * 64 + h;     // flat index in [W,C,H]
  atomicOr(&ohbits[b * NN + L / CC], 1u << (L % CC));
}

// ---------------------------------------------------------------------------
// K2: row-normalize features, stored transposed xnT[b][d][n]
// ---------------------------------------------------------------------------
__global__ void k_norm_feat(const float* __restrict__ feat, float* __restrict__ xnT) {
  int g = blockIdx.x * 64 + threadIdx.x;
  int b = g >> 12, n = g & (NN - 1);
  const float* f = feat + (size_t)b * DD * NN + n;
  float s = 0.f;
  for (int d = 0; d < DD; ++d) { float t = f[(size_t)d * NN]; s += t * t; }
  float r = 1.f / (sqrtf(s) + 1e-9f);
  float* o = xnT + (size_t)b * DD * NN + n;
  for (int d = 0; d < DD; ++d) o[(size_t)d * NN] = f[(size_t)d * NN] * r;
}

// ---------------------------------------------------------------------------
// K3: aff1 = clamp(Gram(xn), 0).  128x128 tiles, triangular grid.
// fp32 VALU (feeds discrete top-21 threshold; bf16 would flip edges).
// ---------------------------------------------------------------------------
__global__ __launch_bounds__(256) void k_gram1(const float* __restrict__ xnT, float* __restrict__ M) {
  int L = blockIdx.x;          // 0..527 triangular index (32 tiles/dim)
  int b = blockIdx.y;
  int I = 0;
  while (L >= 32 - I) { L -= 32 - I; ++I; }
  int J = I + L;
  const float* X = xnT + (size_t)b * DD * NN;
  float* Mb = M + (size_t)b * NN * NN;
  __shared__ float sA[16][128];
  __shared__ float sB[16][128];
  __shared__ float tr[32][132];
  int t = threadIdx.x;
  int r = t >> 4, c = t & 15;        // 16x16 thread grid, 8x8 acc each
  int i0 = I * 128, j0 = J * 128;
  float acc[8][8] = {};
  int lk = t >> 4, lcol = (t & 15) * 8;
  for (int k0 = 0; k0 < DD; k0 += 16) {
    const float* src = X + (size_t)(k0 + lk) * NN;
    *reinterpret_cast<float4*>(&sA[lk][lcol])     = *reinterpret_cast<const float4*>(&src[i0 + lcol]);
    *reinterpret_cast<float4*>(&sA[lk][lcol + 4]) = *reinterpret_cast<const float4*>(&src[i0 + lcol + 4]);
    *reinterpret_cast<float4*>(&sB[lk][lcol])     = *reinterpret_cast<const float4*>(&src[j0 + lcol]);
    *reinterpret_cast<float4*>(&sB[lk][lcol + 4]) = *reinterpret_cast<const float4*>(&src[j0 + lcol + 4]);
    __syncthreads();
#pragma unroll
    for (int k = 0; k < 16; ++k) {
      float av[8], bv[8];
      *reinterpret_cast<float4*>(&av[0]) = *reinterpret_cast<float4*>(&sA[k][r * 8]);
      *reinterpret_cast<float4*>(&av[4]) = *reinterpret_cast<float4*>(&sA[k][r * 8 + 4]);
      *reinterpret_cast<float4*>(&bv[0]) = *reinterpret_cast<float4*>(&sB[k][c * 8]);
      *reinterpret_cast<float4*>(&bv[4]) = *reinterpret_cast<float4*>(&sB[k][c * 8 + 4]);
#pragma unroll
      for (int i = 0; i < 8; ++i)
#pragma unroll
        for (int j = 0; j < 8; ++j) acc[i][j] += av[i] * bv[j];
    }
    __syncthreads();
  }
  // clamp
#pragma unroll
  for (int i = 0; i < 8; ++i)
#pragma unroll
    for (int j = 0; j < 8; ++j) acc[i][j] = fmaxf(acc[i][j], 0.f);
  // write (I,J) tile
#pragma unroll
  for (int i = 0; i < 8; ++i) {
    float* dst = &Mb[(size_t)(i0 + r * 8 + i) * NN + j0 + c * 8];
    *reinterpret_cast<float4*>(dst)     = make_float4(acc[i][0], acc[i][1], acc[i][2], acc[i][3]);
    *reinterpret_cast<float4*>(dst + 4) = make_float4(acc[i][4], acc[i][5], acc[i][6], acc[i][7]);
  }
  // write mirror tile (J,I) via 4 transpose chunks of 32 cols
  if (I != J) {
    for (int ch = 0; ch < 4; ++ch) {
      if ((c >> 2) == ch) {
#pragma unroll
        for (int i = 0; i < 8; ++i)
#pragma unroll
          for (int j = 0; j < 8; ++j) tr[(c & 3) * 8 + j][r * 8 + i] = acc[i][j];
      }
      __syncthreads();
      int jj = t >> 3, cs = (t & 7) * 16;
#pragma unroll
      for (int q = 0; q < 4; ++q) {
        *reinterpret_cast<float4*>(&Mb[(size_t)(j0 + ch * 32 + jj) * NN + i0 + cs + q * 4]) =
            *reinterpret_cast<float4*>(&tr[jj][cs + q * 4]);
      }
      __syncthreads();
    }
  }
}

// ---------------------------------------------------------------------------
// K4: per-row 21st-largest value (extract-max x21 on LDS copy)
// ---------------------------------------------------------------------------
__global__ __launch_bounds__(256) void k_topk(const float* __restrict__ M, float* __restrict__ thr) {
  int b = blockIdx.y, n = blockIdx.x;
  const float* row = M + (size_t)b * NN * NN + (size_t)n * NN;
  __shared__ float vals[NN];
  __shared__ float wrv[4];
  __shared__ int wri[4];
  int t = threadIdx.x;
  int wid = t >> 6, lane = t & 63;
  for (int i = t; i < NN; i += 256) vals[i] = row[i];
  __syncthreads();
  float last = 0.f;
  for (int it = 0; it < 21; ++it) {
    float bv = -2.f; int bi = 0;
#pragma unroll
    for (int e = 0; e < 16; ++e) {
      int idx = t + e * 256;
      float v = vals[idx];
      if (v > bv) { bv = v; bi = idx; }
    }
    for (int off = 32; off > 0; off >>= 1) {
      float ov = __shfl_down(bv, off);
      int oi = __shfl_down(bi, off);
      if (ov > bv || (ov == bv && oi < bi)) { bv = ov; bi = oi; }
    }
    if (lane == 0) { wrv[wid] = bv; wri[wid] = bi; }
    __syncthreads();
    if (t == 0) {
      float fv = wrv[0]; int fi = wri[0];
#pragma unroll
      for (int w = 1; w < 4; ++w) {
        if (wrv[w] > fv || (wrv[w] == fv && wri[w] < fi)) { fv = wrv[w]; fi = wri[w]; }
      }
      vals[fi] = -1.f;
      last = fv;
    }
    __syncthreads();
  }
  if (t == 0) thr[b * NN + n] = last;
}

// ---------------------------------------------------------------------------
// K5: sparsify + symmetrize As = S + S^T.  Triangular grid.  Outputs:
//   - As as bf16 packed INSIDE each tile's own fp32 footprint (race-free):
//     element (row n, global col g) at ushort idx 2*n*NN + 64*(g>>6) + g
//   - degree partial sums (fp32, pre-rounding) via atomics
// ---------------------------------------------------------------------------
__global__ __launch_bounds__(256) void k_symm(float* __restrict__ M, const float* __restrict__ thr,
                                              float* __restrict__ dsum) {
  int L = blockIdx.x;          // 0..2079 triangular index (64 tiles/dim)
  int b = blockIdx.y;
  int I = 0;
  while (L >= 64 - I) { L -= 64 - I; ++I; }
  int J = I + L;
  float* Mb = M + (size_t)b * NN * NN;
  unsigned short* Mus = (unsigned short*)Mb;
  const float* th = thr + b * NN;
  __shared__ float A[64][65];
  __shared__ float Bt[64][65];
  int t = threadIdx.x;
  int i0 = I * 64, j0 = J * 64;
  float areg[16];
#pragma unroll
  for (int e = 0; e < 16; ++e) {
    int lin = t + e * 256;
    int i = lin >> 6, j = lin & 63;
    areg[e] = Mb[(size_t)(i0 + i) * NN + j0 + j];
    Bt[i][j] = Mb[(size_t)(j0 + i) * NN + i0 + j];
  }
  __syncthreads();
#pragma unroll
  for (int e = 0; e < 16; ++e) {
    int lin = t + e * 256;
    int i = lin >> 6, j = lin & 63;
    float a = areg[e];
    float sa = (a >= th[i0 + i]) ? a : 0.f;
    float bt = Bt[j][i];
    float sb = (bt >= th[j0 + j]) ? bt : 0.f;
    A[i][j] = sa + sb;
  }
  __syncthreads();
  // bf16 packed write of tile (I,J): rows i0+i, cols [j0, j0+64)
  {
    int i = t >> 2, seg = (t & 3) * 16;
    float v[16];
#pragma unroll
    for (int q = 0; q < 4; ++q)
      *reinterpret_cast<float4*>(&v[q * 4]) = *reinterpret_cast<float4*>(&A[i][seg + q * 4]);
    unsigned int pk[8];
#pragma unroll
    for (int q = 0; q < 8; ++q) pk[q] = pack2(v[2 * q], v[2 * q + 1]);
    size_t ub = 2 * (size_t)(i0 + i) * NN + 2 * (size_t)j0 + seg;
    *reinterpret_cast<int4*>(&Mus[ub])     = *reinterpret_cast<int4*>(&pk[0]);
    *reinterpret_cast<int4*>(&Mus[ub + 8]) = *reinterpret_cast<int4*>(&pk[4]);
  }
  // mirror tile (J,I): rows j0+j, cols [i0, i0+64)  (A transposed)
  if (I != J) {
    int j = t >> 2, seg = (t & 3) * 16;
    float v[16];
#pragma unroll
    for (int e = 0; e < 16; ++e) v[e] = A[seg + e][j];
    unsigned int pk[8];
#pragma unroll
    for (int q = 0; q < 8; ++q) pk[q] = pack2(v[2 * q], v[2 * q + 1]);
    size_t ub = 2 * (size_t)(j0 + j) * NN + 2 * (size_t)i0 + seg;
    *reinterpret_cast<int4*>(&Mus[ub])     = *reinterpret_cast<int4*>(&pk[0]);
    *reinterpret_cast<int4*>(&Mus[ub + 8]) = *reinterpret_cast<int4*>(&pk[4]);
  }
  // degree partial sums (fp32, pre-rounding)
  if (t < 64) {
    float s = 0.f;
#pragma unroll
    for (int j = 0; j < 64; ++j) s += A[t][j];
    atomicAdd(&dsum[b * NN + i0 + t], s);
  } else if (t < 128 && I != J) {
    int j = t - 64;
    float s = 0.f;
#pragma unroll
    for (int i = 0; i < 64; ++i) s += A[i][j];
    atomicAdd(&dsum[b * NN + j0 + j], s);
  }
}

// ---------------------------------------------------------------------------
// K6: d = (d + 1e-10)^-0.5
// ---------------------------------------------------------------------------
__global__ void k_fin_d(float* __restrict__ d) {
  int g = blockIdx.x * 256 + threadIdx.x;
  if (g < BB * NN) d[g] = 1.f / sqrtf(d[g] + 1e-10f);
}

// ---------------------------------------------------------------------------
// K7: yT[b][c][n] = d1n[b][n] * pred[b][c][n]
// ---------------------------------------------------------------------------
__global__ void k_make_y(const float* __restrict__ pred, const float* __restrict__ d1,
                         float* __restrict__ yT) {
  int g = blockIdx.x * 256 + threadIdx.x;
  if (g >= BB * CC * NN) return;
  int b = g / (CC * NN);
  int n = g & (NN - 1);
  yT[g] = pred[g] * d1[b * NN + n];
}

// ---------------------------------------------------------------------------
// K8: p2[b][n][c] = d1n[n] * sum_m As[n][m] * yT[c][m]   (As read bf16-packed)
// ---------------------------------------------------------------------------
__global__ __launch_bounds__(256) void k_p2(const float* __restrict__ M, const float* __restrict__ yT,
                                            const float* __restrict__ d1, float* __restrict__ p2b) {
  int b = blockIdx.y, n = blockIdx.x;
  const unsigned short* Mus = (const unsigned short*)(M + (size_t)b * NN * NN);
  size_t base = 2 * (size_t)n * NN;
  const float* Y = yT + (size_t)b * CC * NN;
  __shared__ float ys[CC][256];
  __shared__ float part[CC][4];
  int t = threadIdx.x;
  float acc[CC] = {};
  for (int m0 = 0; m0 < NN; m0 += 256) {
#pragma unroll
    for (int c = 0; c < CC; ++c) ys[c][t] = Y[(size_t)c * NN + m0 + t];
    __syncthreads();
    int g = m0 + t;
    float a = b2f(Mus[base + 64 * (g >> 6) + g]);
#pragma unroll
    for (int c = 0; c < CC; ++c) acc[c] += a * ys[c][t];
    __syncthreads();
  }
  int wid = t >> 6, lane = t & 63;
#pragma unroll
  for (int c = 0; c < CC; ++c) {
    float v = acc[c];
    for (int off = 32; off > 0; off >>= 1) v += __shfl_down(v, off);
    if (lane == 0) part[c][wid] = v;
  }
  __syncthreads();
  if (t < CC) {
    float s = part[t][0] + part[t][1] + part[t][2] + part[t][3];
    p2b[((size_t)b * NN + n) * CC + t] = d1[b * NN + n] * s;
  }
}

// ---------------------------------------------------------------------------
// K9: fused blend + 19x19 conv x2 -> pred_out, then softmax + cosine-normalize
// ---------------------------------------------------------------------------
__global__ __launch_bounds__(256) void k_pred_head(const float* __restrict__ pred,
    const float* __restrict__ p2b, const float* __restrict__ maskb,
    const float* __restrict__ w1, const float* __restrict__ b1,
    const float* __restrict__ w2, const float* __restrict__ b2,
    float* __restrict__ out, float* __restrict__ spnT) {
  __shared__ float sw1[CC * CC], sw2[CC * CC], sb1[CC], sb2[CC];
  int t = threadIdx.x;
  for (int i = t; i < CC * CC; i += 256) { sw1[i] = w1[i]; sw2[i] = w2[i]; }
  if (t < CC) { sb1[t] = b1[t]; sb2[t] = b2[t]; }
  __syncthreads();
  int g = blockIdx.x * 256 + t;
  int b = g >> 12, n = g & (NN - 1);
  float m = maskb[g];
  float ca = (m > 0.5f) ? 0.2f : 0.8f;
  float cb = (m > 0.5f) ? 0.8f : 0.2f;
  const float* P = pred + (size_t)b * CC * NN + n;
  const float* Q = p2b + (size_t)g * CC;
  float p3[CC];
#pragma unroll
  for (int c = 0; c < CC; ++c) p3[c] = ca * Q[c] + cb * P[(size_t)c * NN];
  float midv[CC];
#pragma unroll
  for (int o = 0; o < CC; ++o) {
    float s = sb1[o];
#pragma unroll
    for (int c = 0; c < CC; ++c) s += sw1[o * CC + c] * p3[c];
    midv[o] = s;
  }
  float ov[CC];
  float mx = -1e30f;
#pragma unroll
  for (int o = 0; o < CC; ++o) {
    float s = sb2[o];
#pragma unroll
    for (int c = 0; c < CC; ++c) s += sw2[o * CC + c] * midv[c];
    ov[o] = s;
    out[(size_t)b * CC * NN + (size_t)o * NN + n] = s;
    mx = fmaxf(mx, s);
  }
  float se = 0.f;
  float e[CC];
#pragma unroll
  for (int o = 0; o < CC; ++o) { e[o] = expf(ov[o] - mx); se += e[o]; }
  float inv = 1.f / se;
  float nrm = 0.f;
#pragma unroll
  for (int o = 0; o < CC; ++o) { float sp = e[o] * inv; e[o] = sp; nrm += sp * sp; }
  float rn = 1.f / (sqrtf(nrm) + 1e-9f);
#pragma unroll
  for (int o = 0; o < CC; ++o) spnT[(size_t)b * CC * NN + (size_t)o * NN + n] = e[o] * rn;
}

// ---------------------------------------------------------------------------
// K10: aff_f = bitmask ? clamp(Gram(spn),0) : 0   (K=19), writes bf16
// ---------------------------------------------------------------------------
__global__ __launch_bounds__(256) void k_gram2(const float* __restrict__ spnT,
    const unsigned int* __restrict__ bits, unsigned short* __restrict__ Mh) {
  int b = blockIdx.z, I = blockIdx.y, J = blockIdx.x;
  if (I > J) return;
  const float* X = spnT + (size_t)b * CC * NN;
  unsigned short* Mb = Mh + (size_t)b * NN * NN;
  __shared__ float sA[CC][64], sB[CC][64];
  __shared__ unsigned int bI[64], bJ[64];
  __shared__ float tr[64][65];
  int t = threadIdx.x;
  int r = t >> 4, c = t & 15;
  int i0 = I * 64, j0 = J * 64;
  for (int e = t; e < CC * 64; e += 256) {
    int k = e >> 6, col = e & 63;
    sA[k][col] = X[(size_t)k * NN + i0 + col];
    sB[k][col] = X[(size_t)k * NN + j0 + col];
  }
  if (t < 64) bI[t] = bits[b * NN + i0 + t];
  else if (t < 128) bJ[t - 64] = bits[b * NN + j0 + t - 64];
  __syncthreads();
  float acc[4][4] = {};
#pragma unroll
  for (int k = 0; k < CC; ++k) {
    float av[4], bv[4];
#pragma unroll
    for (int i = 0; i < 4; ++i) av[i] = sA[k][r * 4 + i];
#pragma unroll
    for (int j = 0; j < 4; ++j) bv[j] = sB[k][c * 4 + j];
#pragma unroll
    for (int i = 0; i < 4; ++i) {
#pragma unroll
      for (int j = 0; j < 4; ++j) acc[i][j] += av[i] * bv[j];
    }
  }
#pragma unroll
  for (int i = 0; i < 4; ++i) {
#pragma unroll
    for (int j = 0; j < 4; ++j) {
      bool keep = (bI[r * 4 + i] & bJ[c * 4 + j]) != 0u;
      acc[i][j] = keep ? fmaxf(acc[i][j], 0.f) : 0.f;
    }
    ushort4 v;
    v.x = f2b(acc[i][0]); v.y = f2b(acc[i][1]); v.z = f2b(acc[i][2]); v.w = f2b(acc[i][3]);
    *reinterpret_cast<ushort4*>(&Mb[(size_t)(i0 + r * 4 + i) * NN + j0 + c * 4]) = v;
  }
  if (I != J) {
#pragma unroll
    for (int i = 0; i < 4; ++i) {
#pragma unroll
      for (int j = 0; j < 4; ++j) tr[r * 4 + i][c * 4 + j] = acc[i][j];
    }
    __syncthreads();
#pragma unroll
    for (int e = 0; e < 16; ++e) {
      int lin = t + e * 256;
      int jr = lin >> 6, ic = lin & 63;
      Mb[(size_t)(j0 + jr) * NN + i0 + ic] = f2b(tr[ic][jr]);
    }
  }
}

// ---------------------------------------------------------------------------
// K11: d2[n] = (row_sum(aff_f bf16) + 1e-10)^-0.5
// ---------------------------------------------------------------------------
__global__ __launch_bounds__(256) void k_rowsum2h(const unsigned short* __restrict__ Mh,
                                                  float* __restrict__ d2) {
  int b = blockIdx.y, n = blockIdx.x;
  const unsigned short* row = Mh + (size_t)b * NN * NN + (size_t)n * NN;
  int t = threadIdx.x;
  float s = 0.f;
#pragma unroll
  for (int i = 0; i < 8; ++i) {
    unsigned int u = *reinterpret_cast<const unsigned int*>(&row[(i * 256 + t) * 2]);
    s += __uint_as_float(u << 16) + __uint_as_float(u & 0xffff0000u);
  }
  for (int off = 32; off > 0; off >>= 1) s += __shfl_down(s, off);
  __shared__ float p4[4];
  int wid = t >> 6, lane = t & 63;
  if (lane == 0) p4[wid] = s;
  __syncthreads();
  if (t == 0) d2[b * NN + n] = 1.f / sqrtf(p4[0] + p4[1] + p4[2] + p4[3] + 1e-10f);
}

// ---------------------------------------------------------------------------
// K12a: zb[b][d][m] = bf16(feat[b][d][m] * d2[b][m])
// ---------------------------------------------------------------------------
__global__ void k_make_z(const float* __restrict__ feat, const float* __restrict__ d2,
                         unsigned short* __restrict__ zb) {
  int g = blockIdx.x * 256 + threadIdx.x;   // BB*DD*NN/4 threads
  int idx = g * 4;
  int b = idx / (DD * NN);
  int m = idx & (NN - 1);
  float4 f = *reinterpret_cast<const float4*>(&feat[idx]);
  const float* dd = d2 + b * NN + m;
  ushort4 o;
  o.x = f2b(f.x * dd[0]); o.y = f2b(f.y * dd[1]);
  o.z = f2b(f.z * dd[2]); o.w = f2b(f.w * dd[3]);
  *reinterpret_cast<ushort4*>(&zb[idx]) = o;
}

// K12b: convert projection weights to bf16
__global__ void k_prep_w(const float* __restrict__ w1, const float* __restrict__ w2,
                         unsigned short* __restrict__ wb1, unsigned short* __restrict__ wb2) {
  int g = blockIdx.x * 256 + threadIdx.x;   // DD*DD threads
  wb1[g] = f2b(w1[g]);
  wb2[g] = f2b(w2[g]);
}

// ---------------------------------------------------------------------------
// K13: new_feat via MFMA.  GEMM: M=d(64-tile), N=n(64-tile), K=m(4096).
// ---------------------------------------------------------------------------
__global__ __launch_bounds__(256) void k_newfeat_mfma(
    const unsigned short* __restrict__ Mh, const unsigned short* __restrict__ zb,
    const float* __restrict__ d2, unsigned short* __restrict__ nfh) {
  int b = blockIdx.z;
  int nblk = blockIdx.x;   // 64
  int dblk = blockIdx.y;   // 4
  const unsigned short* A = zb + (size_t)b * DD * NN + (size_t)(dblk * 64) * NN;
  const unsigned short* Bm = Mh + (size_t)b * NN * NN + (size_t)(nblk * 64) * NN;
  __shared__ unsigned short As[64][72];
  __shared__ unsigned short Bs[64][72];
  int t = threadIdx.x;
  int wave = t >> 6, lane = t & 63;
  int wd = (wave & 1) * 32, wn = (wave >> 1) * 32;
  int lrow = lane & 15, quad = lane >> 4;
  f32x4 acc[2][2] = {{{0.f,0.f,0.f,0.f},{0.f,0.f,0.f,0.f}},{{0.f,0.f,0.f,0.f},{0.f,0.f,0.f,0.f}}};
  int sr = t >> 3, sc = (t & 7) * 8;     // sr: 0..31, two row-passes cover 64
  for (int m0 = 0; m0 < NN; m0 += 64) {
#pragma unroll
    for (int e = 0; e < 2; ++e) {
      int rr = sr + e * 32;
      *reinterpret_cast<int4*>(&As[rr][sc]) =
          *reinterpret_cast<const int4*>(&A[(size_t)rr * NN + m0 + sc]);
      *reinterpret_cast<int4*>(&Bs[rr][sc]) =
          *reinterpret_cast<const int4*>(&Bm[(size_t)rr * NN + m0 + sc]);
    }
    __syncthreads();
#pragma unroll
    for (int kc = 0; kc < 2; ++kc) {
      int ko = kc * 32 + quad * 8;
      bf16x8 af[2], bfr[2];
#pragma unroll
      for (int i = 0; i < 2; ++i) {
        af[i]  = *reinterpret_cast<const bf16x8*>(&As[wd + i * 16 + lrow][ko]);
        bfr[i] = *reinterpret_cast<const bf16x8*>(&Bs[wn + i * 16 + lrow][ko]);
      }
#pragma unroll
      for (int i = 0; i < 2; ++i)
#pragma unroll
        for (int j = 0; j < 2; ++j)
          acc[i][j] = __builtin_amdgcn_mfma_f32_16x16x32_bf16(af[i], bfr[j], acc[i][j], 0, 0, 0);
    }
    __syncthreads();
  }
#pragma unroll
  for (int j = 0; j < 2; ++j) {
    int n = nblk * 64 + wn + j * 16 + lrow;
    float sc2 = d2[b * NN + n];
#pragma unroll
    for (int i = 0; i < 2; ++i) {
      int d = dblk * 64 + wd + i * 16 + quad * 4;
      ushort4 v;
      v.x = f2b(acc[i][j].x * sc2); v.y = f2b(acc[i][j].y * sc2);
      v.z = f2b(acc[i][j].z * sc2); v.w = f2b(acc[i][j].w * sc2);
      *reinterpret_cast<ushort4*>(&nfh[((size_t)b * NN + n) * DD + d]) = v;
    }
  }
}

// ---------------------------------------------------------------------------
// K14: conv1 via MFMA. GEMM: M=n, N=o1, K=d.
// ---------------------------------------------------------------------------
__global__ __launch_bounds__(256) void k_conv1_mfma(
    const unsigned short* __restrict__ nfh, const unsigned short* __restrict__ wb1,
    const float* __restrict__ b1, unsigned short* __restrict__ midh) {
  int b = blockIdx.z;
  int nblk = blockIdx.x;   // 64
  int oblk = blockIdx.y;   // 4
  int n0 = nblk * 64, o0 = oblk * 64;
  __shared__ unsigned short As[64][72];   // nf tile [n][d]
  __shared__ unsigned short Bs[64][72];   // W1 tile [o][d]
  int t = threadIdx.x;
  int wave = t >> 6, lane = t & 63;
  int wn = (wave & 1) * 32, wo = (wave >> 1) * 32;
  int lrow = lane & 15, quad = lane >> 4;
  f32x4 acc[2][2] = {{{0.f,0.f,0.f,0.f},{0.f,0.f,0.f,0.f}},{{0.f,0.f,0.f,0.f},{0.f,0.f,0.f,0.f}}};
  int sr = t >> 3, sc = (t & 7) * 8;
  for (int d0 = 0; d0 < DD; d0 += 64) {
#pragma unroll
    for (int e = 0; e < 2; ++e) {
      int rr = sr + e * 32;
      *reinterpret_cast<int4*>(&As[rr][sc]) =
          *reinterpret_cast<const int4*>(&nfh[((size_t)b * NN + n0 + rr) * DD + d0 + sc]);
      *reinterpret_cast<int4*>(&Bs[rr][sc]) =
          *reinterpret_cast<const int4*>(&wb1[(size_t)(o0 + rr) * DD + d0 + sc]);
    }
    __syncthreads();
#pragma unroll
    for (int kc = 0; kc < 2; ++kc) {
      int ko = kc * 32 + quad * 8;
      bf16x8 af[2], bfr[2];
#pragma unroll
      for (int i = 0; i < 2; ++i) {
        af[i]  = *reinterpret_cast<const bf16x8*>(&As[wn + i * 16 + lrow][ko]);
        bfr[i] = *reinterpret_cast<const bf16x8*>(&Bs[wo + i * 16 + lrow][ko]);
      }
#pragma unroll
      for (int i = 0; i < 2; ++i)
#pragma unroll
        for (int j = 0; j < 2; ++j)
          acc[i][j] = __builtin_amdgcn_mfma_f32_16x16x32_bf16(af[i], bfr[j], acc[i][j], 0, 0, 0);
    }
    __syncthreads();
  }
#pragma unroll
  for (int j = 0; j < 2; ++j) {
    int o = o0 + wo + j * 16 + lrow;
    float bias = b1[o];
#pragma unroll
    for (int i = 0; i < 2; ++i) {
      int nb = n0 + wn + i * 16 + quad * 4;
      ushort4 v;
      v.x = f2b(fmaxf(acc[i][j].x + bias, 0.f));
      v.y = f2b(fmaxf(acc[i][j].y + bias, 0.f));
      v.z = f2b(fmaxf(acc[i][j].z + bias, 0.f));
      v.w = f2b(fmaxf(acc[i][j].w + bias, 0.f));
      *reinterpret_cast<ushort4*>(&midh[((size_t)b * DD + o) * NN + nb]) = v;
    }
  }
}

// ---------------------------------------------------------------------------
// K15: conv2 via MFMA. GEMM: M=n, N=o2, K=o1.
// ---------------------------------------------------------------------------
__global__ __launch_bounds__(256) void k_conv2_mfma(
    const unsigned short* __restrict__ midh, const unsigned short* __restrict__ wb2,
    const float* __restrict__ b2, float* __restrict__ outp) {
  int b = blockIdx.z;
  int nblk = blockIdx.x;   // 64
  int oblk = blockIdx.y;   // 4
  int n0 = nblk * 64, o0 = oblk * 64;
  __shared__ unsigned short As[64][72];   // mid^T tile [n][o1]
  __shared__ unsigned short Bs[64][72];   // W2 tile [o2][o1]
  int t = threadIdx.x;
  int wave = t >> 6, lane = t & 63;
  int wn = (wave & 1) * 32, wo = (wave >> 1) * 32;
  int lrow = lane & 15, quad = lane >> 4;
  f32x4 acc[2][2] = {{{0.f,0.f,0.f,0.f},{0.f,0.f,0.f,0.f}},{{0.f,0.f,0.f,0.f},{0.f,0.f,0.f,0.f}}};
  int sr = t >> 3, sc = (t & 7) * 8;
  for (int d0 = 0; d0 < DD; d0 += 64) {
#pragma unroll
    for (int e = 0; e < 2; ++e) {
      int rr = sr + e * 32;
      *reinterpret_cast<int4*>(&Bs[rr][sc]) =
          *reinterpret_cast<const int4*>(&wb2[(size_t)(o0 + rr) * DD + d0 + sc]);
      unsigned short v[8];
      *reinterpret_cast<int4*>(v) =
          *reinterpret_cast<const int4*>(&midh[((size_t)b * DD + d0 + rr) * NN + n0 + sc]);
#pragma unroll
      for (int j = 0; j < 8; ++j) As[sc + j][rr] = v[j];
    }
    __syncthreads();
#pragma unroll
    for (int kc = 0; kc < 2; ++kc) {
      int ko = kc * 32 + quad * 8;
      bf16x8 af[2], bfr[2];
#pragma unroll
      for (int i = 0; i < 2; ++i) {
        af[i]  = *reinterpret_cast<const bf16x8*>(&As[wn + i * 16 + lrow][ko]);
        bfr[i] = *reinterpret_cast<const bf16x8*>(&Bs[wo + i * 16 + lrow][ko]);
      }
#pragma unroll
      for (int i = 0; i < 2; ++i)
#pragma unroll
        for (int j = 0; j < 2; ++j)
          acc[i][j] = __builtin_amdgcn_mfma_f32_16x16x32_bf16(af[i], bfr[j], acc[i][j], 0, 0, 0);
    }
    __syncthreads();
  }
#pragma unroll
  for (int j = 0; j < 2; ++j) {
    int o = o0 + wo + j * 16 + lrow;
    float bias = b2[o];
#pragma unroll
    for (int i = 0; i < 2; ++i) {
      int nb = n0 + wn + i * 16 + quad * 4;
      float4 v = make_float4(acc[i][j].x + bias, acc[i][j].y + bias,
                             acc[i][j].z + bias, acc[i][j].w + bias);
      *reinterpret_cast<float4*>(&outp[((size_t)b * DD + o) * NN + nb]) = v;
    }
  }
}

// ---------------------------------------------------------------------------
extern "C" void kernel_launch(void* const* d_in, const int* in_sizes, int n_in,
                              void* d_out, int out_size, void* d_ws, size_t ws_size,
                              hipStream_t stream) {
  (void)in_sizes; (void)n_in; (void)out_size; (void)ws_size;
  const float* pred   = (const float*)d_in[0];
  const float* feat   = (const float*)d_in[1];
  const float* w_cls1 = (const float*)d_in[2];
  const float* b_cls1 = (const float*)d_in[3];
  const float* w_cls2 = (const float*)d_in[4];
  const float* b_cls2 = (const float*)d_in[5];
  const float* w_pro1 = (const float*)d_in[6];
  const float* b_pro1 = (const float*)d_in[7];
  const float* w_pro2 = (const float*)d_in[8];
  const float* b_pro2 = (const float*)d_in[9];
  const float* cw     = (const float*)d_in[10];
  float* out = (float*)d_out;

  // workspace layout
  float* Mbuf = (float*)d_ws;                               // B*N*N fp32 (aff1 / packed-bf16 As / bf16 aff_f)
  float* xnT  = Mbuf + (size_t)BB * NN * NN;
  float* spnT = xnT + (size_t)BB * DD * NN;
  float* yT   = spnT + (size_t)BB * CC * NN;
  float* p2b  = yT + (size_t)BB * CC * NN;
  float* thr  = p2b + (size_t)BB * NN * CC;
  float* dsum = thr + BB * NN;
  float* d2s  = dsum + BB * NN;
  float* maskb = d2s + BB * NN;
  unsigned int* ohbits = (unsigned int*)(maskb + BB * NN);
  unsigned short* nfh  = (unsigned short*)(ohbits + BB * NN);  // B*N*D bf16
  unsigned short* midh = nfh + (size_t)BB * NN * DD;           // B*D*N bf16
  unsigned short* zb   = midh + (size_t)BB * DD * NN;          // B*D*N bf16
  unsigned short* wb1  = zb + (size_t)BB * DD * NN;            // D*D bf16
  unsigned short* wb2  = wb1 + (size_t)DD * DD;                // D*D bf16
  unsigned short* Mh   = (unsigned short*)Mbuf;                // aliases Mbuf (after k_p2)

  hipMemsetAsync(dsum, 0, sizeof(float) * BB * NN, stream);
  hipMemsetAsync(ohbits, 0, sizeof(unsigned int) * BB * NN, stream);

  // --- pred branch (fp32, discrete-safe) ---
  k_mask_bits<<<BB * NN / 256, 256, 0, stream>>>(pred, cw, maskb, ohbits);
  k_norm_feat<<<BB * NN / 64, 64, 0, stream>>>(feat, xnT);
  k_gram1<<<dim3(528, BB), 256, 0, stream>>>(xnT, Mbuf);
  k_topk<<<dim3(NN, BB), 256, 0, stream>>>(Mbuf, thr);
  k_symm<<<dim3(2080, BB), 256, 0, stream>>>(Mbuf, thr, dsum);
  k_fin_d<<<BB * NN / 256, 256, 0, stream>>>(dsum);
  k_make_y<<<(BB * CC * NN + 255) / 256, 256, 0, stream>>>(pred, dsum, yT);
  k_p2<<<dim3(NN, BB), 256, 0, stream>>>(Mbuf, yT, dsum, p2b);
  k_pred_head<<<BB * NN / 256, 256, 0, stream>>>(pred, p2b, maskb, w_cls1, b_cls1,
                                                 w_cls2, b_cls2, out, spnT);
  // --- feat branch (bf16 MFMA) ---
  dim3 gt(64, 64, BB);
  k_gram2<<<gt, 256, 0, stream>>>(spnT, ohbits, Mh);
  k_rowsum2h<<<dim3(NN, BB), 256, 0, stream>>>(Mh, d2s);
  k_make_z<<<BB * DD * NN / 4 / 256, 256, 0, stream>>>(feat, d2s, zb);
  k_prep_w<<<DD * DD / 256, 256, 0, stream>>>(w_pro1, w_pro2, wb1, wb2);
  k_newfeat_mfma<<<dim3(64, 4, BB), 256, 0, stream>>>(Mh, zb, d2s, nfh);
  k_conv1_mfma<<<dim3(64, 4, BB), 256, 0, stream>>>(nfh, wb1, b_pro1, midh);
  k_conv2_mfma<<<dim3(64, 4, BB), 256, 0, stream>>>(midh, wb2, b_pro2,
                                                    out + (size_t)BB * CC * NN);
}

// Round 5
// 623.783 us; speedup vs baseline: 1.6517x; 1.2381x over previous
//
#include <hip/hip_runtime.h>

#define NN 4096   // H*W
#define DD 256    // feature channels
#define CC 19     // classes
#define BB 2      // batch

typedef __attribute__((ext_vector_type(8))) short bf16x8;   // MFMA A/B frag (4 VGPRs)
typedef __attribute__((ext_vector_type(4))) float f32x4;    // MFMA C/D frag

__device__ inline unsigned short f2b(float f) {   // fp32 -> bf16 RNE
  unsigned int u = __float_as_uint(f);
  return (unsigned short)((u + 0x7FFFu + ((u >> 16) & 1u)) >> 16);
}
__device__ inline float b2f(unsigned short h) {
  return __uint_as_float(((unsigned int)h) << 16);
}
__device__ inline unsigned int pack2(float a, float b) {
  return (unsigned int)f2b(a) | ((unsigned int)f2b(b) << 16);
}

// ---------------------------------------------------------------------------
// K1: softmax confidence mask + scrambled one-hot bitmasks
// ---------------------------------------------------------------------------
__global__ void k_mask_bits(const float* __restrict__ pred, const float* __restrict__ cw,
                            float* __restrict__ maskb, unsigned int* __restrict__ ohbits) {
  int g = blockIdx.x * 256 + threadIdx.x;
  if (g >= BB * NN) return;
  int b = g >> 12, n = g & (NN - 1);
  const float* p = pred + (size_t)b * CC * NN + n;
  float v[CC];
  float mx = -1e30f; int am = 0;
#pragma unroll
  for (int c = 0; c < CC; ++c) {
    float t = p[(size_t)c * NN];
    v[c] = t;
    if (t > mx) { mx = t; am = c; }
  }
  float s = 0.f;
#pragma unroll
  for (int c = 0; c < CC; ++c) s += expf(v[c] - mx);
  float pprob = 1.f / s;
  float cmax = 0.f;
#pragma unroll
  for (int c = 0; c < CC; ++c) cmax = fmaxf(cmax, cw[c]);
  float cwm = cw[am] / (cmax + 1e-10f) * 0.95f;
  maskb[g] = (pprob >= 0.95f || pprob >= cwm) ? 1.f : 0.f;
  // one_hot [B,H,W,C] -> transpose(0,2,3,1) -> [B,W,C,H] -> reshape(B,-1,19)
  int h = n >> 6, w = n & 63;
  int L = w * (CC * 64) + am * 64 + h;     // flat index in [W,C,H]
  atomicOr(&ohbits[b * NN + L / CC], 1u << (L % CC));
}

// ---------------------------------------------------------------------------
// K2: row-normalize features, stored transposed xnT[b][d][n]
// ---------------------------------------------------------------------------
__global__ void k_norm_feat(const float* __restrict__ feat, float* __restrict__ xnT) {
  int g = blockIdx.x * 64 + threadIdx.x;
  int b = g >> 12, n = g & (NN - 1);
  const float* f = feat + (size_t)b * DD * NN + n;
  float s = 0.f;
  for (int d = 0; d < DD; ++d) { float t = f[(size_t)d * NN]; s += t * t; }
  float r = 1.f / (sqrtf(s) + 1e-9f);
  float* o = xnT + (size_t)b * DD * NN + n;
  for (int d = 0; d < DD; ++d) o[(size_t)d * NN] = f[(size_t)d * NN] * r;
}

// ---------------------------------------------------------------------------
// K3: aff1 = clamp(Gram(xn), 0).  128x128 tiles, triangular grid.
// fp32 VALU (feeds discrete top-21 threshold; bf16 would flip edges).
// ---------------------------------------------------------------------------
__global__ __launch_bounds__(256) void k_gram1(const float* __restrict__ xnT, float* __restrict__ M) {
  int L = blockIdx.x;          // 0..527 triangular index (32 tiles/dim)
  int b = blockIdx.y;
  int I = 0;
  while (L >= 32 - I) { L -= 32 - I; ++I; }
  int J = I + L;
  const float* X = xnT + (size_t)b * DD * NN;
  float* Mb = M + (size_t)b * NN * NN;
  __shared__ float sA[16][128];
  __shared__ float sB[16][128];
  __shared__ float tr[32][132];
  int t = threadIdx.x;
  int r = t >> 4, c = t & 15;        // 16x16 thread grid, 8x8 acc each
  int i0 = I * 128, j0 = J * 128;
  float acc[8][8] = {};
  int lk = t >> 4, lcol = (t & 15) * 8;
  for (int k0 = 0; k0 < DD; k0 += 16) {
    const float* src = X + (size_t)(k0 + lk) * NN;
    *reinterpret_cast<float4*>(&sA[lk][lcol])     = *reinterpret_cast<const float4*>(&src[i0 + lcol]);
    *reinterpret_cast<float4*>(&sA[lk][lcol + 4]) = *reinterpret_cast<const float4*>(&src[i0 + lcol + 4]);
    *reinterpret_cast<float4*>(&sB[lk][lcol])     = *reinterpret_cast<const float4*>(&src[j0 + lcol]);
    *reinterpret_cast<float4*>(&sB[lk][lcol + 4]) = *reinterpret_cast<const float4*>(&src[j0 + lcol + 4]);
    __syncthreads();
#pragma unroll
    for (int k = 0; k < 16; ++k) {
      float av[8], bv[8];
      *reinterpret_cast<float4*>(&av[0]) = *reinterpret_cast<float4*>(&sA[k][r * 8]);
      *reinterpret_cast<float4*>(&av[4]) = *reinterpret_cast<float4*>(&sA[k][r * 8 + 4]);
      *reinterpret_cast<float4*>(&bv[0]) = *reinterpret_cast<float4*>(&sB[k][c * 8]);
      *reinterpret_cast<float4*>(&bv[4]) = *reinterpret_cast<float4*>(&sB[k][c * 8 + 4]);
#pragma unroll
      for (int i = 0; i < 8; ++i)
#pragma unroll
        for (int j = 0; j < 8; ++j) acc[i][j] += av[i] * bv[j];
    }
    __syncthreads();
  }
#pragma unroll
  for (int i = 0; i < 8; ++i)
#pragma unroll
    for (int j = 0; j < 8; ++j) acc[i][j] = fmaxf(acc[i][j], 0.f);
#pragma unroll
  for (int i = 0; i < 8; ++i) {
    float* dst = &Mb[(size_t)(i0 + r * 8 + i) * NN + j0 + c * 8];
    *reinterpret_cast<float4*>(dst)     = make_float4(acc[i][0], acc[i][1], acc[i][2], acc[i][3]);
    *reinterpret_cast<float4*>(dst + 4) = make_float4(acc[i][4], acc[i][5], acc[i][6], acc[i][7]);
  }
  if (I != J) {
    for (int ch = 0; ch < 4; ++ch) {
      if ((c >> 2) == ch) {
#pragma unroll
        for (int i = 0; i < 8; ++i)
#pragma unroll
          for (int j = 0; j < 8; ++j) tr[(c & 3) * 8 + j][r * 8 + i] = acc[i][j];
      }
      __syncthreads();
      int jj = t >> 3, cs = (t & 7) * 16;
#pragma unroll
      for (int q = 0; q < 4; ++q) {
        *reinterpret_cast<float4*>(&Mb[(size_t)(j0 + ch * 32 + jj) * NN + i0 + cs + q * 4]) =
            *reinterpret_cast<float4*>(&tr[jj][cs + q * 4]);
      }
      __syncthreads();
    }
  }
}

// ---------------------------------------------------------------------------
// K4: per-row 21st-largest value (extract-max x21 on LDS copy)
// ---------------------------------------------------------------------------
__global__ __launch_bounds__(256) void k_topk(const float* __restrict__ M, float* __restrict__ thr) {
  int b = blockIdx.y, n = blockIdx.x;
  const float* row = M + (size_t)b * NN * NN + (size_t)n * NN;
  __shared__ float vals[NN];
  __shared__ float wrv[4];
  __shared__ int wri[4];
  int t = threadIdx.x;
  int wid = t >> 6, lane = t & 63;
  for (int i = t; i < NN; i += 256) vals[i] = row[i];
  __syncthreads();
  float last = 0.f;
  for (int it = 0; it < 21; ++it) {
    float bv = -2.f; int bi = 0;
#pragma unroll
    for (int e = 0; e < 16; ++e) {
      int idx = t + e * 256;
      float v = vals[idx];
      if (v > bv) { bv = v; bi = idx; }
    }
    for (int off = 32; off > 0; off >>= 1) {
      float ov = __shfl_down(bv, off);
      int oi = __shfl_down(bi, off);
      if (ov > bv || (ov == bv && oi < bi)) { bv = ov; bi = oi; }
    }
    if (lane == 0) { wrv[wid] = bv; wri[wid] = bi; }
    __syncthreads();
    if (t == 0) {
      float fv = wrv[0]; int fi = wri[0];
#pragma unroll
      for (int w = 1; w < 4; ++w) {
        if (wrv[w] > fv || (wrv[w] == fv && wri[w] < fi)) { fv = wrv[w]; fi = wri[w]; }
      }
      vals[fi] = -1.f;
      last = fv;
    }
    __syncthreads();
  }
  if (t == 0) thr[b * NN + n] = last;
}

// ---------------------------------------------------------------------------
// K5: sparsify + symmetrize As = S + S^T.  Triangular grid.  Outputs:
//   - As as bf16 packed INSIDE each tile's own fp32 footprint (race-free):
//     element (row n, col g) at ushort idx 2*n*NN + 2*(g&~63) + (g&63)
//   - degree partial sums (fp32, pre-rounding) via atomics
// ---------------------------------------------------------------------------
__global__ __launch_bounds__(256) void k_symm(float* __restrict__ M, const float* __restrict__ thr,
                                              float* __restrict__ dsum) {
  int L = blockIdx.x;          // 0..2079 triangular index (64 tiles/dim)
  int b = blockIdx.y;
  int I = 0;
  while (L >= 64 - I) { L -= 64 - I; ++I; }
  int J = I + L;
  float* Mb = M + (size_t)b * NN * NN;
  unsigned short* Mus = (unsigned short*)Mb;
  const float* th = thr + b * NN;
  __shared__ float A[64][65];
  __shared__ float Bt[64][65];
  int t = threadIdx.x;
  int i0 = I * 64, j0 = J * 64;
  float areg[16];
#pragma unroll
  for (int e = 0; e < 16; ++e) {
    int lin = t + e * 256;
    int i = lin >> 6, j = lin & 63;
    areg[e] = Mb[(size_t)(i0 + i) * NN + j0 + j];
    Bt[i][j] = Mb[(size_t)(j0 + i) * NN + i0 + j];
  }
  __syncthreads();
#pragma unroll
  for (int e = 0; e < 16; ++e) {
    int lin = t + e * 256;
    int i = lin >> 6, j = lin & 63;
    float a = areg[e];
    float sa = (a >= th[i0 + i]) ? a : 0.f;
    float bt = Bt[j][i];
    float sb = (bt >= th[j0 + j]) ? bt : 0.f;
    A[i][j] = sa + sb;
  }
  __syncthreads();
  {
    int i = t >> 2, seg = (t & 3) * 16;
    float v[16];
#pragma unroll
    for (int q = 0; q < 4; ++q)
      *reinterpret_cast<float4*>(&v[q * 4]) = *reinterpret_cast<float4*>(&A[i][seg + q * 4]);
    unsigned int pk[8];
#pragma unroll
    for (int q = 0; q < 8; ++q) pk[q] = pack2(v[2 * q], v[2 * q + 1]);
    size_t ub = 2 * (size_t)(i0 + i) * NN + 2 * (size_t)j0 + seg;
    *reinterpret_cast<int4*>(&Mus[ub])     = *reinterpret_cast<int4*>(&pk[0]);
    *reinterpret_cast<int4*>(&Mus[ub + 8]) = *reinterpret_cast<int4*>(&pk[4]);
  }
  if (I != J) {
    int j = t >> 2, seg = (t & 3) * 16;
    float v[16];
#pragma unroll
    for (int e = 0; e < 16; ++e) v[e] = A[seg + e][j];
    unsigned int pk[8];
#pragma unroll
    for (int q = 0; q < 8; ++q) pk[q] = pack2(v[2 * q], v[2 * q + 1]);
    size_t ub = 2 * (size_t)(j0 + j) * NN + 2 * (size_t)i0 + seg;
    *reinterpret_cast<int4*>(&Mus[ub])     = *reinterpret_cast<int4*>(&pk[0]);
    *reinterpret_cast<int4*>(&Mus[ub + 8]) = *reinterpret_cast<int4*>(&pk[4]);
  }
  if (t < 64) {
    float s = 0.f;
#pragma unroll
    for (int j = 0; j < 64; ++j) s += A[t][j];
    atomicAdd(&dsum[b * NN + i0 + t], s);
  } else if (t < 128 && I != J) {
    int j = t - 64;
    float s = 0.f;
#pragma unroll
    for (int i = 0; i < 64; ++i) s += A[i][j];
    atomicAdd(&dsum[b * NN + j0 + j], s);
  }
}

// ---------------------------------------------------------------------------
// K6: d = (d + 1e-10)^-0.5
// ---------------------------------------------------------------------------
__global__ void k_fin_d(float* __restrict__ d) {
  int g = blockIdx.x * 256 + threadIdx.x;
  if (g < BB * NN) d[g] = 1.f / sqrtf(d[g] + 1e-10f);
}

// ---------------------------------------------------------------------------
// K7: ybh[b][c][n] = bf16(d1[b][n] * pred[b][c][n]), zero-padded to 32 classes
// ---------------------------------------------------------------------------
__global__ void k_make_yb(const float* __restrict__ pred, const float* __restrict__ d1,
                          unsigned short* __restrict__ ybh) {
  int g = blockIdx.x * 256 + threadIdx.x;   // BB*32*NN/4 threads
  int idx = g * 4;
  int b = idx / (32 * NN);
  int c = (idx / NN) & 31;
  int n = idx & (NN - 1);
  ushort4 o = make_ushort4(0, 0, 0, 0);
  if (c < CC) {
    float4 p = *reinterpret_cast<const float4*>(&pred[((size_t)b * CC + c) * NN + n]);
    const float* dd = d1 + b * NN + n;
    o.x = f2b(p.x * dd[0]); o.y = f2b(p.y * dd[1]);
    o.z = f2b(p.z * dd[2]); o.w = f2b(p.w * dd[3]);
  }
  *reinterpret_cast<ushort4*>(&ybh[idx]) = o;
}

// ---------------------------------------------------------------------------
// K8: p2 via MFMA.  GEMM: M=n (64-tile), N=c (32 padded), K=m (4096).
//   A = As packed bf16 (chunk at ushort 2nNN+2m0, 64 wide), B = ybh[c][m].
//   p2b[b][n][c] = d1[n] * acc.
// ---------------------------------------------------------------------------
__global__ __launch_bounds__(256) void k_p2_mfma(
    const float* __restrict__ M, const unsigned short* __restrict__ ybh,
    const float* __restrict__ d1, float* __restrict__ p2b) {
  int b = blockIdx.y;
  int n0 = blockIdx.x * 64;
  const unsigned short* Mus = (const unsigned short*)(M + (size_t)b * NN * NN);
  const unsigned short* Y = ybh + (size_t)b * 32 * NN;
  __shared__ unsigned short As[64][72];
  __shared__ unsigned short Ys[32][72];
  int t = threadIdx.x;
  int wave = t >> 6, lane = t & 63;
  int wn = (wave & 1) * 32;      // n-offset in tile
  int wc = (wave >> 1) * 16;     // c-offset (0 or 16)
  int lrow = lane & 15, quad = lane >> 4;
  f32x4 acc[2] = {{0.f,0.f,0.f,0.f},{0.f,0.f,0.f,0.f}};
  int sr = t >> 3, scc = (t & 7) * 8;
  for (int m0 = 0; m0 < NN; m0 += 64) {
#pragma unroll
    for (int e = 0; e < 2; ++e) {
      int rr = sr + e * 32;
      *reinterpret_cast<int4*>(&As[rr][scc]) =
          *reinterpret_cast<const int4*>(&Mus[2 * (size_t)(n0 + rr) * NN + 2 * (size_t)m0 + scc]);
    }
    *reinterpret_cast<int4*>(&Ys[sr][scc]) =
        *reinterpret_cast<const int4*>(&Y[(size_t)sr * NN + m0 + scc]);
    __syncthreads();
#pragma unroll
    for (int kc = 0; kc < 2; ++kc) {
      int ko = kc * 32 + quad * 8;
      bf16x8 bfr = *reinterpret_cast<const bf16x8*>(&Ys[wc + lrow][ko]);
#pragma unroll
      for (int i = 0; i < 2; ++i) {
        bf16x8 af = *reinterpret_cast<const bf16x8*>(&As[wn + i * 16 + lrow][ko]);
        acc[i] = __builtin_amdgcn_mfma_f32_16x16x32_bf16(af, bfr, acc[i], 0, 0, 0);
      }
    }
    __syncthreads();
  }
  int c = wc + lrow;
  if (c < CC) {
#pragma unroll
    for (int i = 0; i < 2; ++i) {
#pragma unroll
      for (int reg = 0; reg < 4; ++reg) {
        int n = n0 + wn + i * 16 + quad * 4 + reg;
        p2b[((size_t)b * NN + n) * CC + c] = d1[b * NN + n] * acc[i][reg];
      }
    }
  }
}

// ---------------------------------------------------------------------------
// K9: fused blend + 19x19 conv x2 -> pred_out, then softmax + cosine-normalize
// ---------------------------------------------------------------------------
__global__ __launch_bounds__(256) void k_pred_head(const float* __restrict__ pred,
    const float* __restrict__ p2b, const float* __restrict__ maskb,
    const float* __restrict__ w1, const float* __restrict__ b1,
    const float* __restrict__ w2, const float* __restrict__ b2,
    float* __restrict__ out, float* __restrict__ spnT) {
  __shared__ float sw1[CC * CC], sw2[CC * CC], sb1[CC], sb2[CC];
  int t = threadIdx.x;
  for (int i = t; i < CC * CC; i += 256) { sw1[i] = w1[i]; sw2[i] = w2[i]; }
  if (t < CC) { sb1[t] = b1[t]; sb2[t] = b2[t]; }
  __syncthreads();
  int g = blockIdx.x * 256 + t;
  int b = g >> 12, n = g & (NN - 1);
  float m = maskb[g];
  float ca = (m > 0.5f) ? 0.2f : 0.8f;
  float cb = (m > 0.5f) ? 0.8f : 0.2f;
  const float* P = pred + (size_t)b * CC * NN + n;
  const float* Q = p2b + (size_t)g * CC;
  float p3[CC];
#pragma unroll
  for (int c = 0; c < CC; ++c) p3[c] = ca * Q[c] + cb * P[(size_t)c * NN];
  float midv[CC];
#pragma unroll
  for (int o = 0; o < CC; ++o) {
    float s = sb1[o];
#pragma unroll
    for (int c = 0; c < CC; ++c) s += sw1[o * CC + c] * p3[c];
    midv[o] = s;
  }
  float ov[CC];
  float mx = -1e30f;
#pragma unroll
  for (int o = 0; o < CC; ++o) {
    float s = sb2[o];
#pragma unroll
    for (int c = 0; c < CC; ++c) s += sw2[o * CC + c] * midv[c];
    ov[o] = s;
    out[(size_t)b * CC * NN + (size_t)o * NN + n] = s;
    mx = fmaxf(mx, s);
  }
  float se = 0.f;
  float e[CC];
#pragma unroll
  for (int o = 0; o < CC; ++o) { e[o] = expf(ov[o] - mx); se += e[o]; }
  float inv = 1.f / se;
  float nrm = 0.f;
#pragma unroll
  for (int o = 0; o < CC; ++o) { float sp = e[o] * inv; e[o] = sp; nrm += sp * sp; }
  float rn = 1.f / (sqrtf(nrm) + 1e-9f);
#pragma unroll
  for (int o = 0; o < CC; ++o) spnT[(size_t)b * CC * NN + (size_t)o * NN + n] = e[o] * rn;
}

// ---------------------------------------------------------------------------
// K10: aff_f = bitmask ? clamp(Gram(spn),0) : 0   (K=19), writes bf16.
// Triangular grid.
// ---------------------------------------------------------------------------
__global__ __launch_bounds__(256) void k_gram2(const float* __restrict__ spnT,
    const unsigned int* __restrict__ bits, unsigned short* __restrict__ Mh) {
  int L = blockIdx.x;          // 0..2079 triangular (64 tiles/dim)
  int b = blockIdx.y;
  int I = 0;
  while (L >= 64 - I) { L -= 64 - I; ++I; }
  int J = I + L;
  const float* X = spnT + (size_t)b * CC * NN;
  unsigned short* Mb = Mh + (size_t)b * NN * NN;
  __shared__ float sA[CC][64], sB[CC][64];
  __shared__ unsigned int bI[64], bJ[64];
  __shared__ float tr[64][65];
  int t = threadIdx.x;
  int r = t >> 4, c = t & 15;
  int i0 = I * 64, j0 = J * 64;
  for (int e = t; e < CC * 64; e += 256) {
    int k = e >> 6, col = e & 63;
    sA[k][col] = X[(size_t)k * NN + i0 + col];
    sB[k][col] = X[(size_t)k * NN + j0 + col];
  }
  if (t < 64) bI[t] = bits[b * NN + i0 + t];
  else if (t < 128) bJ[t - 64] = bits[b * NN + j0 + t - 64];
  __syncthreads();
  float acc[4][4] = {};
#pragma unroll
  for (int k = 0; k < CC; ++k) {
    float av[4], bv[4];
#pragma unroll
    for (int i = 0; i < 4; ++i) av[i] = sA[k][r * 4 + i];
#pragma unroll
    for (int j = 0; j < 4; ++j) bv[j] = sB[k][c * 4 + j];
#pragma unroll
    for (int i = 0; i < 4; ++i) {
#pragma unroll
      for (int j = 0; j < 4; ++j) acc[i][j] += av[i] * bv[j];
    }
  }
#pragma unroll
  for (int i = 0; i < 4; ++i) {
#pragma unroll
    for (int j = 0; j < 4; ++j) {
      bool keep = (bI[r * 4 + i] & bJ[c * 4 + j]) != 0u;
      acc[i][j] = keep ? fmaxf(acc[i][j], 0.f) : 0.f;
    }
    ushort4 v;
    v.x = f2b(acc[i][0]); v.y = f2b(acc[i][1]); v.z = f2b(acc[i][2]); v.w = f2b(acc[i][3]);
    *reinterpret_cast<ushort4*>(&Mb[(size_t)(i0 + r * 4 + i) * NN + j0 + c * 4]) = v;
  }
  if (I != J) {
#pragma unroll
    for (int i = 0; i < 4; ++i) {
#pragma unroll
      for (int j = 0; j < 4; ++j) tr[r * 4 + i][c * 4 + j] = acc[i][j];
    }
    __syncthreads();
#pragma unroll
    for (int e = 0; e < 16; ++e) {
      int lin = t + e * 256;
      int jr = lin >> 6, ic = lin & 63;
      Mb[(size_t)(j0 + jr) * NN + i0 + ic] = f2b(tr[ic][jr]);
    }
  }
}

// ---------------------------------------------------------------------------
// K11: d2[n] = (row_sum(aff_f bf16) + 1e-10)^-0.5
// ---------------------------------------------------------------------------
__global__ __launch_bounds__(256) void k_rowsum2h(const unsigned short* __restrict__ Mh,
                                                  float* __restrict__ d2) {
  int b = blockIdx.y, n = blockIdx.x;
  const unsigned short* row = Mh + (size_t)b * NN * NN + (size_t)n * NN;
  int t = threadIdx.x;
  float s = 0.f;
#pragma unroll
  for (int i = 0; i < 8; ++i) {
    unsigned int u = *reinterpret_cast<const unsigned int*>(&row[(i * 256 + t) * 2]);
    s += __uint_as_float(u << 16) + __uint_as_float(u & 0xffff0000u);
  }
  for (int off = 32; off > 0; off >>= 1) s += __shfl_down(s, off);
  __shared__ float p4[4];
  int wid = t >> 6, lane = t & 63;
  if (lane == 0) p4[wid] = s;
  __syncthreads();
  if (t == 0) d2[b * NN + n] = 1.f / sqrtf(p4[0] + p4[1] + p4[2] + p4[3] + 1e-10f);
}

// ---------------------------------------------------------------------------
// K12a: zb[b][d][m] = bf16(feat[b][d][m] * d2[b][m])
// ---------------------------------------------------------------------------
__global__ void k_make_z(const float* __restrict__ feat, const float* __restrict__ d2,
                         unsigned short* __restrict__ zb) {
  int g = blockIdx.x * 256 + threadIdx.x;   // BB*DD*NN/4 threads
  int idx = g * 4;
  int b = idx / (DD * NN);
  int m = idx & (NN - 1);
  float4 f = *reinterpret_cast<const float4*>(&feat[idx]);
  const float* dd = d2 + b * NN + m;
  ushort4 o;
  o.x = f2b(f.x * dd[0]); o.y = f2b(f.y * dd[1]);
  o.z = f2b(f.z * dd[2]); o.w = f2b(f.w * dd[3]);
  *reinterpret_cast<ushort4*>(&zb[idx]) = o;
}

// K12b: convert projection weights to bf16
__global__ void k_prep_w(const float* __restrict__ w1, const float* __restrict__ w2,
                         unsigned short* __restrict__ wb1, unsigned short* __restrict__ wb2) {
  int g = blockIdx.x * 256 + threadIdx.x;   // DD*DD threads
  wb1[g] = f2b(w1[g]);
  wb2[g] = f2b(w2[g]);
}

// ---------------------------------------------------------------------------
// K13: new_feat via MFMA.  GEMM: M=d(64-tile), N=n(64-tile), K=m(4096).
// ---------------------------------------------------------------------------
__global__ __launch_bounds__(256) void k_newfeat_mfma(
    const unsigned short* __restrict__ Mh, const unsigned short* __restrict__ zb,
    const float* __restrict__ d2, unsigned short* __restrict__ nfh) {
  int b = blockIdx.z;
  int nblk = blockIdx.x;   // 64
  int dblk = blockIdx.y;   // 4
  const unsigned short* A = zb + (size_t)b * DD * NN + (size_t)(dblk * 64) * NN;
  const unsigned short* Bm = Mh + (size_t)b * NN * NN + (size_t)(nblk * 64) * NN;
  __shared__ unsigned short As[64][72];
  __shared__ unsigned short Bs[64][72];
  int t = threadIdx.x;
  int wave = t >> 6, lane = t & 63;
  int wd = (wave & 1) * 32, wn = (wave >> 1) * 32;
  int lrow = lane & 15, quad = lane >> 4;
  f32x4 acc[2][2] = {{{0.f,0.f,0.f,0.f},{0.f,0.f,0.f,0.f}},{{0.f,0.f,0.f,0.f},{0.f,0.f,0.f,0.f}}};
  int sr = t >> 3, sc = (t & 7) * 8;
  for (int m0 = 0; m0 < NN; m0 += 64) {
#pragma unroll
    for (int e = 0; e < 2; ++e) {
      int rr = sr + e * 32;
      *reinterpret_cast<int4*>(&As[rr][sc]) =
          *reinterpret_cast<const int4*>(&A[(size_t)rr * NN + m0 + sc]);
      *reinterpret_cast<int4*>(&Bs[rr][sc]) =
          *reinterpret_cast<const int4*>(&Bm[(size_t)rr * NN + m0 + sc]);
    }
    __syncthreads();
#pragma unroll
    for (int kc = 0; kc < 2; ++kc) {
      int ko = kc * 32 + quad * 8;
      bf16x8 af[2], bfr[2];
#pragma unroll
      for (int i = 0; i < 2; ++i) {
        af[i]  = *reinterpret_cast<const bf16x8*>(&As[wd + i * 16 + lrow][ko]);
        bfr[i] = *reinterpret_cast<const bf16x8*>(&Bs[wn + i * 16 + lrow][ko]);
      }
#pragma unroll
      for (int i = 0; i < 2; ++i)
#pragma unroll
        for (int j = 0; j < 2; ++j)
          acc[i][j] = __builtin_amdgcn_mfma_f32_16x16x32_bf16(af[i], bfr[j], acc[i][j], 0, 0, 0);
    }
    __syncthreads();
  }
#pragma unroll
  for (int j = 0; j < 2; ++j) {
    int n = nblk * 64 + wn + j * 16 + lrow;
    float sc2 = d2[b * NN + n];
#pragma unroll
    for (int i = 0; i < 2; ++i) {
      int d = dblk * 64 + wd + i * 16 + quad * 4;
      ushort4 v;
      v.x = f2b(acc[i][j].x * sc2); v.y = f2b(acc[i][j].y * sc2);
      v.z = f2b(acc[i][j].z * sc2); v.w = f2b(acc[i][j].w * sc2);
      *reinterpret_cast<ushort4*>(&nfh[((size_t)b * NN + n) * DD + d]) = v;
    }
  }
}

// ---------------------------------------------------------------------------
// K14: conv1 via MFMA. GEMM: M=n, N=o1, K=d.
// ---------------------------------------------------------------------------
__global__ __launch_bounds__(256) void k_conv1_mfma(
    const unsigned short* __restrict__ nfh, const unsigned short* __restrict__ wb1,
    const float* __restrict__ b1, unsigned short* __restrict__ midh) {
  int b = blockIdx.z;
  int nblk = blockIdx.x;   // 64
  int oblk = blockIdx.y;   // 4
  int n0 = nblk * 64, o0 = oblk * 64;
  __shared__ unsigned short As[64][72];
  __shared__ unsigned short Bs[64][72];
  int t = threadIdx.x;
  int wave = t >> 6, lane = t & 63;
  int wn = (wave & 1) * 32, wo = (wave >> 1) * 32;
  int lrow = lane & 15, quad = lane >> 4;
  f32x4 acc[2][2] = {{{0.f,0.f,0.f,0.f},{0.f,0.f,0.f,0.f}},{{0.f,0.f,0.f,0.f},{0.f,0.f,0.f,0.f}}};
  int sr = t >> 3, sc = (t & 7) * 8;
  for (int d0 = 0; d0 < DD; d0 += 64) {
#pragma unroll
    for (int e = 0; e < 2; ++e) {
      int rr = sr + e * 32;
      *reinterpret_cast<int4*>(&As[rr][sc]) =
          *reinterpret_cast<const int4*>(&nfh[((size_t)b * NN + n0 + rr) * DD + d0 + sc]);
      *reinterpret_cast<int4*>(&Bs[rr][sc]) =
          *reinterpret_cast<const int4*>(&wb1[(size_t)(o0 + rr) * DD + d0 + sc]);
    }
    __syncthreads();
#pragma unroll
    for (int kc = 0; kc < 2; ++kc) {
      int ko = kc * 32 + quad * 8;
      bf16x8 af[2], bfr[2];
#pragma unroll
      for (int i = 0; i < 2; ++i) {
        af[i]  = *reinterpret_cast<const bf16x8*>(&As[wn + i * 16 + lrow][ko]);
        bfr[i] = *reinterpret_cast<const bf16x8*>(&Bs[wo + i * 16 + lrow][ko]);
      }
#pragma unroll
      for (int i = 0; i < 2; ++i)
#pragma unroll
        for (int j = 0; j < 2; ++j)
          acc[i][j] = __builtin_amdgcn_mfma_f32_16x16x32_bf16(af[i], bfr[j], acc[i][j], 0, 0, 0);
    }
    __syncthreads();
  }
#pragma unroll
  for (int j = 0; j < 2; ++j) {
    int o = o0 + wo + j * 16 + lrow;
    float bias = b1[o];
#pragma unroll
    for (int i = 0; i < 2; ++i) {
      int nb = n0 + wn + i * 16 + quad * 4;
      ushort4 v;
      v.x = f2b(fmaxf(acc[i][j].x + bias, 0.f));
      v.y = f2b(fmaxf(acc[i][j].y + bias, 0.f));
      v.z = f2b(fmaxf(acc[i][j].z + bias, 0.f));
      v.w = f2b(fmaxf(acc[i][j].w + bias, 0.f));
      *reinterpret_cast<ushort4*>(&midh[((size_t)b * DD + o) * NN + nb]) = v;
    }
  }
}

// ---------------------------------------------------------------------------
// K15: conv2 via MFMA. GEMM: M=n, N=o2, K=o1.
// ---------------------------------------------------------------------------
__global__ __launch_bounds__(256) void k_conv2_mfma(
    const unsigned short* __restrict__ midh, const unsigned short* __restrict__ wb2,
    const float* __restrict__ b2, float* __restrict__ outp) {
  int b = blockIdx.z;
  int nblk = blockIdx.x;   // 64
  int oblk = blockIdx.y;   // 4
  int n0 = nblk * 64, o0 = oblk * 64;
  __shared__ unsigned short As[64][72];
  __shared__ unsigned short Bs[64][72];
  int t = threadIdx.x;
  int wave = t >> 6, lane = t & 63;
  int wn = (wave & 1) * 32, wo = (wave >> 1) * 32;
  int lrow = lane & 15, quad = lane >> 4;
  f32x4 acc[2][2] = {{{0.f,0.f,0.f,0.f},{0.f,0.f,0.f,0.f}},{{0.f,0.f,0.f,0.f},{0.f,0.f,0.f,0.f}}};
  int sr = t >> 3, sc = (t & 7) * 8;
  for (int d0 = 0; d0 < DD; d0 += 64) {
#pragma unroll
    for (int e = 0; e < 2; ++e) {
      int rr = sr + e * 32;
      *reinterpret_cast<int4*>(&Bs[rr][sc]) =
          *reinterpret_cast<const int4*>(&wb2[(size_t)(o0 + rr) * DD + d0 + sc]);
      unsigned short v[8];
      *reinterpret_cast<int4*>(v) =
          *reinterpret_cast<const int4*>(&midh[((size_t)b * DD + d0 + rr) * NN + n0 + sc]);
#pragma unroll
      for (int j = 0; j < 8; ++j) As[sc + j][rr] = v[j];
    }
    __syncthreads();
#pragma unroll
    for (int kc = 0; kc < 2; ++kc) {
      int ko = kc * 32 + quad * 8;
      bf16x8 af[2], bfr[2];
#pragma unroll
      for (int i = 0; i < 2; ++i) {
        af[i]  = *reinterpret_cast<const bf16x8*>(&As[wn + i * 16 + lrow][ko]);
        bfr[i] = *reinterpret_cast<const bf16x8*>(&Bs[wo + i * 16 + lrow][ko]);
      }
#pragma unroll
      for (int i = 0; i < 2; ++i)
#pragma unroll
        for (int j = 0; j < 2; ++j)
          acc[i][j] = __builtin_amdgcn_mfma_f32_16x16x32_bf16(af[i], bfr[j], acc[i][j], 0, 0, 0);
    }
    __syncthreads();
  }
#pragma unroll
  for (int j = 0; j < 2; ++j) {
    int o = o0 + wo + j * 16 + lrow;
    float bias = b2[o];
#pragma unroll
    for (int i = 0; i < 2; ++i) {
      int nb = n0 + wn + i * 16 + quad * 4;
      float4 v = make_float4(acc[i][j].x + bias, acc[i][j].y + bias,
                             acc[i][j].z + bias, acc[i][j].w + bias);
      *reinterpret_cast<float4*>(&outp[((size_t)b * DD + o) * NN + nb]) = v;
    }
  }
}

// ---------------------------------------------------------------------------
extern "C" void kernel_launch(void* const* d_in, const int* in_sizes, int n_in,
                              void* d_out, int out_size, void* d_ws, size_t ws_size,
                              hipStream_t stream) {
  (void)in_sizes; (void)n_in; (void)out_size; (void)ws_size;
  const float* pred   = (const float*)d_in[0];
  const float* feat   = (const float*)d_in[1];
  const float* w_cls1 = (const float*)d_in[2];
  const float* b_cls1 = (const float*)d_in[3];
  const float* w_cls2 = (const float*)d_in[4];
  const float* b_cls2 = (const float*)d_in[5];
  const float* w_pro1 = (const float*)d_in[6];
  const float* b_pro1 = (const float*)d_in[7];
  const float* w_pro2 = (const float*)d_in[8];
  const float* b_pro2 = (const float*)d_in[9];
  const float* cw     = (const float*)d_in[10];
  float* out = (float*)d_out;

  // workspace layout
  float* Mbuf = (float*)d_ws;                               // B*N*N fp32 (aff1 / packed-bf16 As / bf16 aff_f)
  float* xnT  = Mbuf + (size_t)BB * NN * NN;
  float* spnT = xnT + (size_t)BB * DD * NN;
  float* p2b  = spnT + (size_t)BB * CC * NN;
  float* thr  = p2b + (size_t)BB * NN * CC;
  float* dsum = thr + BB * NN;
  float* d2s  = dsum + BB * NN;
  float* maskb = d2s + BB * NN;
  unsigned int* ohbits = (unsigned int*)(maskb + BB * NN);
  unsigned short* nfh  = (unsigned short*)(ohbits + BB * NN);  // B*N*D bf16
  unsigned short* midh = nfh + (size_t)BB * NN * DD;           // B*D*N bf16
  unsigned short* zb   = midh + (size_t)BB * DD * NN;          // B*D*N bf16
  unsigned short* wb1  = zb + (size_t)BB * DD * NN;            // D*D bf16
  unsigned short* wb2  = wb1 + (size_t)DD * DD;                // D*D bf16
  unsigned short* ybh  = wb2 + (size_t)DD * DD;                // B*32*N bf16 (padded y)
  unsigned short* Mh   = (unsigned short*)Mbuf;

  hipMemsetAsync(dsum, 0, sizeof(float) * BB * NN, stream);
  hipMemsetAsync(ohbits, 0, sizeof(unsigned int) * BB * NN, stream);

  // --- pred branch ---
  k_mask_bits<<<BB * NN / 256, 256, 0, stream>>>(pred, cw, maskb, ohbits);
  k_norm_feat<<<BB * NN / 64, 64, 0, stream>>>(feat, xnT);
  k_gram1<<<dim3(528, BB), 256, 0, stream>>>(xnT, Mbuf);
  k_topk<<<dim3(NN, BB), 256, 0, stream>>>(Mbuf, thr);
  k_symm<<<dim3(2080, BB), 256, 0, stream>>>(Mbuf, thr, dsum);
  k_fin_d<<<BB * NN / 256, 256, 0, stream>>>(dsum);
  k_make_yb<<<BB * 32 * NN / 4 / 256, 256, 0, stream>>>(pred, dsum, ybh);
  k_p2_mfma<<<dim3(NN / 64, BB), 256, 0, stream>>>(Mbuf, ybh, dsum, p2b);
  k_pred_head<<<BB * NN / 256, 256, 0, stream>>>(pred, p2b, maskb, w_cls1, b_cls1,
                                                 w_cls2, b_cls2, out, spnT);
  // --- feat branch (bf16 MFMA) ---
  k_gram2<<<dim3(2080, BB), 256, 0, stream>>>(spnT, ohbits, Mh);
  k_rowsum2h<<<dim3(NN, BB), 256, 0, stream>>>(Mh, d2s);
  k_make_z<<<BB * DD * NN / 4 / 256, 256, 0, stream>>>(feat, d2s, zb);
  k_prep_w<<<DD * DD / 256, 256, 0, stream>>>(w_pro1, w_pro2, wb1, wb2);
  k_newfeat_mfma<<<dim3(64, 4, BB), 256, 0, stream>>>(Mh, zb, d2s, nfh);
  k_conv1_mfma<<<dim3(64, 4, BB), 256, 0, stream>>>(nfh, wb1, b_pro1, midh);
  k_conv2_mfma<<<dim3(64, 4, BB), 256, 0, stream>>>(midh, wb2, b_pro2,
                                                    out + (size_t)BB * CC * NN);
}

// Round 6
// 556.274 us; speedup vs baseline: 1.8521x; 1.1214x over previous
//
#include <hip/hip_runtime.h>

#define NN 4096   // H*W
#define DD 256    // feature channels
#define CC 19     // classes
#define BB 2      // batch

typedef __attribute__((ext_vector_type(8))) short bf16x8;   // MFMA A/B frag (4 VGPRs)
typedef __attribute__((ext_vector_type(4))) float f32x4;    // MFMA C/D frag

__device__ inline unsigned short f2b(float f) {   // fp32 -> bf16 RNE
  unsigned int u = __float_as_uint(f);
  return (unsigned short)((u + 0x7FFFu + ((u >> 16) & 1u)) >> 16);
}
__device__ inline float b2f(unsigned short h) {
  return __uint_as_float(((unsigned int)h) << 16);
}
__device__ inline unsigned int pack2(float a, float b) {
  return (unsigned int)f2b(a) | ((unsigned int)f2b(b) << 16);
}

// ---------------------------------------------------------------------------
// K1: softmax confidence mask + scrambled one-hot bitmasks
// ---------------------------------------------------------------------------
__global__ void k_mask_bits(const float* __restrict__ pred, const float* __restrict__ cw,
                            float* __restrict__ maskb, unsigned int* __restrict__ ohbits) {
  int g = blockIdx.x * 256 + threadIdx.x;
  if (g >= BB * NN) return;
  int b = g >> 12, n = g & (NN - 1);
  const float* p = pred + (size_t)b * CC * NN + n;
  float v[CC];
  float mx = -1e30f; int am = 0;
#pragma unroll
  for (int c = 0; c < CC; ++c) {
    float t = p[(size_t)c * NN];
    v[c] = t;
    if (t > mx) { mx = t; am = c; }
  }
  float s = 0.f;
#pragma unroll
  for (int c = 0; c < CC; ++c) s += expf(v[c] - mx);
  float pprob = 1.f / s;
  float cmax = 0.f;
#pragma unroll
  for (int c = 0; c < CC; ++c) cmax = fmaxf(cmax, cw[c]);
  float cwm = cw[am] / (cmax + 1e-10f) * 0.95f;
  maskb[g] = (pprob >= 0.95f || pprob >= cwm) ? 1.f : 0.f;
  // one_hot [B,H,W,C] -> transpose(0,2,3,1) -> [B,W,C,H] -> reshape(B,-1,19)
  int h = n >> 6, w = n & 63;
  int L = w * (CC * 64) + am * 64 + h;     // flat index in [W,C,H]
  atomicOr(&ohbits[b * NN + L / CC], 1u << (L % CC));
}

// ---------------------------------------------------------------------------
// K2: row-normalize features, stored transposed xnT[b][d][n]
// ---------------------------------------------------------------------------
__global__ void k_norm_feat(const float* __restrict__ feat, float* __restrict__ xnT) {
  int g = blockIdx.x * 64 + threadIdx.x;
  int b = g >> 12, n = g & (NN - 1);
  const float* f = feat + (size_t)b * DD * NN + n;
  float s = 0.f;
  for (int d = 0; d < DD; ++d) { float t = f[(size_t)d * NN]; s += t * t; }
  float r = 1.f / (sqrtf(s) + 1e-9f);
  float* o = xnT + (size_t)b * DD * NN + n;
  for (int d = 0; d < DD; ++d) o[(size_t)d * NN] = f[(size_t)d * NN] * r;
}

// ---------------------------------------------------------------------------
// K3: aff1 = clamp(Gram(xn), 0).  128x128 tiles, triangular grid.
// fp32 VALU (feeds discrete top-21 threshold; bf16 would flip edges).
// ---------------------------------------------------------------------------
__global__ __launch_bounds__(256) void k_gram1(const float* __restrict__ xnT, float* __restrict__ M) {
  int L = blockIdx.x;          // 0..527 triangular index (32 tiles/dim)
  int b = blockIdx.y;
  int I = 0;
  while (L >= 32 - I) { L -= 32 - I; ++I; }
  int J = I + L;
  const float* X = xnT + (size_t)b * DD * NN;
  float* Mb = M + (size_t)b * NN * NN;
  __shared__ float sA[16][128];
  __shared__ float sB[16][128];
  __shared__ float tr[32][132];
  int t = threadIdx.x;
  int r = t >> 4, c = t & 15;        // 16x16 thread grid, 8x8 acc each
  int i0 = I * 128, j0 = J * 128;
  float acc[8][8] = {};
  int lk = t >> 4, lcol = (t & 15) * 8;
  for (int k0 = 0; k0 < DD; k0 += 16) {
    const float* src = X + (size_t)(k0 + lk) * NN;
    *reinterpret_cast<float4*>(&sA[lk][lcol])     = *reinterpret_cast<const float4*>(&src[i0 + lcol]);
    *reinterpret_cast<float4*>(&sA[lk][lcol + 4]) = *reinterpret_cast<const float4*>(&src[i0 + lcol + 4]);
    *reinterpret_cast<float4*>(&sB[lk][lcol])     = *reinterpret_cast<const float4*>(&src[j0 + lcol]);
    *reinterpret_cast<float4*>(&sB[lk][lcol + 4]) = *reinterpret_cast<const float4*>(&src[j0 + lcol + 4]);
    __syncthreads();
#pragma unroll
    for (int k = 0; k < 16; ++k) {
      float av[8], bv[8];
      *reinterpret_cast<float4*>(&av[0]) = *reinterpret_cast<float4*>(&sA[k][r * 8]);
      *reinterpret_cast<float4*>(&av[4]) = *reinterpret_cast<float4*>(&sA[k][r * 8 + 4]);
      *reinterpret_cast<float4*>(&bv[0]) = *reinterpret_cast<float4*>(&sB[k][c * 8]);
      *reinterpret_cast<float4*>(&bv[4]) = *reinterpret_cast<float4*>(&sB[k][c * 8 + 4]);
#pragma unroll
      for (int i = 0; i < 8; ++i)
#pragma unroll
        for (int j = 0; j < 8; ++j) acc[i][j] += av[i] * bv[j];
    }
    __syncthreads();
  }
#pragma unroll
  for (int i = 0; i < 8; ++i)
#pragma unroll
    for (int j = 0; j < 8; ++j) acc[i][j] = fmaxf(acc[i][j], 0.f);
#pragma unroll
  for (int i = 0; i < 8; ++i) {
    float* dst = &Mb[(size_t)(i0 + r * 8 + i) * NN + j0 + c * 8];
    *reinterpret_cast<float4*>(dst)     = make_float4(acc[i][0], acc[i][1], acc[i][2], acc[i][3]);
    *reinterpret_cast<float4*>(dst + 4) = make_float4(acc[i][4], acc[i][5], acc[i][6], acc[i][7]);
  }
  if (I != J) {
    for (int ch = 0; ch < 4; ++ch) {
      if ((c >> 2) == ch) {
#pragma unroll
        for (int i = 0; i < 8; ++i)
#pragma unroll
          for (int j = 0; j < 8; ++j) tr[(c & 3) * 8 + j][r * 8 + i] = acc[i][j];
      }
      __syncthreads();
      int jj = t >> 3, cs = (t & 7) * 16;
#pragma unroll
      for (int q = 0; q < 4; ++q) {
        *reinterpret_cast<float4*>(&Mb[(size_t)(j0 + ch * 32 + jj) * NN + i0 + cs + q * 4]) =
            *reinterpret_cast<float4*>(&tr[jj][cs + q * 4]);
      }
      __syncthreads();
    }
  }
}

// ---------------------------------------------------------------------------
// K4: per-row 21st-largest value via bisection on the fp32 bit pattern.
// Row elements are >= 0 so uint bit order == float order; the largest u with
// count(x >= u) >= 21 is bit-exact the sort-descending index-20 value.
// Row lives in registers (16/thread); no LDS staging, no serial section.
// ---------------------------------------------------------------------------
__global__ __launch_bounds__(256) void k_topk(const float* __restrict__ M, float* __restrict__ thr) {
  int b = blockIdx.y, n = blockIdx.x;
  const float* row = M + (size_t)b * NN * NN + (size_t)n * NN;
  int t = threadIdx.x;
  unsigned int u[16];
#pragma unroll
  for (int e = 0; e < 4; ++e)
    *reinterpret_cast<uint4*>(&u[e * 4]) =
        *reinterpret_cast<const uint4*>(&row[t * 4 + e * 1024]);
  __shared__ int wsum[4];
  int lane = t & 63, wid = t >> 6;
  unsigned int lo = 0u, hi = 0x40000000u;   // values in [0, ~1.0]; 2.0f upper bound
  while (lo < hi) {
    unsigned int mid = lo + ((hi - lo + 1) >> 1);
    int c = 0;
#pragma unroll
    for (int i = 0; i < 16; ++i) c += (u[i] >= mid) ? 1 : 0;
#pragma unroll
    for (int off = 32; off > 0; off >>= 1) c += __shfl_down(c, off);
    if (lane == 0) wsum[wid] = c;
    __syncthreads();
    int tot = wsum[0] + wsum[1] + wsum[2] + wsum[3];
    __syncthreads();
    if (tot >= 21) lo = mid; else hi = mid - 1;
  }
  if (t == 0) thr[b * NN + n] = __uint_as_float(lo);
}

// ---------------------------------------------------------------------------
// K5: sparsify + symmetrize As = S + S^T.  Triangular grid.  Outputs:
//   - As as bf16 packed INSIDE each tile's own fp32 footprint (race-free):
//     element (row n, col g) at ushort idx 2*n*NN + 2*(g&~63) + (g&63)
//   - degree partial sums (fp32, pre-rounding) via atomics
// ---------------------------------------------------------------------------
__global__ __launch_bounds__(256) void k_symm(float* __restrict__ M, const float* __restrict__ thr,
                                              float* __restrict__ dsum) {
  int L = blockIdx.x;          // 0..2079 triangular index (64 tiles/dim)
  int b = blockIdx.y;
  int I = 0;
  while (L >= 64 - I) { L -= 64 - I; ++I; }
  int J = I + L;
  float* Mb = M + (size_t)b * NN * NN;
  unsigned short* Mus = (unsigned short*)Mb;
  const float* th = thr + b * NN;
  __shared__ float A[64][65];
  __shared__ float Bt[64][65];
  int t = threadIdx.x;
  int i0 = I * 64, j0 = J * 64;
  float areg[16];
#pragma unroll
  for (int e = 0; e < 16; ++e) {
    int lin = t + e * 256;
    int i = lin >> 6, j = lin & 63;
    areg[e] = Mb[(size_t)(i0 + i) * NN + j0 + j];
    Bt[i][j] = Mb[(size_t)(j0 + i) * NN + i0 + j];
  }
  __syncthreads();
#pragma unroll
  for (int e = 0; e < 16; ++e) {
    int lin = t + e * 256;
    int i = lin >> 6, j = lin & 63;
    float a = areg[e];
    float sa = (a >= th[i0 + i]) ? a : 0.f;
    float bt = Bt[j][i];
    float sb = (bt >= th[j0 + j]) ? bt : 0.f;
    A[i][j] = sa + sb;
  }
  __syncthreads();
  {
    int i = t >> 2, seg = (t & 3) * 16;
    float v[16];
#pragma unroll
    for (int q = 0; q < 4; ++q)
      *reinterpret_cast<float4*>(&v[q * 4]) = *reinterpret_cast<float4*>(&A[i][seg + q * 4]);
    unsigned int pk[8];
#pragma unroll
    for (int q = 0; q < 8; ++q) pk[q] = pack2(v[2 * q], v[2 * q + 1]);
    size_t ub = 2 * (size_t)(i0 + i) * NN + 2 * (size_t)j0 + seg;
    *reinterpret_cast<int4*>(&Mus[ub])     = *reinterpret_cast<int4*>(&pk[0]);
    *reinterpret_cast<int4*>(&Mus[ub + 8]) = *reinterpret_cast<int4*>(&pk[4]);
  }
  if (I != J) {
    int j = t >> 2, seg = (t & 3) * 16;
    float v[16];
#pragma unroll
    for (int e = 0; e < 16; ++e) v[e] = A[seg + e][j];
    unsigned int pk[8];
#pragma unroll
    for (int q = 0; q < 8; ++q) pk[q] = pack2(v[2 * q], v[2 * q + 1]);
    size_t ub = 2 * (size_t)(j0 + j) * NN + 2 * (size_t)i0 + seg;
    *reinterpret_cast<int4*>(&Mus[ub])     = *reinterpret_cast<int4*>(&pk[0]);
    *reinterpret_cast<int4*>(&Mus[ub + 8]) = *reinterpret_cast<int4*>(&pk[4]);
  }
  if (t < 64) {
    float s = 0.f;
#pragma unroll
    for (int j = 0; j < 64; ++j) s += A[t][j];
    atomicAdd(&dsum[b * NN + i0 + t], s);
  } else if (t < 128 && I != J) {
    int j = t - 64;
    float s = 0.f;
#pragma unroll
    for (int i = 0; i < 64; ++i) s += A[i][j];
    atomicAdd(&dsum[b * NN + j0 + j], s);
  }
}

// ---------------------------------------------------------------------------
// K6: d = (d + 1e-10)^-0.5
// ---------------------------------------------------------------------------
__global__ void k_fin_d(float* __restrict__ d) {
  int g = blockIdx.x * 256 + threadIdx.x;
  if (g < BB * NN) d[g] = 1.f / sqrtf(d[g] + 1e-10f);
}

// ---------------------------------------------------------------------------
// K7: ybh[b][c][n] = bf16(d1[b][n] * pred[b][c][n]), zero-padded to 32 classes
// ---------------------------------------------------------------------------
__global__ void k_make_yb(const float* __restrict__ pred, const float* __restrict__ d1,
                          unsigned short* __restrict__ ybh) {
  int g = blockIdx.x * 256 + threadIdx.x;   // BB*32*NN/4 threads
  int idx = g * 4;
  int b = idx / (32 * NN);
  int c = (idx / NN) & 31;
  int n = idx & (NN - 1);
  ushort4 o = make_ushort4(0, 0, 0, 0);
  if (c < CC) {
    float4 p = *reinterpret_cast<const float4*>(&pred[((size_t)b * CC + c) * NN + n]);
    const float* dd = d1 + b * NN + n;
    o.x = f2b(p.x * dd[0]); o.y = f2b(p.y * dd[1]);
    o.z = f2b(p.z * dd[2]); o.w = f2b(p.w * dd[3]);
  }
  *reinterpret_cast<ushort4*>(&ybh[idx]) = o;
}

// ---------------------------------------------------------------------------
// K8: p2 via MFMA.  GEMM: M=n (64-tile), N=c (32 padded), K=m (4096).
// ---------------------------------------------------------------------------
__global__ __launch_bounds__(256) void k_p2_mfma(
    const float* __restrict__ M, const unsigned short* __restrict__ ybh,
    const float* __restrict__ d1, float* __restrict__ p2b) {
  int b = blockIdx.y;
  int n0 = blockIdx.x * 64;
  const unsigned short* Mus = (const unsigned short*)(M + (size_t)b * NN * NN);
  const unsigned short* Y = ybh + (size_t)b * 32 * NN;
  __shared__ unsigned short As[64][72];
  __shared__ unsigned short Ys[32][72];
  int t = threadIdx.x;
  int wave = t >> 6, lane = t & 63;
  int wn = (wave & 1) * 32;      // n-offset in tile
  int wc = (wave >> 1) * 16;     // c-offset (0 or 16)
  int lrow = lane & 15, quad = lane >> 4;
  f32x4 acc[2] = {{0.f,0.f,0.f,0.f},{0.f,0.f,0.f,0.f}};
  int sr = t >> 3, scc = (t & 7) * 8;
  for (int m0 = 0; m0 < NN; m0 += 64) {
#pragma unroll
    for (int e = 0; e < 2; ++e) {
      int rr = sr + e * 32;
      *reinterpret_cast<int4*>(&As[rr][scc]) =
          *reinterpret_cast<const int4*>(&Mus[2 * (size_t)(n0 + rr) * NN + 2 * (size_t)m0 + scc]);
    }
    *reinterpret_cast<int4*>(&Ys[sr][scc]) =
        *reinterpret_cast<const int4*>(&Y[(size_t)sr * NN + m0 + scc]);
    __syncthreads();
#pragma unroll
    for (int kc = 0; kc < 2; ++kc) {
      int ko = kc * 32 + quad * 8;
      bf16x8 bfr = *reinterpret_cast<const bf16x8*>(&Ys[wc + lrow][ko]);
#pragma unroll
      for (int i = 0; i < 2; ++i) {
        bf16x8 af = *reinterpret_cast<const bf16x8*>(&As[wn + i * 16 + lrow][ko]);
        acc[i] = __builtin_amdgcn_mfma_f32_16x16x32_bf16(af, bfr, acc[i], 0, 0, 0);
      }
    }
    __syncthreads();
  }
  int c = wc + lrow;
  if (c < CC) {
#pragma unroll
    for (int i = 0; i < 2; ++i) {
#pragma unroll
      for (int reg = 0; reg < 4; ++reg) {
        int n = n0 + wn + i * 16 + quad * 4 + reg;
        p2b[((size_t)b * NN + n) * CC + c] = d1[b * NN + n] * acc[i][reg];
      }
    }
  }
}

// ---------------------------------------------------------------------------
// K9: fused blend + 19x19 conv x2 -> pred_out, then softmax + cosine-normalize
// ---------------------------------------------------------------------------
__global__ __launch_bounds__(256) void k_pred_head(const float* __restrict__ pred,
    const float* __restrict__ p2b, const float* __restrict__ maskb,
    const float* __restrict__ w1, const float* __restrict__ b1,
    const float* __restrict__ w2, const float* __restrict__ b2,
    float* __restrict__ out, float* __restrict__ spnT) {
  __shared__ float sw1[CC * CC], sw2[CC * CC], sb1[CC], sb2[CC];
  int t = threadIdx.x;
  for (int i = t; i < CC * CC; i += 256) { sw1[i] = w1[i]; sw2[i] = w2[i]; }
  if (t < CC) { sb1[t] = b1[t]; sb2[t] = b2[t]; }
  __syncthreads();
  int g = blockIdx.x * 256 + t;
  int b = g >> 12, n = g & (NN - 1);
  float m = maskb[g];
  float ca = (m > 0.5f) ? 0.2f : 0.8f;
  float cb = (m > 0.5f) ? 0.8f : 0.2f;
  const float* P = pred + (size_t)b * CC * NN + n;
  const float* Q = p2b + (size_t)g * CC;
  float p3[CC];
#pragma unroll
  for (int c = 0; c < CC; ++c) p3[c] = ca * Q[c] + cb * P[(size_t)c * NN];
  float midv[CC];
#pragma unroll
  for (int o = 0; o < CC; ++o) {
    float s = sb1[o];
#pragma unroll
    for (int c = 0; c < CC; ++c) s += sw1[o * CC + c] * p3[c];
    midv[o] = s;
  }
  float ov[CC];
  float mx = -1e30f;
#pragma unroll
  for (int o = 0; o < CC; ++o) {
    float s = sb2[o];
#pragma unroll
    for (int c = 0; c < CC; ++c) s += sw2[o * CC + c] * midv[c];
    ov[o] = s;
    out[(size_t)b * CC * NN + (size_t)o * NN + n] = s;
    mx = fmaxf(mx, s);
  }
  float se = 0.f;
  float e[CC];
#pragma unroll
  for (int o = 0; o < CC; ++o) { e[o] = expf(ov[o] - mx); se += e[o]; }
  float inv = 1.f / se;
  float nrm = 0.f;
#pragma unroll
  for (int o = 0; o < CC; ++o) { float sp = e[o] * inv; e[o] = sp; nrm += sp * sp; }
  float rn = 1.f / (sqrtf(nrm) + 1e-9f);
#pragma unroll
  for (int o = 0; o < CC; ++o) spnT[(size_t)b * CC * NN + (size_t)o * NN + n] = e[o] * rn;
}

// ---------------------------------------------------------------------------
// K10: aff_f = bitmask ? clamp(Gram(spn),0) : 0   (K=19), writes bf16.
// Triangular grid.
// ---------------------------------------------------------------------------
__global__ __launch_bounds__(256) void k_gram2(const float* __restrict__ spnT,
    const unsigned int* __restrict__ bits, unsigned short* __restrict__ Mh) {
  int L = blockIdx.x;          // 0..2079 triangular (64 tiles/dim)
  int b = blockIdx.y;
  int I = 0;
  while (L >= 64 - I) { L -= 64 - I; ++I; }
  int J = I + L;
  const float* X = spnT + (size_t)b * CC * NN;
  unsigned short* Mb = Mh + (size_t)b * NN * NN;
  __shared__ float sA[CC][64], sB[CC][64];
  __shared__ unsigned int bI[64], bJ[64];
  __shared__ float tr[64][65];
  int t = threadIdx.x;
  int r = t >> 4, c = t & 15;
  int i0 = I * 64, j0 = J * 64;
  for (int e = t; e < CC * 64; e += 256) {
    int k = e >> 6, col = e & 63;
    sA[k][col] = X[(size_t)k * NN + i0 + col];
    sB[k][col] = X[(size_t)k * NN + j0 + col];
  }
  if (t < 64) bI[t] = bits[b * NN + i0 + t];
  else if (t < 128) bJ[t - 64] = bits[b * NN + j0 + t - 64];
  __syncthreads();
  float acc[4][4] = {};
#pragma unroll
  for (int k = 0; k < CC; ++k) {
    float av[4], bv[4];
#pragma unroll
    for (int i = 0; i < 4; ++i) av[i] = sA[k][r * 4 + i];
#pragma unroll
    for (int j = 0; j < 4; ++j) bv[j] = sB[k][c * 4 + j];
#pragma unroll
    for (int i = 0; i < 4; ++i) {
#pragma unroll
      for (int j = 0; j < 4; ++j) acc[i][j] += av[i] * bv[j];
    }
  }
#pragma unroll
  for (int i = 0; i < 4; ++i) {
#pragma unroll
    for (int j = 0; j < 4; ++j) {
      bool keep = (bI[r * 4 + i] & bJ[c * 4 + j]) != 0u;
      acc[i][j] = keep ? fmaxf(acc[i][j], 0.f) : 0.f;
    }
    ushort4 v;
    v.x = f2b(acc[i][0]); v.y = f2b(acc[i][1]); v.z = f2b(acc[i][2]); v.w = f2b(acc[i][3]);
    *reinterpret_cast<ushort4*>(&Mb[(size_t)(i0 + r * 4 + i) * NN + j0 + c * 4]) = v;
  }
  if (I != J) {
#pragma unroll
    for (int i = 0; i < 4; ++i) {
#pragma unroll
      for (int j = 0; j < 4; ++j) tr[r * 4 + i][c * 4 + j] = acc[i][j];
    }
    __syncthreads();
#pragma unroll
    for (int e = 0; e < 16; ++e) {
      int lin = t + e * 256;
      int jr = lin >> 6, ic = lin & 63;
      Mb[(size_t)(j0 + jr) * NN + i0 + ic] = f2b(tr[ic][jr]);
    }
  }
}

// ---------------------------------------------------------------------------
// K11: d2[n] = (row_sum(aff_f bf16) + 1e-10)^-0.5
// ---------------------------------------------------------------------------
__global__ __launch_bounds__(256) void k_rowsum2h(const unsigned short* __restrict__ Mh,
                                                  float* __restrict__ d2) {
  int b = blockIdx.y, n = blockIdx.x;
  const unsigned short* row = Mh + (size_t)b * NN * NN + (size_t)n * NN;
  int t = threadIdx.x;
  float s = 0.f;
#pragma unroll
  for (int i = 0; i < 8; ++i) {
    unsigned int u = *reinterpret_cast<const unsigned int*>(&row[(i * 256 + t) * 2]);
    s += __uint_as_float(u << 16) + __uint_as_float(u & 0xffff0000u);
  }
  for (int off = 32; off > 0; off >>= 1) s += __shfl_down(s, off);
  __shared__ float p4[4];
  int wid = t >> 6, lane = t & 63;
  if (lane == 0) p4[wid] = s;
  __syncthreads();
  if (t == 0) d2[b * NN + n] = 1.f / sqrtf(p4[0] + p4[1] + p4[2] + p4[3] + 1e-10f);
}

// ---------------------------------------------------------------------------
// K12a: zb[b][d][m] = bf16(feat[b][d][m] * d2[b][m])
// ---------------------------------------------------------------------------
__global__ void k_make_z(const float* __restrict__ feat, const float* __restrict__ d2,
                         unsigned short* __restrict__ zb) {
  int g = blockIdx.x * 256 + threadIdx.x;   // BB*DD*NN/4 threads
  int idx = g * 4;
  int b = idx / (DD * NN);
  int m = idx & (NN - 1);
  float4 f = *reinterpret_cast<const float4*>(&feat[idx]);
  const float* dd = d2 + b * NN + m;
  ushort4 o;
  o.x = f2b(f.x * dd[0]); o.y = f2b(f.y * dd[1]);
  o.z = f2b(f.z * dd[2]); o.w = f2b(f.w * dd[3]);
  *reinterpret_cast<ushort4*>(&zb[idx]) = o;
}

// K12b: convert projection weights to bf16
__global__ void k_prep_w(const float* __restrict__ w1, const float* __restrict__ w2,
                         unsigned short* __restrict__ wb1, unsigned short* __restrict__ wb2) {
  int g = blockIdx.x * 256 + threadIdx.x;   // DD*DD threads
  wb1[g] = f2b(w1[g]);
  wb2[g] = f2b(w2[g]);
}

// ---------------------------------------------------------------------------
// K13: new_feat via MFMA.  GEMM: M=d(64-tile), N=n(64-tile), K=m(4096).
// ---------------------------------------------------------------------------
__global__ __launch_bounds__(256) void k_newfeat_mfma(
    const unsigned short* __restrict__ Mh, const unsigned short* __restrict__ zb,
    const float* __restrict__ d2, unsigned short* __restrict__ nfh) {
  int b = blockIdx.z;
  int nblk = blockIdx.x;   // 64
  int dblk = blockIdx.y;   // 4
  const unsigned short* A = zb + (size_t)b * DD * NN + (size_t)(dblk * 64) * NN;
  const unsigned short* Bm = Mh + (size_t)b * NN * NN + (size_t)(nblk * 64) * NN;
  __shared__ unsigned short As[64][72];
  __shared__ unsigned short Bs[64][72];
  int t = threadIdx.x;
  int wave = t >> 6, lane = t & 63;
  int wd = (wave & 1) * 32, wn = (wave >> 1) * 32;
  int lrow = lane & 15, quad = lane >> 4;
  f32x4 acc[2][2] = {{{0.f,0.f,0.f,0.f},{0.f,0.f,0.f,0.f}},{{0.f,0.f,0.f,0.f},{0.f,0.f,0.f,0.f}}};
  int sr = t >> 3, sc = (t & 7) * 8;
  for (int m0 = 0; m0 < NN; m0 += 64) {
#pragma unroll
    for (int e = 0; e < 2; ++e) {
      int rr = sr + e * 32;
      *reinterpret_cast<int4*>(&As[rr][sc]) =
          *reinterpret_cast<const int4*>(&A[(size_t)rr * NN + m0 + sc]);
      *reinterpret_cast<int4*>(&Bs[rr][sc]) =
          *reinterpret_cast<const int4*>(&Bm[(size_t)rr * NN + m0 + sc]);
    }
    __syncthreads();
#pragma unroll
    for (int kc = 0; kc < 2; ++kc) {
      int ko = kc * 32 + quad * 8;
      bf16x8 af[2], bfr[2];
#pragma unroll
      for (int i = 0; i < 2; ++i) {
        af[i]  = *reinterpret_cast<const bf16x8*>(&As[wd + i * 16 + lrow][ko]);
        bfr[i] = *reinterpret_cast<const bf16x8*>(&Bs[wn + i * 16 + lrow][ko]);
      }
#pragma unroll
      for (int i = 0; i < 2; ++i)
#pragma unroll
        for (int j = 0; j < 2; ++j)
          acc[i][j] = __builtin_amdgcn_mfma_f32_16x16x32_bf16(af[i], bfr[j], acc[i][j], 0, 0, 0);
    }
    __syncthreads();
  }
#pragma unroll
  for (int j = 0; j < 2; ++j) {
    int n = nblk * 64 + wn + j * 16 + lrow;
    float sc2 = d2[b * NN + n];
#pragma unroll
    for (int i = 0; i < 2; ++i) {
      int d = dblk * 64 + wd + i * 16 + quad * 4;
      ushort4 v;
      v.x = f2b(acc[i][j].x * sc2); v.y = f2b(acc[i][j].y * sc2);
      v.z = f2b(acc[i][j].z * sc2); v.w = f2b(acc[i][j].w * sc2);
      *reinterpret_cast<ushort4*>(&nfh[((size_t)b * NN + n) * DD + d]) = v;
    }
  }
}

// ---------------------------------------------------------------------------
// K14: conv1 via MFMA. GEMM: M=n, N=o1, K=d.
// ---------------------------------------------------------------------------
__global__ __launch_bounds__(256) void k_conv1_mfma(
    const unsigned short* __restrict__ nfh, const unsigned short* __restrict__ wb1,
    const float* __restrict__ b1, unsigned short* __restrict__ midh) {
  int b = blockIdx.z;
  int nblk = blockIdx.x;   // 64
  int oblk = blockIdx.y;   // 4
  int n0 = nblk * 64, o0 = oblk * 64;
  __shared__ unsigned short As[64][72];
  __shared__ unsigned short Bs[64][72];
  int t = threadIdx.x;
  int wave = t >> 6, lane = t & 63;
  int wn = (wave & 1) * 32, wo = (wave >> 1) * 32;
  int lrow = lane & 15, quad = lane >> 4;
  f32x4 acc[2][2] = {{{0.f,0.f,0.f,0.f},{0.f,0.f,0.f,0.f}},{{0.f,0.f,0.f,0.f},{0.f,0.f,0.f,0.f}}};
  int sr = t >> 3, sc = (t & 7) * 8;
  for (int d0 = 0; d0 < DD; d0 += 64) {
#pragma unroll
    for (int e = 0; e < 2; ++e) {
      int rr = sr + e * 32;
      *reinterpret_cast<int4*>(&As[rr][sc]) =
          *reinterpret_cast<const int4*>(&nfh[((size_t)b * NN + n0 + rr) * DD + d0 + sc]);
      *reinterpret_cast<int4*>(&Bs[rr][sc]) =
          *reinterpret_cast<const int4*>(&wb1[(size_t)(o0 + rr) * DD + d0 + sc]);
    }
    __syncthreads();
#pragma unroll
    for (int kc = 0; kc < 2; ++kc) {
      int ko = kc * 32 + quad * 8;
      bf16x8 af[2], bfr[2];
#pragma unroll
      for (int i = 0; i < 2; ++i) {
        af[i]  = *reinterpret_cast<const bf16x8*>(&As[wn + i * 16 + lrow][ko]);
        bfr[i] = *reinterpret_cast<const bf16x8*>(&Bs[wo + i * 16 + lrow][ko]);
      }
#pragma unroll
      for (int i = 0; i < 2; ++i)
#pragma unroll
        for (int j = 0; j < 2; ++j)
          acc[i][j] = __builtin_amdgcn_mfma_f32_16x16x32_bf16(af[i], bfr[j], acc[i][j], 0, 0, 0);
    }
    __syncthreads();
  }
#pragma unroll
  for (int j = 0; j < 2; ++j) {
    int o = o0 + wo + j * 16 + lrow;
    float bias = b1[o];
#pragma unroll
    for (int i = 0; i < 2; ++i) {
      int nb = n0 + wn + i * 16 + quad * 4;
      ushort4 v;
      v.x = f2b(fmaxf(acc[i][j].x + bias, 0.f));
      v.y = f2b(fmaxf(acc[i][j].y + bias, 0.f));
      v.z = f2b(fmaxf(acc[i][j].z + bias, 0.f));
      v.w = f2b(fmaxf(acc[i][j].w + bias, 0.f));
      *reinterpret_cast<ushort4*>(&midh[((size_t)b * DD + o) * NN + nb]) = v;
    }
  }
}

// ---------------------------------------------------------------------------
// K15: conv2 via MFMA. GEMM: M=n, N=o2, K=o1.
// ---------------------------------------------------------------------------
__global__ __launch_bounds__(256) void k_conv2_mfma(
    const unsigned short* __restrict__ midh, const unsigned short* __restrict__ wb2,
    const float* __restrict__ b2, float* __restrict__ outp) {
  int b = blockIdx.z;
  int nblk = blockIdx.x;   // 64
  int oblk = blockIdx.y;   // 4
  int n0 = nblk * 64, o0 = oblk * 64;
  __shared__ unsigned short As[64][72];
  __shared__ unsigned short Bs[64][72];
  int t = threadIdx.x;
  int wave = t >> 6, lane = t & 63;
  int wn = (wave & 1) * 32, wo = (wave >> 1) * 32;
  int lrow = lane & 15, quad = lane >> 4;
  f32x4 acc[2][2] = {{{0.f,0.f,0.f,0.f},{0.f,0.f,0.f,0.f}},{{0.f,0.f,0.f,0.f},{0.f,0.f,0.f,0.f}}};
  int sr = t >> 3, sc = (t & 7) * 8;
  for (int d0 = 0; d0 < DD; d0 += 64) {
#pragma unroll
    for (int e = 0; e < 2; ++e) {
      int rr = sr + e * 32;
      *reinterpret_cast<int4*>(&Bs[rr][sc]) =
          *reinterpret_cast<const int4*>(&wb2[(size_t)(o0 + rr) * DD + d0 + sc]);
      unsigned short v[8];
      *reinterpret_cast<int4*>(v) =
          *reinterpret_cast<const int4*>(&midh[((size_t)b * DD + d0 + rr) * NN + n0 + sc]);
#pragma unroll
      for (int j = 0; j < 8; ++j) As[sc + j][rr] = v[j];
    }
    __syncthreads();
#pragma unroll
    for (int kc = 0; kc < 2; ++kc) {
      int ko = kc * 32 + quad * 8;
      bf16x8 af[2], bfr[2];
#pragma unroll
      for (int i = 0; i < 2; ++i) {
        af[i]  = *reinterpret_cast<const bf16x8*>(&As[wn + i * 16 + lrow][ko]);
        bfr[i] = *reinterpret_cast<const bf16x8*>(&Bs[wo + i * 16 + lrow][ko]);
      }
#pragma unroll
      for (int i = 0; i < 2; ++i)
#pragma unroll
        for (int j = 0; j < 2; ++j)
          acc[i][j] = __builtin_amdgcn_mfma_f32_16x16x32_bf16(af[i], bfr[j], acc[i][j], 0, 0, 0);
    }
    __syncthreads();
  }
#pragma unroll
  for (int j = 0; j < 2; ++j) {
    int o = o0 + wo + j * 16 + lrow;
    float bias = b2[o];
#pragma unroll
    for (int i = 0; i < 2; ++i) {
      int nb = n0 + wn + i * 16 + quad * 4;
      float4 v = make_float4(acc[i][j].x + bias, acc[i][j].y + bias,
                             acc[i][j].z + bias, acc[i][j].w + bias);
      *reinterpret_cast<float4*>(&outp[((size_t)b * DD + o) * NN + nb]) = v;
    }
  }
}

// ---------------------------------------------------------------------------
extern "C" void kernel_launch(void* const* d_in, const int* in_sizes, int n_in,
                              void* d_out, int out_size, void* d_ws, size_t ws_size,
                              hipStream_t stream) {
  (void)in_sizes; (void)n_in; (void)out_size; (void)ws_size;
  const float* pred   = (const float*)d_in[0];
  const float* feat   = (const float*)d_in[1];
  const float* w_cls1 = (const float*)d_in[2];
  const float* b_cls1 = (const float*)d_in[3];
  const float* w_cls2 = (const float*)d_in[4];
  const float* b_cls2 = (const float*)d_in[5];
  const float* w_pro1 = (const float*)d_in[6];
  const float* b_pro1 = (const float*)d_in[7];
  const float* w_pro2 = (const float*)d_in[8];
  const float* b_pro2 = (const float*)d_in[9];
  const float* cw     = (const float*)d_in[10];
  float* out = (float*)d_out;

  // workspace layout
  float* Mbuf = (float*)d_ws;                               // B*N*N fp32 (aff1 / packed-bf16 As / bf16 aff_f)
  float* xnT  = Mbuf + (size_t)BB * NN * NN;
  float* spnT = xnT + (size_t)BB * DD * NN;
  float* p2b  = spnT + (size_t)BB * CC * NN;
  float* thr  = p2b + (size_t)BB * NN * CC;
  float* dsum = thr + BB * NN;
  float* d2s  = dsum + BB * NN;
  float* maskb = d2s + BB * NN;
  unsigned int* ohbits = (unsigned int*)(maskb + BB * NN);
  unsigned short* nfh  = (unsigned short*)(ohbits + BB * NN);  // B*N*D bf16
  unsigned short* midh = nfh + (size_t)BB * NN * DD;           // B*D*N bf16
  unsigned short* zb   = midh + (size_t)BB * DD * NN;          // B*D*N bf16
  unsigned short* wb1  = zb + (size_t)BB * DD * NN;            // D*D bf16
  unsigned short* wb2  = wb1 + (size_t)DD * DD;                // D*D bf16
  unsigned short* ybh  = wb2 + (size_t)DD * DD;                // B*32*N bf16 (padded y)
  unsigned short* Mh   = (unsigned short*)Mbuf;

  hipMemsetAsync(dsum, 0, sizeof(float) * BB * NN, stream);
  hipMemsetAsync(ohbits, 0, sizeof(unsigned int) * BB * NN, stream);

  // --- pred branch ---
  k_mask_bits<<<BB * NN / 256, 256, 0, stream>>>(pred, cw, maskb, ohbits);
  k_norm_feat<<<BB * NN / 64, 64, 0, stream>>>(feat, xnT);
  k_gram1<<<dim3(528, BB), 256, 0, stream>>>(xnT, Mbuf);
  k_topk<<<dim3(NN, BB), 256, 0, stream>>>(Mbuf, thr);
  k_symm<<<dim3(2080, BB), 256, 0, stream>>>(Mbuf, thr, dsum);
  k_fin_d<<<BB * NN / 256, 256, 0, stream>>>(dsum);
  k_make_yb<<<BB * 32 * NN / 4 / 256, 256, 0, stream>>>(pred, dsum, ybh);
  k_p2_mfma<<<dim3(NN / 64, BB), 256, 0, stream>>>(Mbuf, ybh, dsum, p2b);
  k_pred_head<<<BB * NN / 256, 256, 0, stream>>>(pred, p2b, maskb, w_cls1, b_cls1,
                                                 w_cls2, b_cls2, out, spnT);
  // --- feat branch (bf16 MFMA) ---
  k_gram2<<<dim3(2080, BB), 256, 0, stream>>>(spnT, ohbits, Mh);
  k_rowsum2h<<<dim3(NN, BB), 256, 0, stream>>>(Mh, d2s);
  k_make_z<<<BB * DD * NN / 4 / 256, 256, 0, stream>>>(feat, d2s, zb);
  k_prep_w<<<DD * DD / 256, 256, 0, stream>>>(w_pro1, w_pro2, wb1, wb2);
  k_newfeat_mfma<<<dim3(64, 4, BB), 256, 0, stream>>>(Mh, zb, d2s, nfh);
  k_conv1_mfma<<<dim3(64, 4, BB), 256, 0, stream>>>(nfh, wb1, b_pro1, midh);
  k_conv2_mfma<<<dim3(64, 4, BB), 256, 0, stream>>>(midh, wb2, b_pro2,
                                                    out + (size_t)BB * CC * NN);
}

// Round 7
// 519.272 us; speedup vs baseline: 1.9841x; 1.0713x over previous
//
#include <hip/hip_runtime.h>

#define NN 4096   // H*W
#define DD 256    // feature channels
#define CC 19     // classes
#define BB 2      // batch

typedef __attribute__((ext_vector_type(8))) short bf16x8;     // bf16 MFMA A/B frag
typedef _Float16 f16x8 __attribute__((ext_vector_type(8)));   // fp16 MFMA A/B frag
typedef __attribute__((ext_vector_type(4))) float f32x4;      // MFMA C/D frag

__device__ inline unsigned short f2b(float f) {   // fp32 -> bf16 RNE
  unsigned int u = __float_as_uint(f);
  return (unsigned short)((u + 0x7FFFu + ((u >> 16) & 1u)) >> 16);
}
__device__ inline float b2f(unsigned short h) {
  return __uint_as_float(((unsigned int)h) << 16);
}
__device__ inline unsigned int pack2(float a, float b) {
  return (unsigned int)f2b(a) | ((unsigned int)f2b(b) << 16);
}
// fp32 -> (fp16 hi, fp16 lo*2^11): hi+2^-11*lo carries ~22 mantissa bits
__device__ inline void split16(float x, unsigned short& h, unsigned short& l) {
  _Float16 hh = (_Float16)x;
  float hf = (float)hh;
  _Float16 ll = (_Float16)((x - hf) * 2048.0f);
  h = *reinterpret_cast<unsigned short*>(&hh);
  l = *reinterpret_cast<unsigned short*>(&ll);
}

// ---------------------------------------------------------------------------
// K1: softmax confidence mask + scrambled one-hot bitmasks
// ---------------------------------------------------------------------------
__global__ void k_mask_bits(const float* __restrict__ pred, const float* __restrict__ cw,
                            float* __restrict__ maskb, unsigned int* __restrict__ ohbits) {
  int g = blockIdx.x * 256 + threadIdx.x;
  if (g >= BB * NN) return;
  int b = g >> 12, n = g & (NN - 1);
  const float* p = pred + (size_t)b * CC * NN + n;
  float v[CC];
  float mx = -1e30f; int am = 0;
#pragma unroll
  for (int c = 0; c < CC; ++c) {
    float t = p[(size_t)c * NN];
    v[c] = t;
    if (t > mx) { mx = t; am = c; }
  }
  float s = 0.f;
#pragma unroll
  for (int c = 0; c < CC; ++c) s += expf(v[c] - mx);
  float pprob = 1.f / s;
  float cmax = 0.f;
#pragma unroll
  for (int c = 0; c < CC; ++c) cmax = fmaxf(cmax, cw[c]);
  float cwm = cw[am] / (cmax + 1e-10f) * 0.95f;
  maskb[g] = (pprob >= 0.95f || pprob >= cwm) ? 1.f : 0.f;
  int h = n >> 6, w = n & 63;
  int L = w * (CC * 64) + am * 64 + h;     // flat index in [W,C,H]
  atomicOr(&ohbits[b * NN + L / CC], 1u << (L % CC));
}

// ---------------------------------------------------------------------------
// K2: row-normalize features -> split fp16 hi/lo, stored [b][n][d] (d-major)
// ---------------------------------------------------------------------------
__global__ void k_norm_feat(const float* __restrict__ feat,
                            unsigned short* __restrict__ xh, unsigned short* __restrict__ xl) {
  int g = blockIdx.x * 64 + threadIdx.x;
  int b = g >> 12, n = g & (NN - 1);
  const float* f = feat + (size_t)b * DD * NN + n;
  float s = 0.f;
  for (int d = 0; d < DD; ++d) { float t = f[(size_t)d * NN]; s += t * t; }
  float r = 1.f / (sqrtf(s) + 1e-9f);
  size_t ob = ((size_t)b * NN + n) * DD;
  for (int d = 0; d < DD; d += 4) {
    ushort4 oh, ol;
    split16(f[(size_t)d * NN] * r, oh.x, ol.x);
    split16(f[(size_t)(d + 1) * NN] * r, oh.y, ol.y);
    split16(f[(size_t)(d + 2) * NN] * r, oh.z, ol.z);
    split16(f[(size_t)(d + 3) * NN] * r, oh.w, ol.w);
    *reinterpret_cast<ushort4*>(&xh[ob + d]) = oh;
    *reinterpret_cast<ushort4*>(&xl[ob + d]) = ol;
  }
}

// ---------------------------------------------------------------------------
// K3: aff1 = clamp(Gram(xn), 0) via 3-pass split-fp16 MFMA (~fp32 accuracy).
// 128x128 tiles, triangular grid; writes fp32 both tiles.
// ---------------------------------------------------------------------------
__global__ __launch_bounds__(256, 2) void k_gram1(const unsigned short* __restrict__ xh,
                                                  const unsigned short* __restrict__ xl,
                                                  float* __restrict__ M) {
  int L = blockIdx.x;          // 0..527 triangular (32 tiles/dim)
  int b = blockIdx.y;
  int I = 0;
  while (L >= 32 - I) { L -= 32 - I; ++I; }
  int J = I + L;
  int i0 = I * 128, j0 = J * 128;
  float* Mb = M + (size_t)b * NN * NN;
  const unsigned short* XH = xh + (size_t)b * NN * DD;
  const unsigned short* XL = xl + (size_t)b * NN * DD;
  __shared__ unsigned short stage[4 * 128 * 40];   // 40KB; rows padded to 40 ushort
  int t = threadIdx.x;
  int wave = t >> 6, lane = t & 63;
  int wr = (wave & 1) * 64, wc = (wave >> 1) * 64;
  int lrow = lane & 15, quad = lane >> 4;
  f32x4 accH[4][4] = {}, accL[4][4] = {};
  const unsigned short* src = (wave == 0) ? XH + (size_t)i0 * DD
                             : (wave == 1) ? XL + (size_t)i0 * DD
                             : (wave == 2) ? XH + (size_t)j0 * DD
                                           : XL + (size_t)j0 * DD;
  for (int k0 = 0; k0 < DD; k0 += 32) {
#pragma unroll
    for (int e = 0; e < 8; ++e) {
      int row = lane + 64 * (e & 1);
      int o = e >> 1;
      *reinterpret_cast<int4*>(&stage[(wave * 128 + row) * 40 + o * 8]) =
          *reinterpret_cast<const int4*>(&src[(size_t)row * DD + k0 + o * 8]);
    }
    __syncthreads();
    f16x8 ah[4], al[4], bh[4], bl[4];
#pragma unroll
    for (int i = 0; i < 4; ++i) {
      int ra = wr + i * 16 + lrow;
      int rb = wc + i * 16 + lrow;
      ah[i] = *reinterpret_cast<const f16x8*>(&stage[(0 * 128 + ra) * 40 + quad * 8]);
      al[i] = *reinterpret_cast<const f16x8*>(&stage[(1 * 128 + ra) * 40 + quad * 8]);
      bh[i] = *reinterpret_cast<const f16x8*>(&stage[(2 * 128 + rb) * 40 + quad * 8]);
      bl[i] = *reinterpret_cast<const f16x8*>(&stage[(3 * 128 + rb) * 40 + quad * 8]);
    }
#pragma unroll
    for (int i = 0; i < 4; ++i) {
#pragma unroll
      for (int j = 0; j < 4; ++j) {
        accH[i][j] = __builtin_amdgcn_mfma_f32_16x16x32_f16(ah[i], bh[j], accH[i][j], 0, 0, 0);
        accL[i][j] = __builtin_amdgcn_mfma_f32_16x16x32_f16(ah[i], bl[j], accL[i][j], 0, 0, 0);
        accL[i][j] = __builtin_amdgcn_mfma_f32_16x16x32_f16(al[i], bh[j], accL[i][j], 0, 0, 0);
      }
    }
    __syncthreads();
  }
  // combine + clamp (store result back into accH), write (I,J) tile
#pragma unroll
  for (int i = 0; i < 4; ++i) {
#pragma unroll
    for (int j = 0; j < 4; ++j) {
#pragma unroll
      for (int reg = 0; reg < 4; ++reg) {
        float v = fmaxf(accH[i][j][reg] + accL[i][j][reg] * 4.8828125e-4f, 0.f);
        accH[i][j][reg] = v;
        Mb[(size_t)(i0 + wr + i * 16 + quad * 4 + reg) * NN + j0 + wc + j * 16 + lrow] = v;
      }
    }
  }
  // mirror tile (J,I) via LDS transpose in two 64-row chunks
  if (I != J) {
    float* trf = (float*)stage;   // [64][130] = 33.3KB <= 40KB
    for (int half = 0; half < 2; ++half) {
      __syncthreads();
      if ((wc >> 6) == half) {
#pragma unroll
        for (int i = 0; i < 4; ++i)
#pragma unroll
          for (int j = 0; j < 4; ++j)
#pragma unroll
            for (int reg = 0; reg < 4; ++reg)
              trf[(j * 16 + lrow) * 130 + wr + i * 16 + quad * 4 + reg] = accH[i][j][reg];
      }
      __syncthreads();
      int r = t >> 2, cbase = (t & 3) * 32;
#pragma unroll
      for (int q = 0; q < 8; ++q) {
        *reinterpret_cast<float4*>(&Mb[(size_t)(j0 + half * 64 + r) * NN + i0 + cbase + q * 4]) =
            *reinterpret_cast<float4*>(&trf[r * 130 + cbase + q * 4]);
      }
    }
  }
}

// ---------------------------------------------------------------------------
// K4: per-row 21st-largest value via bisection on the fp32 bit pattern.
// ---------------------------------------------------------------------------
__global__ __launch_bounds__(256) void k_topk(const float* __restrict__ M, float* __restrict__ thr) {
  int b = blockIdx.y, n = blockIdx.x;
  const float* row = M + (size_t)b * NN * NN + (size_t)n * NN;
  int t = threadIdx.x;
  unsigned int u[16];
#pragma unroll
  for (int e = 0; e < 4; ++e)
    *reinterpret_cast<uint4*>(&u[e * 4]) =
        *reinterpret_cast<const uint4*>(&row[t * 4 + e * 1024]);
  __shared__ int wsum[4];
  int lane = t & 63, wid = t >> 6;
  unsigned int lo = 0u, hi = 0x40000000u;
  while (lo < hi) {
    unsigned int mid = lo + ((hi - lo + 1) >> 1);
    int c = 0;
#pragma unroll
    for (int i = 0; i < 16; ++i) c += (u[i] >= mid) ? 1 : 0;
#pragma unroll
    for (int off = 32; off > 0; off >>= 1) c += __shfl_down(c, off);
    if (lane == 0) wsum[wid] = c;
    __syncthreads();
    int tot = wsum[0] + wsum[1] + wsum[2] + wsum[3];
    __syncthreads();
    if (tot >= 21) lo = mid; else hi = mid - 1;
  }
  if (t == 0) thr[b * NN + n] = __uint_as_float(lo);
}

// ---------------------------------------------------------------------------
// K5: sparsify + symmetrize As = S + S^T; bf16 packed in-place; degree sums
// ---------------------------------------------------------------------------
__global__ __launch_bounds__(256) void k_symm(float* __restrict__ M, const float* __restrict__ thr,
                                              float* __restrict__ dsum) {
  int L = blockIdx.x;          // 0..2079 triangular (64 tiles/dim)
  int b = blockIdx.y;
  int I = 0;
  while (L >= 64 - I) { L -= 64 - I; ++I; }
  int J = I + L;
  float* Mb = M + (size_t)b * NN * NN;
  unsigned short* Mus = (unsigned short*)Mb;
  const float* th = thr + b * NN;
  __shared__ float A[64][65];
  __shared__ float Bt[64][65];
  int t = threadIdx.x;
  int i0 = I * 64, j0 = J * 64;
  float areg[16];
#pragma unroll
  for (int e = 0; e < 16; ++e) {
    int lin = t + e * 256;
    int i = lin >> 6, j = lin & 63;
    areg[e] = Mb[(size_t)(i0 + i) * NN + j0 + j];
    Bt[i][j] = Mb[(size_t)(j0 + i) * NN + i0 + j];
  }
  __syncthreads();
#pragma unroll
  for (int e = 0; e < 16; ++e) {
    int lin = t + e * 256;
    int i = lin >> 6, j = lin & 63;
    float a = areg[e];
    float sa = (a >= th[i0 + i]) ? a : 0.f;
    float bt = Bt[j][i];
    float sb = (bt >= th[j0 + j]) ? bt : 0.f;
    A[i][j] = sa + sb;
  }
  __syncthreads();
  {
    int i = t >> 2, seg = (t & 3) * 16;
    float v[16];
#pragma unroll
    for (int q = 0; q < 4; ++q)
      *reinterpret_cast<float4*>(&v[q * 4]) = *reinterpret_cast<float4*>(&A[i][seg + q * 4]);
    unsigned int pk[8];
#pragma unroll
    for (int q = 0; q < 8; ++q) pk[q] = pack2(v[2 * q], v[2 * q + 1]);
    size_t ub = 2 * (size_t)(i0 + i) * NN + 2 * (size_t)j0 + seg;
    *reinterpret_cast<int4*>(&Mus[ub])     = *reinterpret_cast<int4*>(&pk[0]);
    *reinterpret_cast<int4*>(&Mus[ub + 8]) = *reinterpret_cast<int4*>(&pk[4]);
  }
  if (I != J) {
    int j = t >> 2, seg = (t & 3) * 16;
    float v[16];
#pragma unroll
    for (int e = 0; e < 16; ++e) v[e] = A[seg + e][j];
    unsigned int pk[8];
#pragma unroll
    for (int q = 0; q < 8; ++q) pk[q] = pack2(v[2 * q], v[2 * q + 1]);
    size_t ub = 2 * (size_t)(j0 + j) * NN + 2 * (size_t)i0 + seg;
    *reinterpret_cast<int4*>(&Mus[ub])     = *reinterpret_cast<int4*>(&pk[0]);
    *reinterpret_cast<int4*>(&Mus[ub + 8]) = *reinterpret_cast<int4*>(&pk[4]);
  }
  if (t < 64) {
    float s = 0.f;
#pragma unroll
    for (int j = 0; j < 64; ++j) s += A[t][j];
    atomicAdd(&dsum[b * NN + i0 + t], s);
  } else if (t < 128 && I != J) {
    int j = t - 64;
    float s = 0.f;
#pragma unroll
    for (int i = 0; i < 64; ++i) s += A[i][j];
    atomicAdd(&dsum[b * NN + j0 + j], s);
  }
}

// ---------------------------------------------------------------------------
// K6: d = (d + 1e-10)^-0.5
// ---------------------------------------------------------------------------
__global__ void k_fin_d(float* __restrict__ d) {
  int g = blockIdx.x * 256 + threadIdx.x;
  if (g < BB * NN) d[g] = 1.f / sqrtf(d[g] + 1e-10f);
}

// ---------------------------------------------------------------------------
// K7: ybh[b][c][n] = bf16(d1[b][n] * pred[b][c][n]), zero-padded to 32 classes
// ---------------------------------------------------------------------------
__global__ void k_make_yb(const float* __restrict__ pred, const float* __restrict__ d1,
                          unsigned short* __restrict__ ybh) {
  int g = blockIdx.x * 256 + threadIdx.x;   // BB*32*NN/4 threads
  int idx = g * 4;
  int b = idx / (32 * NN);
  int c = (idx / NN) & 31;
  int n = idx & (NN - 1);
  ushort4 o = make_ushort4(0, 0, 0, 0);
  if (c < CC) {
    float4 p = *reinterpret_cast<const float4*>(&pred[((size_t)b * CC + c) * NN + n]);
    const float* dd = d1 + b * NN + n;
    o.x = f2b(p.x * dd[0]); o.y = f2b(p.y * dd[1]);
    o.z = f2b(p.z * dd[2]); o.w = f2b(p.w * dd[3]);
  }
  *reinterpret_cast<ushort4*>(&ybh[idx]) = o;
}

// ---------------------------------------------------------------------------
// K8: p2 via MFMA.  GEMM: M=n (64-tile), N=c (32 padded), K=m (4096).
// ---------------------------------------------------------------------------
__global__ __launch_bounds__(256) void k_p2_mfma(
    const float* __restrict__ M, const unsigned short* __restrict__ ybh,
    const float* __restrict__ d1, float* __restrict__ p2b) {
  int b = blockIdx.y;
  int n0 = blockIdx.x * 64;
  const unsigned short* Mus = (const unsigned short*)(M + (size_t)b * NN * NN);
  const unsigned short* Y = ybh + (size_t)b * 32 * NN;
  __shared__ unsigned short As[64][72];
  __shared__ unsigned short Ys[32][72];
  int t = threadIdx.x;
  int wave = t >> 6, lane = t & 63;
  int wn = (wave & 1) * 32;
  int wc = (wave >> 1) * 16;
  int lrow = lane & 15, quad = lane >> 4;
  f32x4 acc[2] = {{0.f,0.f,0.f,0.f},{0.f,0.f,0.f,0.f}};
  int sr = t >> 3, scc = (t & 7) * 8;
  for (int m0 = 0; m0 < NN; m0 += 64) {
#pragma unroll
    for (int e = 0; e < 2; ++e) {
      int rr = sr + e * 32;
      *reinterpret_cast<int4*>(&As[rr][scc]) =
          *reinterpret_cast<const int4*>(&Mus[2 * (size_t)(n0 + rr) * NN + 2 * (size_t)m0 + scc]);
    }
    *reinterpret_cast<int4*>(&Ys[sr][scc]) =
        *reinterpret_cast<const int4*>(&Y[(size_t)sr * NN + m0 + scc]);
    __syncthreads();
#pragma unroll
    for (int kc = 0; kc < 2; ++kc) {
      int ko = kc * 32 + quad * 8;
      bf16x8 bfr = *reinterpret_cast<const bf16x8*>(&Ys[wc + lrow][ko]);
#pragma unroll
      for (int i = 0; i < 2; ++i) {
        bf16x8 af = *reinterpret_cast<const bf16x8*>(&As[wn + i * 16 + lrow][ko]);
        acc[i] = __builtin_amdgcn_mfma_f32_16x16x32_bf16(af, bfr, acc[i], 0, 0, 0);
      }
    }
    __syncthreads();
  }
  int c = wc + lrow;
  if (c < CC) {
#pragma unroll
    for (int i = 0; i < 2; ++i) {
#pragma unroll
      for (int reg = 0; reg < 4; ++reg) {
        int n = n0 + wn + i * 16 + quad * 4 + reg;
        p2b[((size_t)b * NN + n) * CC + c] = d1[b * NN + n] * acc[i][reg];
      }
    }
  }
}

// ---------------------------------------------------------------------------
// K9: fused blend + 19x19 conv x2 -> pred_out, then softmax + cosine-normalize
// ---------------------------------------------------------------------------
__global__ __launch_bounds__(256) void k_pred_head(const float* __restrict__ pred,
    const float* __restrict__ p2b, const float* __restrict__ maskb,
    const float* __restrict__ w1, const float* __restrict__ b1,
    const float* __restrict__ w2, const float* __restrict__ b2,
    float* __restrict__ out, float* __restrict__ spnT) {
  __shared__ float sw1[CC * CC], sw2[CC * CC], sb1[CC], sb2[CC];
  int t = threadIdx.x;
  for (int i = t; i < CC * CC; i += 256) { sw1[i] = w1[i]; sw2[i] = w2[i]; }
  if (t < CC) { sb1[t] = b1[t]; sb2[t] = b2[t]; }
  __syncthreads();
  int g = blockIdx.x * 256 + t;
  int b = g >> 12, n = g & (NN - 1);
  float m = maskb[g];
  float ca = (m > 0.5f) ? 0.2f : 0.8f;
  float cb = (m > 0.5f) ? 0.8f : 0.2f;
  const float* P = pred + (size_t)b * CC * NN + n;
  const float* Q = p2b + (size_t)g * CC;
  float p3[CC];
#pragma unroll
  for (int c = 0; c < CC; ++c) p3[c] = ca * Q[c] + cb * P[(size_t)c * NN];
  float midv[CC];
#pragma unroll
  for (int o = 0; o < CC; ++o) {
    float s = sb1[o];
#pragma unroll
    for (int c = 0; c < CC; ++c) s += sw1[o * CC + c] * p3[c];
    midv[o] = s;
  }
  float ov[CC];
  float mx = -1e30f;
#pragma unroll
  for (int o = 0; o < CC; ++o) {
    float s = sb2[o];
#pragma unroll
    for (int c = 0; c < CC; ++c) s += sw2[o * CC + c] * midv[c];
    ov[o] = s;
    out[(size_t)b * CC * NN + (size_t)o * NN + n] = s;
    mx = fmaxf(mx, s);
  }
  float se = 0.f;
  float e[CC];
#pragma unroll
  for (int o = 0; o < CC; ++o) { e[o] = expf(ov[o] - mx); se += e[o]; }
  float inv = 1.f / se;
  float nrm = 0.f;
#pragma unroll
  for (int o = 0; o < CC; ++o) { float sp = e[o] * inv; e[o] = sp; nrm += sp * sp; }
  float rn = 1.f / (sqrtf(nrm) + 1e-9f);
#pragma unroll
  for (int o = 0; o < CC; ++o) spnT[(size_t)b * CC * NN + (size_t)o * NN + n] = e[o] * rn;
}

// ---------------------------------------------------------------------------
// K10: aff_f = bitmask ? clamp(Gram(spn),0) : 0   (K=19), writes bf16.
// ---------------------------------------------------------------------------
__global__ __launch_bounds__(256) void k_gram2(const float* __restrict__ spnT,
    const unsigned int* __restrict__ bits, unsigned short* __restrict__ Mh) {
  int L = blockIdx.x;          // 0..2079 triangular (64 tiles/dim)
  int b = blockIdx.y;
  int I = 0;
  while (L >= 64 - I) { L -= 64 - I; ++I; }
  int J = I + L;
  const float* X = spnT + (size_t)b * CC * NN;
  unsigned short* Mb = Mh + (size_t)b * NN * NN;
  __shared__ float sA[CC][64], sB[CC][64];
  __shared__ unsigned int bI[64], bJ[64];
  __shared__ float tr[64][65];
  int t = threadIdx.x;
  int r = t >> 4, c = t & 15;
  int i0 = I * 64, j0 = J * 64;
  for (int e = t; e < CC * 64; e += 256) {
    int k = e >> 6, col = e & 63;
    sA[k][col] = X[(size_t)k * NN + i0 + col];
    sB[k][col] = X[(size_t)k * NN + j0 + col];
  }
  if (t < 64) bI[t] = bits[b * NN + i0 + t];
  else if (t < 128) bJ[t - 64] = bits[b * NN + j0 + t - 64];
  __syncthreads();
  float acc[4][4] = {};
#pragma unroll
  for (int k = 0; k < CC; ++k) {
    float av[4], bv[4];
#pragma unroll
    for (int i = 0; i < 4; ++i) av[i] = sA[k][r * 4 + i];
#pragma unroll
    for (int j = 0; j < 4; ++j) bv[j] = sB[k][c * 4 + j];
#pragma unroll
    for (int i = 0; i < 4; ++i) {
#pragma unroll
      for (int j = 0; j < 4; ++j) acc[i][j] += av[i] * bv[j];
    }
  }
#pragma unroll
  for (int i = 0; i < 4; ++i) {
#pragma unroll
    for (int j = 0; j < 4; ++j) {
      bool keep = (bI[r * 4 + i] & bJ[c * 4 + j]) != 0u;
      acc[i][j] = keep ? fmaxf(acc[i][j], 0.f) : 0.f;
    }
    ushort4 v;
    v.x = f2b(acc[i][0]); v.y = f2b(acc[i][1]); v.z = f2b(acc[i][2]); v.w = f2b(acc[i][3]);
    *reinterpret_cast<ushort4*>(&Mb[(size_t)(i0 + r * 4 + i) * NN + j0 + c * 4]) = v;
  }
  if (I != J) {
#pragma unroll
    for (int i = 0; i < 4; ++i) {
#pragma unroll
      for (int j = 0; j < 4; ++j) tr[r * 4 + i][c * 4 + j] = acc[i][j];
    }
    __syncthreads();
#pragma unroll
    for (int e = 0; e < 16; ++e) {
      int lin = t + e * 256;
      int jr = lin >> 6, ic = lin & 63;
      Mb[(size_t)(j0 + jr) * NN + i0 + ic] = f2b(tr[ic][jr]);
    }
  }
}

// ---------------------------------------------------------------------------
// K11: d2[n] = (row_sum(aff_f bf16) + 1e-10)^-0.5
// ---------------------------------------------------------------------------
__global__ __launch_bounds__(256) void k_rowsum2h(const unsigned short* __restrict__ Mh,
                                                  float* __restrict__ d2) {
  int b = blockIdx.y, n = blockIdx.x;
  const unsigned short* row = Mh + (size_t)b * NN * NN + (size_t)n * NN;
  int t = threadIdx.x;
  float s = 0.f;
#pragma unroll
  for (int i = 0; i < 8; ++i) {
    unsigned int u = *reinterpret_cast<const unsigned int*>(&row[(i * 256 + t) * 2]);
    s += __uint_as_float(u << 16) + __uint_as_float(u & 0xffff0000u);
  }
  for (int off = 32; off > 0; off >>= 1) s += __shfl_down(s, off);
  __shared__ float p4[4];
  int wid = t >> 6, lane = t & 63;
  if (lane == 0) p4[wid] = s;
  __syncthreads();
  if (t == 0) d2[b * NN + n] = 1.f / sqrtf(p4[0] + p4[1] + p4[2] + p4[3] + 1e-10f);
}

// ---------------------------------------------------------------------------
// K12a: zb[b][d][m] = bf16(feat[b][d][m] * d2[b][m])
// ---------------------------------------------------------------------------
__global__ void k_make_z(const float* __restrict__ feat, const float* __restrict__ d2,
                         unsigned short* __restrict__ zb) {
  int g = blockIdx.x * 256 + threadIdx.x;   // BB*DD*NN/4 threads
  int idx = g * 4;
  int b = idx / (DD * NN);
  int m = idx & (NN - 1);
  float4 f = *reinterpret_cast<const float4*>(&feat[idx]);
  const float* dd = d2 + b * NN + m;
  ushort4 o;
  o.x = f2b(f.x * dd[0]); o.y = f2b(f.y * dd[1]);
  o.z = f2b(f.z * dd[2]); o.w = f2b(f.w * dd[3]);
  *reinterpret_cast<ushort4*>(&zb[idx]) = o;
}

// K12b: convert projection weights to bf16
__global__ void k_prep_w(const float* __restrict__ w1, const float* __restrict__ w2,
                         unsigned short* __restrict__ wb1, unsigned short* __restrict__ wb2) {
  int g = blockIdx.x * 256 + threadIdx.x;   // DD*DD threads
  wb1[g] = f2b(w1[g]);
  wb2[g] = f2b(w2[g]);
}

// ---------------------------------------------------------------------------
// K13: new_feat via MFMA.  GEMM: M=d(64-tile), N=n(64-tile), K=m(4096).
// ---------------------------------------------------------------------------
__global__ __launch_bounds__(256) void k_newfeat_mfma(
    const unsigned short* __restrict__ Mh, const unsigned short* __restrict__ zb,
    const float* __restrict__ d2, unsigned short* __restrict__ nfh) {
  int b = blockIdx.z;
  int nblk = blockIdx.x;   // 64
  int dblk = blockIdx.y;   // 4
  const unsigned short* A = zb + (size_t)b * DD * NN + (size_t)(dblk * 64) * NN;
  const unsigned short* Bm = Mh + (size_t)b * NN * NN + (size_t)(nblk * 64) * NN;
  __shared__ unsigned short As[64][72];
  __shared__ unsigned short Bs[64][72];
  int t = threadIdx.x;
  int wave = t >> 6, lane = t & 63;
  int wd = (wave & 1) * 32, wn = (wave >> 1) * 32;
  int lrow = lane & 15, quad = lane >> 4;
  f32x4 acc[2][2] = {{{0.f,0.f,0.f,0.f},{0.f,0.f,0.f,0.f}},{{0.f,0.f,0.f,0.f},{0.f,0.f,0.f,0.f}}};
  int sr = t >> 3, sc = (t & 7) * 8;
  for (int m0 = 0; m0 < NN; m0 += 64) {
#pragma unroll
    for (int e = 0; e < 2; ++e) {
      int rr = sr + e * 32;
      *reinterpret_cast<int4*>(&As[rr][sc]) =
          *reinterpret_cast<const int4*>(&A[(size_t)rr * NN + m0 + sc]);
      *reinterpret_cast<int4*>(&Bs[rr][sc]) =
          *reinterpret_cast<const int4*>(&Bm[(size_t)rr * NN + m0 + sc]);
    }
    __syncthreads();
#pragma unroll
    for (int kc = 0; kc < 2; ++kc) {
      int ko = kc * 32 + quad * 8;
      bf16x8 af[2], bfr[2];
#pragma unroll
      for (int i = 0; i < 2; ++i) {
        af[i]  = *reinterpret_cast<const bf16x8*>(&As[wd + i * 16 + lrow][ko]);
        bfr[i] = *reinterpret_cast<const bf16x8*>(&Bs[wn + i * 16 + lrow][ko]);
      }
#pragma unroll
      for (int i = 0; i < 2; ++i)
#pragma unroll
        for (int j = 0; j < 2; ++j)
          acc[i][j] = __builtin_amdgcn_mfma_f32_16x16x32_bf16(af[i], bfr[j], acc[i][j], 0, 0, 0);
    }
    __syncthreads();
  }
#pragma unroll
  for (int j = 0; j < 2; ++j) {
    int n = nblk * 64 + wn + j * 16 + lrow;
    float sc2 = d2[b * NN + n];
#pragma unroll
    for (int i = 0; i < 2; ++i) {
      int d = dblk * 64 + wd + i * 16 + quad * 4;
      ushort4 v;
      v.x = f2b(acc[i][j].x * sc2); v.y = f2b(acc[i][j].y * sc2);
      v.z = f2b(acc[i][j].z * sc2); v.w = f2b(acc[i][j].w * sc2);
      *reinterpret_cast<ushort4*>(&nfh[((size_t)b * NN + n) * DD + d]) = v;
    }
  }
}

// ---------------------------------------------------------------------------
// K14: conv1 via MFMA. GEMM: M=n, N=o1, K=d.
// ---------------------------------------------------------------------------
__global__ __launch_bounds__(256) void k_conv1_mfma(
    const unsigned short* __restrict__ nfh, const unsigned short* __restrict__ wb1,
    const float* __restrict__ b1, unsigned short* __restrict__ midh) {
  int b = blockIdx.z;
  int nblk = blockIdx.x;   // 64
  int oblk = blockIdx.y;   // 4
  int n0 = nblk * 64, o0 = oblk * 64;
  __shared__ unsigned short As[64][72];
  __shared__ unsigned short Bs[64][72];
  int t = threadIdx.x;
  int wave = t >> 6, lane = t & 63;
  int wn = (wave & 1) * 32, wo = (wave >> 1) * 32;
  int lrow = lane & 15, quad = lane >> 4;
  f32x4 acc[2][2] = {{{0.f,0.f,0.f,0.f},{0.f,0.f,0.f,0.f}},{{0.f,0.f,0.f,0.f},{0.f,0.f,0.f,0.f}}};
  int sr = t >> 3, sc = (t & 7) * 8;
  for (int d0 = 0; d0 < DD; d0 += 64) {
#pragma unroll
    for (int e = 0; e < 2; ++e) {
      int rr = sr + e * 32;
      *reinterpret_cast<int4*>(&As[rr][sc]) =
          *reinterpret_cast<const int4*>(&nfh[((size_t)b * NN + n0 + rr) * DD + d0 + sc]);
      *reinterpret_cast<int4*>(&Bs[rr][sc]) =
          *reinterpret_cast<const int4*>(&wb1[(size_t)(o0 + rr) * DD + d0 + sc]);
    }
    __syncthreads();
#pragma unroll
    for (int kc = 0; kc < 2; ++kc) {
      int ko = kc * 32 + quad * 8;
      bf16x8 af[2], bfr[2];
#pragma unroll
      for (int i = 0; i < 2; ++i) {
        af[i]  = *reinterpret_cast<const bf16x8*>(&As[wn + i * 16 + lrow][ko]);
        bfr[i] = *reinterpret_cast<const bf16x8*>(&Bs[wo + i * 16 + lrow][ko]);
      }
#pragma unroll
      for (int i = 0; i < 2; ++i)
#pragma unroll
        for (int j = 0; j < 2; ++j)
          acc[i][j] = __builtin_amdgcn_mfma_f32_16x16x32_bf16(af[i], bfr[j], acc[i][j], 0, 0, 0);
    }
    __syncthreads();
  }
#pragma unroll
  for (int j = 0; j < 2; ++j) {
    int o = o0 + wo + j * 16 + lrow;
    float bias = b1[o];
#pragma unroll
    for (int i = 0; i < 2; ++i) {
      int nb = n0 + wn + i * 16 + quad * 4;
      ushort4 v;
      v.x = f2b(fmaxf(acc[i][j].x + bias, 0.f));
      v.y = f2b(fmaxf(acc[i][j].y + bias, 0.f));
      v.z = f2b(fmaxf(acc[i][j].z + bias, 0.f));
      v.w = f2b(fmaxf(acc[i][j].w + bias, 0.f));
      *reinterpret_cast<ushort4*>(&midh[((size_t)b * DD + o) * NN + nb]) = v;
    }
  }
}

// ---------------------------------------------------------------------------
// K15: conv2 via MFMA. GEMM: M=n, N=o2, K=o1.
// ---------------------------------------------------------------------------
__global__ __launch_bounds__(256) void k_conv2_mfma(
    const unsigned short* __restrict__ midh, const unsigned short* __restrict__ wb2,
    const float* __restrict__ b2, float* __restrict__ outp) {
  int b = blockIdx.z;
  int nblk = blockIdx.x;   // 64
  int oblk = blockIdx.y;   // 4
  int n0 = nblk * 64, o0 = oblk * 64;
  __shared__ unsigned short As[64][72];
  __shared__ unsigned short Bs[64][72];
  int t = threadIdx.x;
  int wave = t >> 6, lane = t & 63;
  int wn = (wave & 1) * 32, wo = (wave >> 1) * 32;
  int lrow = lane & 15, quad = lane >> 4;
  f32x4 acc[2][2] = {{{0.f,0.f,0.f,0.f},{0.f,0.f,0.f,0.f}},{{0.f,0.f,0.f,0.f},{0.f,0.f,0.f,0.f}}};
  int sr = t >> 3, sc = (t & 7) * 8;
  for (int d0 = 0; d0 < DD; d0 += 64) {
#pragma unroll
    for (int e = 0; e < 2; ++e) {
      int rr = sr + e * 32;
      *reinterpret_cast<int4*>(&Bs[rr][sc]) =
          *reinterpret_cast<const int4*>(&wb2[(size_t)(o0 + rr) * DD + d0 + sc]);
      unsigned short v[8];
      *reinterpret_cast<int4*>(v) =
          *reinterpret_cast<const int4*>(&midh[((size_t)b * DD + d0 + rr) * NN + n0 + sc]);
#pragma unroll
      for (int j = 0; j < 8; ++j) As[sc + j][rr] = v[j];
    }
    __syncthreads();
#pragma unroll
    for (int kc = 0; kc < 2; ++kc) {
      int ko = kc * 32 + quad * 8;
      bf16x8 af[2], bfr[2];
#pragma unroll
      for (int i = 0; i < 2; ++i) {
        af[i]  = *reinterpret_cast<const bf16x8*>(&As[wn + i * 16 + lrow][ko]);
        bfr[i] = *reinterpret_cast<const bf16x8*>(&Bs[wo + i * 16 + lrow][ko]);
      }
#pragma unroll
      for (int i = 0; i < 2; ++i)
#pragma unroll
        for (int j = 0; j < 2; ++j)
          acc[i][j] = __builtin_amdgcn_mfma_f32_16x16x32_bf16(af[i], bfr[j], acc[i][j], 0, 0, 0);
    }
    __syncthreads();
  }
#pragma unroll
  for (int j = 0; j < 2; ++j) {
    int o = o0 + wo + j * 16 + lrow;
    float bias = b2[o];
#pragma unroll
    for (int i = 0; i < 2; ++i) {
      int nb = n0 + wn + i * 16 + quad * 4;
      float4 v = make_float4(acc[i][j].x + bias, acc[i][j].y + bias,
                             acc[i][j].z + bias, acc[i][j].w + bias);
      *reinterpret_cast<float4*>(&outp[((size_t)b * DD + o) * NN + nb]) = v;
    }
  }
}

// ---------------------------------------------------------------------------
extern "C" void kernel_launch(void* const* d_in, const int* in_sizes, int n_in,
                              void* d_out, int out_size, void* d_ws, size_t ws_size,
                              hipStream_t stream) {
  (void)in_sizes; (void)n_in; (void)out_size; (void)ws_size;
  const float* pred   = (const float*)d_in[0];
  const float* feat   = (const float*)d_in[1];
  const float* w_cls1 = (const float*)d_in[2];
  const float* b_cls1 = (const float*)d_in[3];
  const float* w_cls2 = (const float*)d_in[4];
  const float* b_cls2 = (const float*)d_in[5];
  const float* w_pro1 = (const float*)d_in[6];
  const float* b_pro1 = (const float*)d_in[7];
  const float* w_pro2 = (const float*)d_in[8];
  const float* b_pro2 = (const float*)d_in[9];
  const float* cw     = (const float*)d_in[10];
  float* out = (float*)d_out;

  // workspace layout
  float* Mbuf = (float*)d_ws;                               // B*N*N fp32 (aff1 / packed-bf16 As / bf16 aff_f)
  float* spnT = Mbuf + (size_t)BB * NN * NN;
  float* p2b  = spnT + (size_t)BB * CC * NN;
  float* thr  = p2b + (size_t)BB * NN * CC;
  float* dsum = thr + BB * NN;
  float* d2s  = dsum + BB * NN;
  float* maskb = d2s + BB * NN;
  unsigned int* ohbits = (unsigned int*)(maskb + BB * NN);
  unsigned short* xh   = (unsigned short*)(ohbits + BB * NN);  // B*N*D fp16 hi
  unsigned short* xl   = xh + (size_t)BB * NN * DD;            // B*N*D fp16 lo*2^11
  unsigned short* nfh  = xl + (size_t)BB * NN * DD;            // B*N*D bf16
  unsigned short* midh = nfh + (size_t)BB * NN * DD;           // B*D*N bf16
  unsigned short* zb   = midh + (size_t)BB * DD * NN;          // B*D*N bf16
  unsigned short* wb1  = zb + (size_t)BB * DD * NN;            // D*D bf16
  unsigned short* wb2  = wb1 + (size_t)DD * DD;                // D*D bf16
  unsigned short* ybh  = wb2 + (size_t)DD * DD;                // B*32*N bf16 (padded y)
  unsigned short* Mh   = (unsigned short*)Mbuf;

  hipMemsetAsync(dsum, 0, sizeof(float) * BB * NN, stream);
  hipMemsetAsync(ohbits, 0, sizeof(unsigned int) * BB * NN, stream);

  // --- pred branch ---
  k_mask_bits<<<BB * NN / 256, 256, 0, stream>>>(pred, cw, maskb, ohbits);
  k_norm_feat<<<BB * NN / 64, 64, 0, stream>>>(feat, xh, xl);
  k_gram1<<<dim3(528, BB), 256, 0, stream>>>(xh, xl, Mbuf);
  k_topk<<<dim3(NN, BB), 256, 0, stream>>>(Mbuf, thr);
  k_symm<<<dim3(2080, BB), 256, 0, stream>>>(Mbuf, thr, dsum);
  k_fin_d<<<BB * NN / 256, 256, 0, stream>>>(dsum);
  k_make_yb<<<BB * 32 * NN / 4 / 256, 256, 0, stream>>>(pred, dsum, ybh);
  k_p2_mfma<<<dim3(NN / 64, BB), 256, 0, stream>>>(Mbuf, ybh, dsum, p2b);
  k_pred_head<<<BB * NN / 256, 256, 0, stream>>>(pred, p2b, maskb, w_cls1, b_cls1,
                                                 w_cls2, b_cls2, out, spnT);
  // --- feat branch (bf16 MFMA) ---
  k_gram2<<<dim3(2080, BB), 256, 0, stream>>>(spnT, ohbits, Mh);
  k_rowsum2h<<<dim3(NN, BB), 256, 0, stream>>>(Mh, d2s);
  k_make_z<<<BB * DD * NN / 4 / 256, 256, 0, stream>>>(feat, d2s, zb);
  k_prep_w<<<DD * DD / 256, 256, 0, stream>>>(w_pro1, w_pro2, wb1, wb2);
  k_newfeat_mfma<<<dim3(64, 4, BB), 256, 0, stream>>>(Mh, zb, d2s, nfh);
  k_conv1_mfma<<<dim3(64, 4, BB), 256, 0, stream>>>(nfh, wb1, b_pro1, midh);
  k_conv2_mfma<<<dim3(64, 4, BB), 256, 0, stream>>>(midh, wb2, b_pro2,
                                                    out + (size_t)BB * CC * NN);
}

// Round 8
// 483.484 us; speedup vs baseline: 2.1309x; 1.0740x over previous
//
#include <hip/hip_runtime.h>

#define NN 4096   // H*W
#define DD 256    // feature channels
#define CC 19     // classes
#define BB 2      // batch
#define KSPLIT 4  // split-K factor for new_feat GEMM

typedef __attribute__((ext_vector_type(8))) short bf16x8;     // bf16 MFMA A/B frag
typedef _Float16 f16x8 __attribute__((ext_vector_type(8)));   // fp16 MFMA A/B frag
typedef __attribute__((ext_vector_type(4))) float f32x4;      // MFMA C/D frag

__device__ inline unsigned short f2b(float f) {   // fp32 -> bf16 RNE
  unsigned int u = __float_as_uint(f);
  return (unsigned short)((u + 0x7FFFu + ((u >> 16) & 1u)) >> 16);
}
__device__ inline float b2f(unsigned short h) {
  return __uint_as_float(((unsigned int)h) << 16);
}
__device__ inline unsigned int pack2(float a, float b) {
  return (unsigned int)f2b(a) | ((unsigned int)f2b(b) << 16);
}
// fp32 -> (fp16 hi, fp16 lo*2^11): hi+2^-11*lo carries ~22 mantissa bits
__device__ inline void split16(float x, unsigned short& h, unsigned short& l) {
  _Float16 hh = (_Float16)x;
  float hf = (float)hh;
  _Float16 ll = (_Float16)((x - hf) * 2048.0f);
  h = *reinterpret_cast<unsigned short*>(&hh);
  l = *reinterpret_cast<unsigned short*>(&ll);
}

// ---------------------------------------------------------------------------
// K1: softmax confidence mask + scrambled one-hot bitmasks
// ---------------------------------------------------------------------------
__global__ void k_mask_bits(const float* __restrict__ pred, const float* __restrict__ cw,
                            float* __restrict__ maskb, unsigned int* __restrict__ ohbits) {
  int g = blockIdx.x * 256 + threadIdx.x;
  if (g >= BB * NN) return;
  int b = g >> 12, n = g & (NN - 1);
  const float* p = pred + (size_t)b * CC * NN + n;
  float v[CC];
  float mx = -1e30f; int am = 0;
#pragma unroll
  for (int c = 0; c < CC; ++c) {
    float t = p[(size_t)c * NN];
    v[c] = t;
    if (t > mx) { mx = t; am = c; }
  }
  float s = 0.f;
#pragma unroll
  for (int c = 0; c < CC; ++c) s += expf(v[c] - mx);
  float pprob = 1.f / s;
  float cmax = 0.f;
#pragma unroll
  for (int c = 0; c < CC; ++c) cmax = fmaxf(cmax, cw[c]);
  float cwm = cw[am] / (cmax + 1e-10f) * 0.95f;
  maskb[g] = (pprob >= 0.95f || pprob >= cwm) ? 1.f : 0.f;
  int h = n >> 6, w = n & 63;
  int L = w * (CC * 64) + am * 64 + h;     // flat index in [W,C,H]
  atomicOr(&ohbits[b * NN + L / CC], 1u << (L % CC));
}

// ---------------------------------------------------------------------------
// K2: row-normalize features -> split fp16 hi/lo, stored [b][n][d] (d-major)
// ---------------------------------------------------------------------------
__global__ void k_norm_feat(const float* __restrict__ feat,
                            unsigned short* __restrict__ xh, unsigned short* __restrict__ xl) {
  int g = blockIdx.x * 64 + threadIdx.x;
  int b = g >> 12, n = g & (NN - 1);
  const float* f = feat + (size_t)b * DD * NN + n;
  float s = 0.f;
  for (int d = 0; d < DD; ++d) { float t = f[(size_t)d * NN]; s += t * t; }
  float r = 1.f / (sqrtf(s) + 1e-9f);
  size_t ob = ((size_t)b * NN + n) * DD;
  for (int d = 0; d < DD; d += 4) {
    ushort4 oh, ol;
    split16(f[(size_t)d * NN] * r, oh.x, ol.x);
    split16(f[(size_t)(d + 1) * NN] * r, oh.y, ol.y);
    split16(f[(size_t)(d + 2) * NN] * r, oh.z, ol.z);
    split16(f[(size_t)(d + 3) * NN] * r, oh.w, ol.w);
    *reinterpret_cast<ushort4*>(&xh[ob + d]) = oh;
    *reinterpret_cast<ushort4*>(&xl[ob + d]) = ol;
  }
}

// ---------------------------------------------------------------------------
// K3: aff1 = clamp(Gram(xn), 0) via 3-pass split-fp16 MFMA (~fp32 accuracy).
// 128x128 tiles, triangular grid; writes fp32 both tiles.
// ---------------------------------------------------------------------------
__global__ __launch_bounds__(256, 2) void k_gram1(const unsigned short* __restrict__ xh,
                                                  const unsigned short* __restrict__ xl,
                                                  float* __restrict__ M) {
  int L = blockIdx.x;          // 0..527 triangular (32 tiles/dim)
  int b = blockIdx.y;
  int I = 0;
  while (L >= 32 - I) { L -= 32 - I; ++I; }
  int J = I + L;
  int i0 = I * 128, j0 = J * 128;
  float* Mb = M + (size_t)b * NN * NN;
  const unsigned short* XH = xh + (size_t)b * NN * DD;
  const unsigned short* XL = xl + (size_t)b * NN * DD;
  __shared__ unsigned short stage[4 * 128 * 40];   // 40KB; rows padded to 40 ushort
  int t = threadIdx.x;
  int wave = t >> 6, lane = t & 63;
  int wr = (wave & 1) * 64, wc = (wave >> 1) * 64;
  int lrow = lane & 15, quad = lane >> 4;
  f32x4 accH[4][4] = {}, accL[4][4] = {};
  const unsigned short* src = (wave == 0) ? XH + (size_t)i0 * DD
                             : (wave == 1) ? XL + (size_t)i0 * DD
                             : (wave == 2) ? XH + (size_t)j0 * DD
                                           : XL + (size_t)j0 * DD;
  for (int k0 = 0; k0 < DD; k0 += 32) {
#pragma unroll
    for (int e = 0; e < 8; ++e) {
      int row = lane + 64 * (e & 1);
      int o = e >> 1;
      *reinterpret_cast<int4*>(&stage[(wave * 128 + row) * 40 + o * 8]) =
          *reinterpret_cast<const int4*>(&src[(size_t)row * DD + k0 + o * 8]);
    }
    __syncthreads();
    f16x8 ah[4], al[4], bh[4], bl[4];
#pragma unroll
    for (int i = 0; i < 4; ++i) {
      int ra = wr + i * 16 + lrow;
      int rb = wc + i * 16 + lrow;
      ah[i] = *reinterpret_cast<const f16x8*>(&stage[(0 * 128 + ra) * 40 + quad * 8]);
      al[i] = *reinterpret_cast<const f16x8*>(&stage[(1 * 128 + ra) * 40 + quad * 8]);
      bh[i] = *reinterpret_cast<const f16x8*>(&stage[(2 * 128 + rb) * 40 + quad * 8]);
      bl[i] = *reinterpret_cast<const f16x8*>(&stage[(3 * 128 + rb) * 40 + quad * 8]);
    }
#pragma unroll
    for (int i = 0; i < 4; ++i) {
#pragma unroll
      for (int j = 0; j < 4; ++j) {
        accH[i][j] = __builtin_amdgcn_mfma_f32_16x16x32_f16(ah[i], bh[j], accH[i][j], 0, 0, 0);
        accL[i][j] = __builtin_amdgcn_mfma_f32_16x16x32_f16(ah[i], bl[j], accL[i][j], 0, 0, 0);
        accL[i][j] = __builtin_amdgcn_mfma_f32_16x16x32_f16(al[i], bh[j], accL[i][j], 0, 0, 0);
      }
    }
    __syncthreads();
  }
#pragma unroll
  for (int i = 0; i < 4; ++i) {
#pragma unroll
    for (int j = 0; j < 4; ++j) {
#pragma unroll
      for (int reg = 0; reg < 4; ++reg) {
        float v = fmaxf(accH[i][j][reg] + accL[i][j][reg] * 4.8828125e-4f, 0.f);
        accH[i][j][reg] = v;
        Mb[(size_t)(i0 + wr + i * 16 + quad * 4 + reg) * NN + j0 + wc + j * 16 + lrow] = v;
      }
    }
  }
  if (I != J) {
    float* trf = (float*)stage;   // [64][130] = 33.3KB <= 40KB
    for (int half = 0; half < 2; ++half) {
      __syncthreads();
      if ((wc >> 6) == half) {
#pragma unroll
        for (int i = 0; i < 4; ++i)
#pragma unroll
          for (int j = 0; j < 4; ++j)
#pragma unroll
            for (int reg = 0; reg < 4; ++reg)
              trf[(j * 16 + lrow) * 130 + wr + i * 16 + quad * 4 + reg] = accH[i][j][reg];
      }
      __syncthreads();
      int r = t >> 2, cbase = (t & 3) * 32;
#pragma unroll
      for (int q = 0; q < 8; ++q) {
        *reinterpret_cast<float4*>(&Mb[(size_t)(j0 + half * 64 + r) * NN + i0 + cbase + q * 4]) =
            *reinterpret_cast<float4*>(&trf[r * 130 + cbase + q * 4]);
      }
    }
  }
}

// ---------------------------------------------------------------------------
// K4: per-row 21st-largest value via bisection on the fp32 bit pattern.
// ---------------------------------------------------------------------------
__global__ __launch_bounds__(256) void k_topk(const float* __restrict__ M, float* __restrict__ thr) {
  int b = blockIdx.y, n = blockIdx.x;
  const float* row = M + (size_t)b * NN * NN + (size_t)n * NN;
  int t = threadIdx.x;
  unsigned int u[16];
#pragma unroll
  for (int e = 0; e < 4; ++e)
    *reinterpret_cast<uint4*>(&u[e * 4]) =
        *reinterpret_cast<const uint4*>(&row[t * 4 + e * 1024]);
  __shared__ int wsum[4];
  int lane = t & 63, wid = t >> 6;
  unsigned int lo = 0u, hi = 0x40000000u;
  while (lo < hi) {
    unsigned int mid = lo + ((hi - lo + 1) >> 1);
    int c = 0;
#pragma unroll
    for (int i = 0; i < 16; ++i) c += (u[i] >= mid) ? 1 : 0;
#pragma unroll
    for (int off = 32; off > 0; off >>= 1) c += __shfl_down(c, off);
    if (lane == 0) wsum[wid] = c;
    __syncthreads();
    int tot = wsum[0] + wsum[1] + wsum[2] + wsum[3];
    __syncthreads();
    if (tot >= 21) lo = mid; else hi = mid - 1;
  }
  if (t == 0) thr[b * NN + n] = __uint_as_float(lo);
}

// ---------------------------------------------------------------------------
// K5: sparsify + symmetrize As = S + S^T; bf16 packed in-place; degree sums
// ---------------------------------------------------------------------------
__global__ __launch_bounds__(256) void k_symm(float* __restrict__ M, const float* __restrict__ thr,
                                              float* __restrict__ dsum) {
  int L = blockIdx.x;          // 0..2079 triangular (64 tiles/dim)
  int b = blockIdx.y;
  int I = 0;
  while (L >= 64 - I) { L -= 64 - I; ++I; }
  int J = I + L;
  float* Mb = M + (size_t)b * NN * NN;
  unsigned short* Mus = (unsigned short*)Mb;
  const float* th = thr + b * NN;
  __shared__ float A[64][65];
  __shared__ float Bt[64][65];
  int t = threadIdx.x;
  int i0 = I * 64, j0 = J * 64;
  float areg[16];
#pragma unroll
  for (int e = 0; e < 16; ++e) {
    int lin = t + e * 256;
    int i = lin >> 6, j = lin & 63;
    areg[e] = Mb[(size_t)(i0 + i) * NN + j0 + j];
    Bt[i][j] = Mb[(size_t)(j0 + i) * NN + i0 + j];
  }
  __syncthreads();
#pragma unroll
  for (int e = 0; e < 16; ++e) {
    int lin = t + e * 256;
    int i = lin >> 6, j = lin & 63;
    float a = areg[e];
    float sa = (a >= th[i0 + i]) ? a : 0.f;
    float bt = Bt[j][i];
    float sb = (bt >= th[j0 + j]) ? bt : 0.f;
    A[i][j] = sa + sb;
  }
  __syncthreads();
  {
    int i = t >> 2, seg = (t & 3) * 16;
    float v[16];
#pragma unroll
    for (int q = 0; q < 4; ++q)
      *reinterpret_cast<float4*>(&v[q * 4]) = *reinterpret_cast<float4*>(&A[i][seg + q * 4]);
    unsigned int pk[8];
#pragma unroll
    for (int q = 0; q < 8; ++q) pk[q] = pack2(v[2 * q], v[2 * q + 1]);
    size_t ub = 2 * (size_t)(i0 + i) * NN + 2 * (size_t)j0 + seg;
    *reinterpret_cast<int4*>(&Mus[ub])     = *reinterpret_cast<int4*>(&pk[0]);
    *reinterpret_cast<int4*>(&Mus[ub + 8]) = *reinterpret_cast<int4*>(&pk[4]);
  }
  if (I != J) {
    int j = t >> 2, seg = (t & 3) * 16;
    float v[16];
#pragma unroll
    for (int e = 0; e < 16; ++e) v[e] = A[seg + e][j];
    unsigned int pk[8];
#pragma unroll
    for (int q = 0; q < 8; ++q) pk[q] = pack2(v[2 * q], v[2 * q + 1]);
    size_t ub = 2 * (size_t)(j0 + j) * NN + 2 * (size_t)i0 + seg;
    *reinterpret_cast<int4*>(&Mus[ub])     = *reinterpret_cast<int4*>(&pk[0]);
    *reinterpret_cast<int4*>(&Mus[ub + 8]) = *reinterpret_cast<int4*>(&pk[4]);
  }
  if (t < 64) {
    float s = 0.f;
#pragma unroll
    for (int j = 0; j < 64; ++j) s += A[t][j];
    atomicAdd(&dsum[b * NN + i0 + t], s);
  } else if (t < 128 && I != J) {
    int j = t - 64;
    float s = 0.f;
#pragma unroll
    for (int i = 0; i < 64; ++i) s += A[i][j];
    atomicAdd(&dsum[b * NN + j0 + j], s);
  }
}

// ---------------------------------------------------------------------------
// K6: d = (d + 1e-10)^-0.5
// ---------------------------------------------------------------------------
__global__ void k_fin_d(float* __restrict__ d) {
  int g = blockIdx.x * 256 + threadIdx.x;
  if (g < BB * NN) d[g] = 1.f / sqrtf(d[g] + 1e-10f);
}

// ---------------------------------------------------------------------------
// K7: ybh[b][c][n] = bf16(d1[b][n] * pred[b][c][n]), zero-padded to 32 classes
// ---------------------------------------------------------------------------
__global__ void k_make_yb(const float* __restrict__ pred, const float* __restrict__ d1,
                          unsigned short* __restrict__ ybh) {
  int g = blockIdx.x * 256 + threadIdx.x;   // BB*32*NN/4 threads
  int idx = g * 4;
  int b = idx / (32 * NN);
  int c = (idx / NN) & 31;
  int n = idx & (NN - 1);
  ushort4 o = make_ushort4(0, 0, 0, 0);
  if (c < CC) {
    float4 p = *reinterpret_cast<const float4*>(&pred[((size_t)b * CC + c) * NN + n]);
    const float* dd = d1 + b * NN + n;
    o.x = f2b(p.x * dd[0]); o.y = f2b(p.y * dd[1]);
    o.z = f2b(p.z * dd[2]); o.w = f2b(p.w * dd[3]);
  }
  *reinterpret_cast<ushort4*>(&ybh[idx]) = o;
}

// ---------------------------------------------------------------------------
// K8: p2 via MFMA.  GEMM: M=n (64-tile), N=c (32 padded), K=m (4096).
// ---------------------------------------------------------------------------
__global__ __launch_bounds__(256) void k_p2_mfma(
    const float* __restrict__ M, const unsigned short* __restrict__ ybh,
    const float* __restrict__ d1, float* __restrict__ p2b) {
  int b = blockIdx.y;
  int n0 = blockIdx.x * 64;
  const unsigned short* Mus = (const unsigned short*)(M + (size_t)b * NN * NN);
  const unsigned short* Y = ybh + (size_t)b * 32 * NN;
  __shared__ unsigned short As[64][72];
  __shared__ unsigned short Ys[32][72];
  int t = threadIdx.x;
  int wave = t >> 6, lane = t & 63;
  int wn = (wave & 1) * 32;
  int wc = (wave >> 1) * 16;
  int lrow = lane & 15, quad = lane >> 4;
  f32x4 acc[2] = {{0.f,0.f,0.f,0.f},{0.f,0.f,0.f,0.f}};
  int sr = t >> 3, scc = (t & 7) * 8;
  for (int m0 = 0; m0 < NN; m0 += 64) {
#pragma unroll
    for (int e = 0; e < 2; ++e) {
      int rr = sr + e * 32;
      *reinterpret_cast<int4*>(&As[rr][scc]) =
          *reinterpret_cast<const int4*>(&Mus[2 * (size_t)(n0 + rr) * NN + 2 * (size_t)m0 + scc]);
    }
    *reinterpret_cast<int4*>(&Ys[sr][scc]) =
        *reinterpret_cast<const int4*>(&Y[(size_t)sr * NN + m0 + scc]);
    __syncthreads();
#pragma unroll
    for (int kc = 0; kc < 2; ++kc) {
      int ko = kc * 32 + quad * 8;
      bf16x8 bfr = *reinterpret_cast<const bf16x8*>(&Ys[wc + lrow][ko]);
#pragma unroll
      for (int i = 0; i < 2; ++i) {
        bf16x8 af = *reinterpret_cast<const bf16x8*>(&As[wn + i * 16 + lrow][ko]);
        acc[i] = __builtin_amdgcn_mfma_f32_16x16x32_bf16(af, bfr, acc[i], 0, 0, 0);
      }
    }
    __syncthreads();
  }
  int c = wc + lrow;
  if (c < CC) {
#pragma unroll
    for (int i = 0; i < 2; ++i) {
#pragma unroll
      for (int reg = 0; reg < 4; ++reg) {
        int n = n0 + wn + i * 16 + quad * 4 + reg;
        p2b[((size_t)b * NN + n) * CC + c] = d1[b * NN + n] * acc[i][reg];
      }
    }
  }
}

// ---------------------------------------------------------------------------
// K9: fused blend + 19x19 conv x2 -> pred_out, then softmax + cosine-normalize
// ---------------------------------------------------------------------------
__global__ __launch_bounds__(256) void k_pred_head(const float* __restrict__ pred,
    const float* __restrict__ p2b, const float* __restrict__ maskb,
    const float* __restrict__ w1, const float* __restrict__ b1,
    const float* __restrict__ w2, const float* __restrict__ b2,
    float* __restrict__ out, float* __restrict__ spnT) {
  __shared__ float sw1[CC * CC], sw2[CC * CC], sb1[CC], sb2[CC];
  int t = threadIdx.x;
  for (int i = t; i < CC * CC; i += 256) { sw1[i] = w1[i]; sw2[i] = w2[i]; }
  if (t < CC) { sb1[t] = b1[t]; sb2[t] = b2[t]; }
  __syncthreads();
  int g = blockIdx.x * 256 + t;
  int b = g >> 12, n = g & (NN - 1);
  float m = maskb[g];
  float ca = (m > 0.5f) ? 0.2f : 0.8f;
  float cb = (m > 0.5f) ? 0.8f : 0.2f;
  const float* P = pred + (size_t)b * CC * NN + n;
  const float* Q = p2b + (size_t)g * CC;
  float p3[CC];
#pragma unroll
  for (int c = 0; c < CC; ++c) p3[c] = ca * Q[c] + cb * P[(size_t)c * NN];
  float midv[CC];
#pragma unroll
  for (int o = 0; o < CC; ++o) {
    float s = sb1[o];
#pragma unroll
    for (int c = 0; c < CC; ++c) s += sw1[o * CC + c] * p3[c];
    midv[o] = s;
  }
  float ov[CC];
  float mx = -1e30f;
#pragma unroll
  for (int o = 0; o < CC; ++o) {
    float s = sb2[o];
#pragma unroll
    for (int c = 0; c < CC; ++c) s += sw2[o * CC + c] * midv[c];
    ov[o] = s;
    out[(size_t)b * CC * NN + (size_t)o * NN + n] = s;
    mx = fmaxf(mx, s);
  }
  float se = 0.f;
  float e[CC];
#pragma unroll
  for (int o = 0; o < CC; ++o) { e[o] = expf(ov[o] - mx); se += e[o]; }
  float inv = 1.f / se;
  float nrm = 0.f;
#pragma unroll
  for (int o = 0; o < CC; ++o) { float sp = e[o] * inv; e[o] = sp; nrm += sp * sp; }
  float rn = 1.f / (sqrtf(nrm) + 1e-9f);
#pragma unroll
  for (int o = 0; o < CC; ++o) spnT[(size_t)b * CC * NN + (size_t)o * NN + n] = e[o] * rn;
}

// ---------------------------------------------------------------------------
// K10: aff_f = bitmask ? clamp(Gram(spn),0) : 0   (K=19), writes bf16.
// ---------------------------------------------------------------------------
__global__ __launch_bounds__(256) void k_gram2(const float* __restrict__ spnT,
    const unsigned int* __restrict__ bits, unsigned short* __restrict__ Mh) {
  int L = blockIdx.x;          // 0..2079 triangular (64 tiles/dim)
  int b = blockIdx.y;
  int I = 0;
  while (L >= 64 - I) { L -= 64 - I; ++I; }
  int J = I + L;
  const float* X = spnT + (size_t)b * CC * NN;
  unsigned short* Mb = Mh + (size_t)b * NN * NN;
  __shared__ float sA[CC][64], sB[CC][64];
  __shared__ unsigned int bI[64], bJ[64];
  __shared__ float tr[64][65];
  int t = threadIdx.x;
  int r = t >> 4, c = t & 15;
  int i0 = I * 64, j0 = J * 64;
  for (int e = t; e < CC * 64; e += 256) {
    int k = e >> 6, col = e & 63;
    sA[k][col] = X[(size_t)k * NN + i0 + col];
    sB[k][col] = X[(size_t)k * NN + j0 + col];
  }
  if (t < 64) bI[t] = bits[b * NN + i0 + t];
  else if (t < 128) bJ[t - 64] = bits[b * NN + j0 + t - 64];
  __syncthreads();
  float acc[4][4] = {};
#pragma unroll
  for (int k = 0; k < CC; ++k) {
    float av[4], bv[4];
#pragma unroll
    for (int i = 0; i < 4; ++i) av[i] = sA[k][r * 4 + i];
#pragma unroll
    for (int j = 0; j < 4; ++j) bv[j] = sB[k][c * 4 + j];
#pragma unroll
    for (int i = 0; i < 4; ++i) {
#pragma unroll
      for (int j = 0; j < 4; ++j) acc[i][j] += av[i] * bv[j];
    }
  }
#pragma unroll
  for (int i = 0; i < 4; ++i) {
#pragma unroll
    for (int j = 0; j < 4; ++j) {
      bool keep = (bI[r * 4 + i] & bJ[c * 4 + j]) != 0u;
      acc[i][j] = keep ? fmaxf(acc[i][j], 0.f) : 0.f;
    }
    ushort4 v;
    v.x = f2b(acc[i][0]); v.y = f2b(acc[i][1]); v.z = f2b(acc[i][2]); v.w = f2b(acc[i][3]);
    *reinterpret_cast<ushort4*>(&Mb[(size_t)(i0 + r * 4 + i) * NN + j0 + c * 4]) = v;
  }
  if (I != J) {
#pragma unroll
    for (int i = 0; i < 4; ++i) {
#pragma unroll
      for (int j = 0; j < 4; ++j) tr[r * 4 + i][c * 4 + j] = acc[i][j];
    }
    __syncthreads();
#pragma unroll
    for (int e = 0; e < 16; ++e) {
      int lin = t + e * 256;
      int jr = lin >> 6, ic = lin & 63;
      Mb[(size_t)(j0 + jr) * NN + i0 + ic] = f2b(tr[ic][jr]);
    }
  }
}

// ---------------------------------------------------------------------------
// K11: d2[n] = (row_sum(aff_f bf16) + 1e-10)^-0.5
// ---------------------------------------------------------------------------
__global__ __launch_bounds__(256) void k_rowsum2h(const unsigned short* __restrict__ Mh,
                                                  float* __restrict__ d2) {
  int b = blockIdx.y, n = blockIdx.x;
  const unsigned short* row = Mh + (size_t)b * NN * NN + (size_t)n * NN;
  int t = threadIdx.x;
  float s = 0.f;
#pragma unroll
  for (int i = 0; i < 8; ++i) {
    unsigned int u = *reinterpret_cast<const unsigned int*>(&row[(i * 256 + t) * 2]);
    s += __uint_as_float(u << 16) + __uint_as_float(u & 0xffff0000u);
  }
  for (int off = 32; off > 0; off >>= 1) s += __shfl_down(s, off);
  __shared__ float p4[4];
  int wid = t >> 6, lane = t & 63;
  if (lane == 0) p4[wid] = s;
  __syncthreads();
  if (t == 0) d2[b * NN + n] = 1.f / sqrtf(p4[0] + p4[1] + p4[2] + p4[3] + 1e-10f);
}

// ---------------------------------------------------------------------------
// K12a: zb[b][d][m] = bf16(feat[b][d][m] * d2[b][m])
// ---------------------------------------------------------------------------
__global__ void k_make_z(const float* __restrict__ feat, const float* __restrict__ d2,
                         unsigned short* __restrict__ zb) {
  int g = blockIdx.x * 256 + threadIdx.x;   // BB*DD*NN/4 threads
  int idx = g * 4;
  int b = idx / (DD * NN);
  int m = idx & (NN - 1);
  float4 f = *reinterpret_cast<const float4*>(&feat[idx]);
  const float* dd = d2 + b * NN + m;
  ushort4 o;
  o.x = f2b(f.x * dd[0]); o.y = f2b(f.y * dd[1]);
  o.z = f2b(f.z * dd[2]); o.w = f2b(f.w * dd[3]);
  *reinterpret_cast<ushort4*>(&zb[idx]) = o;
}

// K12b: convert projection weights to bf16
__global__ void k_prep_w(const float* __restrict__ w1, const float* __restrict__ w2,
                         unsigned short* __restrict__ wb1, unsigned short* __restrict__ wb2) {
  int g = blockIdx.x * 256 + threadIdx.x;   // DD*DD threads
  wb1[g] = f2b(w1[g]);
  wb2[g] = f2b(w2[g]);
}

// ---------------------------------------------------------------------------
// K13: new_feat via MFMA with split-K x4 (fixes launch-width bound: 2048
// blocks -> 8 blocks/CU).  GEMM: M=d(64), N=n(64), K-chunk=1024.
// Writes fp32 partials nfp[(b*KSPLIT+ks)][n][d].
// ---------------------------------------------------------------------------
__global__ __launch_bounds__(256) void k_newfeat_mfma(
    const unsigned short* __restrict__ Mh, const unsigned short* __restrict__ zb,
    float* __restrict__ nfp) {
  int zz = blockIdx.z;                 // b*KSPLIT + ks
  int b = zz / KSPLIT, ks = zz % KSPLIT;
  int nblk = blockIdx.x;   // 64
  int dblk = blockIdx.y;   // 4
  const int KLEN = NN / KSPLIT;        // 1024
  const unsigned short* A = zb + (size_t)b * DD * NN + (size_t)(dblk * 64) * NN + ks * KLEN;
  const unsigned short* Bm = Mh + (size_t)b * NN * NN + (size_t)(nblk * 64) * NN + ks * KLEN;
  __shared__ unsigned short As[64][72];
  __shared__ unsigned short Bs[64][72];
  int t = threadIdx.x;
  int wave = t >> 6, lane = t & 63;
  int wd = (wave & 1) * 32, wn = (wave >> 1) * 32;
  int lrow = lane & 15, quad = lane >> 4;
  f32x4 acc[2][2] = {{{0.f,0.f,0.f,0.f},{0.f,0.f,0.f,0.f}},{{0.f,0.f,0.f,0.f},{0.f,0.f,0.f,0.f}}};
  int sr = t >> 3, sc = (t & 7) * 8;
  for (int m0 = 0; m0 < KLEN; m0 += 64) {
#pragma unroll
    for (int e = 0; e < 2; ++e) {
      int rr = sr + e * 32;
      *reinterpret_cast<int4*>(&As[rr][sc]) =
          *reinterpret_cast<const int4*>(&A[(size_t)rr * NN + m0 + sc]);
      *reinterpret_cast<int4*>(&Bs[rr][sc]) =
          *reinterpret_cast<const int4*>(&Bm[(size_t)rr * NN + m0 + sc]);
    }
    __syncthreads();
#pragma unroll
    for (int kc = 0; kc < 2; ++kc) {
      int ko = kc * 32 + quad * 8;
      bf16x8 af[2], bfr[2];
#pragma unroll
      for (int i = 0; i < 2; ++i) {
        af[i]  = *reinterpret_cast<const bf16x8*>(&As[wd + i * 16 + lrow][ko]);
        bfr[i] = *reinterpret_cast<const bf16x8*>(&Bs[wn + i * 16 + lrow][ko]);
      }
#pragma unroll
      for (int i = 0; i < 2; ++i)
#pragma unroll
        for (int j = 0; j < 2; ++j)
          acc[i][j] = __builtin_amdgcn_mfma_f32_16x16x32_bf16(af[i], bfr[j], acc[i][j], 0, 0, 0);
    }
    __syncthreads();
  }
#pragma unroll
  for (int j = 0; j < 2; ++j) {
    int n = nblk * 64 + wn + j * 16 + lrow;
#pragma unroll
    for (int i = 0; i < 2; ++i) {
      int d = dblk * 64 + wd + i * 16 + quad * 4;
      float4 v = make_float4(acc[i][j].x, acc[i][j].y, acc[i][j].z, acc[i][j].w);
      *reinterpret_cast<float4*>(&nfp[((size_t)zz * NN + n) * DD + d]) = v;
    }
  }
}

// ---------------------------------------------------------------------------
// K13b: reduce split-K partials, scale by d2, emit bf16 nfh[b][n][d]
// ---------------------------------------------------------------------------
__global__ void k_nf_reduce(const float* __restrict__ nfp, const float* __restrict__ d2,
                            unsigned short* __restrict__ nfh) {
  int g = blockIdx.x * 256 + threadIdx.x;   // BB*NN*DD/4 threads
  int idx = g * 4;
  int b = idx / (NN * DD);
  int n = (idx / DD) & (NN - 1);
  int d = idx & (DD - 1);
  size_t base = (((size_t)b * KSPLIT) * NN + n) * DD + d;
  float4 s = make_float4(0.f, 0.f, 0.f, 0.f);
#pragma unroll
  for (int ks = 0; ks < KSPLIT; ++ks) {
    float4 v = *reinterpret_cast<const float4*>(&nfp[base + (size_t)ks * NN * DD]);
    s.x += v.x; s.y += v.y; s.z += v.z; s.w += v.w;
  }
  float sc = d2[b * NN + n];
  ushort4 o;
  o.x = f2b(s.x * sc); o.y = f2b(s.y * sc); o.z = f2b(s.z * sc); o.w = f2b(s.w * sc);
  *reinterpret_cast<ushort4*>(&nfh[idx]) = o;
}

// ---------------------------------------------------------------------------
// K14: conv1 via MFMA. GEMM: M=n, N=o1, K=d.
// ---------------------------------------------------------------------------
__global__ __launch_bounds__(256) void k_conv1_mfma(
    const unsigned short* __restrict__ nfh, const unsigned short* __restrict__ wb1,
    const float* __restrict__ b1, unsigned short* __restrict__ midh) {
  int b = blockIdx.z;
  int nblk = blockIdx.x;   // 64
  int oblk = blockIdx.y;   // 4
  int n0 = nblk * 64, o0 = oblk * 64;
  __shared__ unsigned short As[64][72];
  __shared__ unsigned short Bs[64][72];
  int t = threadIdx.x;
  int wave = t >> 6, lane = t & 63;
  int wn = (wave & 1) * 32, wo = (wave >> 1) * 32;
  int lrow = lane & 15, quad = lane >> 4;
  f32x4 acc[2][2] = {{{0.f,0.f,0.f,0.f},{0.f,0.f,0.f,0.f}},{{0.f,0.f,0.f,0.f},{0.f,0.f,0.f,0.f}}};
  int sr = t >> 3, sc = (t & 7) * 8;
  for (int d0 = 0; d0 < DD; d0 += 64) {
#pragma unroll
    for (int e = 0; e < 2; ++e) {
      int rr = sr + e * 32;
      *reinterpret_cast<int4*>(&As[rr][sc]) =
          *reinterpret_cast<const int4*>(&nfh[((size_t)b * NN + n0 + rr) * DD + d0 + sc]);
      *reinterpret_cast<int4*>(&Bs[rr][sc]) =
          *reinterpret_cast<const int4*>(&wb1[(size_t)(o0 + rr) * DD + d0 + sc]);
    }
    __syncthreads();
#pragma unroll
    for (int kc = 0; kc < 2; ++kc) {
      int ko = kc * 32 + quad * 8;
      bf16x8 af[2], bfr[2];
#pragma unroll
      for (int i = 0; i < 2; ++i) {
        af[i]  = *reinterpret_cast<const bf16x8*>(&As[wn + i * 16 + lrow][ko]);
        bfr[i] = *reinterpret_cast<const bf16x8*>(&Bs[wo + i * 16 + lrow][ko]);
      }
#pragma unroll
      for (int i = 0; i < 2; ++i)
#pragma unroll
        for (int j = 0; j < 2; ++j)
          acc[i][j] = __builtin_amdgcn_mfma_f32_16x16x32_bf16(af[i], bfr[j], acc[i][j], 0, 0, 0);
    }
    __syncthreads();
  }
#pragma unroll
  for (int j = 0; j < 2; ++j) {
    int o = o0 + wo + j * 16 + lrow;
    float bias = b1[o];
#pragma unroll
    for (int i = 0; i < 2; ++i) {
      int nb = n0 + wn + i * 16 + quad * 4;
      ushort4 v;
      v.x = f2b(fmaxf(acc[i][j].x + bias, 0.f));
      v.y = f2b(fmaxf(acc[i][j].y + bias, 0.f));
      v.z = f2b(fmaxf(acc[i][j].z + bias, 0.f));
      v.w = f2b(fmaxf(acc[i][j].w + bias, 0.f));
      *reinterpret_cast<ushort4*>(&midh[((size_t)b * DD + o) * NN + nb]) = v;
    }
  }
}

// ---------------------------------------------------------------------------
// K15: conv2 via MFMA. GEMM: M=n, N=o2, K=o1.
// ---------------------------------------------------------------------------
__global__ __launch_bounds__(256) void k_conv2_mfma(
    const unsigned short* __restrict__ midh, const unsigned short* __restrict__ wb2,
    const float* __restrict__ b2, float* __restrict__ outp) {
  int b = blockIdx.z;
  int nblk = blockIdx.x;   // 64
  int oblk = blockIdx.y;   // 4
  int n0 = nblk * 64, o0 = oblk * 64;
  __shared__ unsigned short As[64][72];
  __shared__ unsigned short Bs[64][72];
  int t = threadIdx.x;
  int wave = t >> 6, lane = t & 63;
  int wn = (wave & 1) * 32, wo = (wave >> 1) * 32;
  int lrow = lane & 15, quad = lane >> 4;
  f32x4 acc[2][2] = {{{0.f,0.f,0.f,0.f},{0.f,0.f,0.f,0.f}},{{0.f,0.f,0.f,0.f},{0.f,0.f,0.f,0.f}}};
  int sr = t >> 3, sc = (t & 7) * 8;
  for (int d0 = 0; d0 < DD; d0 += 64) {
#pragma unroll
    for (int e = 0; e < 2; ++e) {
      int rr = sr + e * 32;
      *reinterpret_cast<int4*>(&Bs[rr][sc]) =
          *reinterpret_cast<const int4*>(&wb2[(size_t)(o0 + rr) * DD + d0 + sc]);
      unsigned short v[8];
      *reinterpret_cast<int4*>(v) =
          *reinterpret_cast<const int4*>(&midh[((size_t)b * DD + d0 + rr) * NN + n0 + sc]);
#pragma unroll
      for (int j = 0; j < 8; ++j) As[sc + j][rr] = v[j];
    }
    __syncthreads();
#pragma unroll
    for (int kc = 0; kc < 2; ++kc) {
      int ko = kc * 32 + quad * 8;
      bf16x8 af[2], bfr[2];
#pragma unroll
      for (int i = 0; i < 2; ++i) {
        af[i]  = *reinterpret_cast<const bf16x8*>(&As[wn + i * 16 + lrow][ko]);
        bfr[i] = *reinterpret_cast<const bf16x8*>(&Bs[wo + i * 16 + lrow][ko]);
      }
#pragma unroll
      for (int i = 0; i < 2; ++i)
#pragma unroll
        for (int j = 0; j < 2; ++j)
          acc[i][j] = __builtin_amdgcn_mfma_f32_16x16x32_bf16(af[i], bfr[j], acc[i][j], 0, 0, 0);
    }
    __syncthreads();
  }
#pragma unroll
  for (int j = 0; j < 2; ++j) {
    int o = o0 + wo + j * 16 + lrow;
    float bias = b2[o];
#pragma unroll
    for (int i = 0; i < 2; ++i) {
      int nb = n0 + wn + i * 16 + quad * 4;
      float4 v = make_float4(acc[i][j].x + bias, acc[i][j].y + bias,
                             acc[i][j].z + bias, acc[i][j].w + bias);
      *reinterpret_cast<float4*>(&outp[((size_t)b * DD + o) * NN + nb]) = v;
    }
  }
}

// ---------------------------------------------------------------------------
extern "C" void kernel_launch(void* const* d_in, const int* in_sizes, int n_in,
                              void* d_out, int out_size, void* d_ws, size_t ws_size,
                              hipStream_t stream) {
  (void)in_sizes; (void)n_in; (void)out_size; (void)ws_size;
  const float* pred   = (const float*)d_in[0];
  const float* feat   = (const float*)d_in[1];
  const float* w_cls1 = (const float*)d_in[2];
  const float* b_cls1 = (const float*)d_in[3];
  const float* w_cls2 = (const float*)d_in[4];
  const float* b_cls2 = (const float*)d_in[5];
  const float* w_pro1 = (const float*)d_in[6];
  const float* b_pro1 = (const float*)d_in[7];
  const float* w_pro2 = (const float*)d_in[8];
  const float* b_pro2 = (const float*)d_in[9];
  const float* cw     = (const float*)d_in[10];
  float* out = (float*)d_out;

  // workspace layout
  float* Mbuf = (float*)d_ws;                               // B*N*N fp32 (aff1 / packed-bf16 As / bf16 aff_f)
  float* spnT = Mbuf + (size_t)BB * NN * NN;
  float* p2b  = spnT + (size_t)BB * CC * NN;
  float* thr  = p2b + (size_t)BB * NN * CC;
  float* dsum = thr + BB * NN;
  float* d2s  = dsum + BB * NN;
  float* maskb = d2s + BB * NN;
  unsigned int* ohbits = (unsigned int*)(maskb + BB * NN);
  unsigned short* xh   = (unsigned short*)(ohbits + BB * NN);  // B*N*D fp16 hi
  unsigned short* xl   = xh + (size_t)BB * NN * DD;            // B*N*D fp16 lo*2^11
  unsigned short* nfh  = xl + (size_t)BB * NN * DD;            // B*N*D bf16
  unsigned short* midh = nfh + (size_t)BB * NN * DD;           // B*D*N bf16
  unsigned short* zb   = midh + (size_t)BB * DD * NN;          // B*D*N bf16
  unsigned short* wb1  = zb + (size_t)BB * DD * NN;            // D*D bf16
  unsigned short* wb2  = wb1 + (size_t)DD * DD;                // D*D bf16
  unsigned short* ybh  = wb2 + (size_t)DD * DD;                // B*32*N bf16 (padded y)
  unsigned short* Mh   = (unsigned short*)Mbuf;
  // split-K partials: alias the upper half of Mbuf (batch-1's packed As,
  // dead after k_p2; Mh/aff_f only occupies the lower half as ushorts)
  float* nfp = (float*)(Mh + (size_t)BB * NN * NN);            // KSPLIT*B*N*D fp32 = 32 MB

  hipMemsetAsync(dsum, 0, sizeof(float) * BB * NN, stream);
  hipMemsetAsync(ohbits, 0, sizeof(unsigned int) * BB * NN, stream);

  // --- pred branch ---
  k_mask_bits<<<BB * NN / 256, 256, 0, stream>>>(pred, cw, maskb, ohbits);
  k_norm_feat<<<BB * NN / 64, 64, 0, stream>>>(feat, xh, xl);
  k_gram1<<<dim3(528, BB), 256, 0, stream>>>(xh, xl, Mbuf);
  k_topk<<<dim3(NN, BB), 256, 0, stream>>>(Mbuf, thr);
  k_symm<<<dim3(2080, BB), 256, 0, stream>>>(Mbuf, thr, dsum);
  k_fin_d<<<BB * NN / 256, 256, 0, stream>>>(dsum);
  k_make_yb<<<BB * 32 * NN / 4 / 256, 256, 0, stream>>>(pred, dsum, ybh);
  k_p2_mfma<<<dim3(NN / 64, BB), 256, 0, stream>>>(Mbuf, ybh, dsum, p2b);
  k_pred_head<<<BB * NN / 256, 256, 0, stream>>>(pred, p2b, maskb, w_cls1, b_cls1,
                                                 w_cls2, b_cls2, out, spnT);
  // --- feat branch (bf16 MFMA) ---
  k_gram2<<<dim3(2080, BB), 256, 0, stream>>>(spnT, ohbits, Mh);
  k_rowsum2h<<<dim3(NN, BB), 256, 0, stream>>>(Mh, d2s);
  k_make_z<<<BB * DD * NN / 4 / 256, 256, 0, stream>>>(feat, d2s, zb);
  k_prep_w<<<DD * DD / 256, 256, 0, stream>>>(w_pro1, w_pro2, wb1, wb2);
  k_newfeat_mfma<<<dim3(64, 4, BB * KSPLIT), 256, 0, stream>>>(Mh, zb, nfp);
  k_nf_reduce<<<BB * NN * DD / 4 / 256, 256, 0, stream>>>(nfp, d2s, nfh);
  k_conv1_mfma<<<dim3(64, 4, BB), 256, 0, stream>>>(nfh, wb1, b_pro1, midh);
  k_conv2_mfma<<<dim3(64, 4, BB), 256, 0, stream>>>(midh, wb2, b_pro2,
                                                    out + (size_t)BB * CC * NN);
}